// Round 4
// baseline (1354.420 us; speedup 1.0000x reference)
//
#include <hip/hip_runtime.h>
#include <math.h>

#define B_ 4
#define N_ 2048
#define C_ 256
#define KMAX_ 1024
#define KU_ 171
#define ITERS_ 3
#define H_ 4
#define EPS_ 1e-8f
#define SIGF_ 0.03f
#define JIT_ 1e-6f
#define LOGKMAX_ 6.93147180559945f

// ---------------- workspace layout (float offsets) ----------------
#define WS_CNT 0          // 4
#define WS_MUS 4          // 12
#define WS_MOS 16         // 24
#define WS_SGS 40         // 36
#define WS_COLACC 100     // 1 (zeroed by the stats memset)
#define WS_SSUM 128       // 1024
#define WS_STATS_BYTES (1152*4)
#define WS_MEAN 1152      // 12
#define WS_STD 1164       // 12
#define WS_SIGAVG 1176    // 36
#define WS_IDXI 1216      // 684 ints (pad to 1920)
#define WS_KSEM 1920                  // B*N*C = 2097152
#define WS_QSEM (WS_KSEM+2097152)     // 175104
#define WS_OCC  (WS_QSEM+175104)      // 684 (pad 704)
#define WS_SLOTIN (WS_OCC+704)        // 175104
#define WS_GI (WS_SLOTIN+175104)      // 525312
#define WS_GH (WS_GI+525312)          // 525312 region reused:
#define WS_QV     WS_GH               //   1024
#define WS_SCORE (WS_GH+1024)         //   4096
#define WS_ACPART (WS_GH+1024+4096)   //   4*4*176*10 = 28160
#define WS_XM (WS_GH+525312)          // 175104 (unused)
#define WS_HID (WS_XM+175104)         // 700416
#define WS_ATA (WS_HID+700416)        // 116964

// ---------------- output layout (float offsets) ----------------
#define O_A 0
#define O_SLOTS 1400832
#define O_MUK   1575936
#define O_SIGK  1577988
#define O_IDX   1584144
#define O_KL    1584828
#define O_ENT   1584829
#define O_OCC   1584830
#define O_COL   1584831
#define O_TOT   1584832

__device__ __forceinline__ float wred(float v) {
  #pragma unroll
  for (int i = 32; i; i >>= 1) v += __shfl_xor(v, i);
  return v;
}

__device__ __forceinline__ float blk_red(float v, float* red, int t) {
  red[t] = v; __syncthreads();
  #pragma unroll
  for (int s = 128; s > 0; s >>= 1) {
    if (t < s) red[t] += red[t + s];
    __syncthreads();
  }
  float r = red[0]; __syncthreads();
  return r;
}

// ---- partial batch stats: wave-level reductions, no blockwide syncs ----
__global__ __launch_bounds__(256) void k_stats(const float* __restrict__ s,
    const float* __restrict__ mu, const float* __restrict__ Sigma,
    const float* __restrict__ mask, float* __restrict__ ws) {
  int blk = blockIdx.x; int b = blk / 8; int nc = blk % 8; int t = threadIdx.x;
  int n = nc * 256 + t;
  float m = mask[b * N_ + n];
  const float* mun = mu + ((size_t)(b * N_ + n)) * 3;
  float m0 = mun[0], m1v = mun[1], m2 = mun[2];
  const float* sgn = Sigma + ((size_t)(b * N_ + n)) * 9;
  float sg[9];
  #pragma unroll
  for (int j = 0; j < 9; j++) sg[j] = sgn[j];
  int lane = t & 63;
  float vals[19];
  vals[0] = m; vals[1] = m * m0; vals[2] = m * m1v; vals[3] = m * m2;
  vals[4] = m * m0 * m0; vals[5] = m * m0 * m1v; vals[6] = m * m0 * m2;
  vals[7] = m * m1v * m1v; vals[8] = m * m1v * m2; vals[9] = m * m2 * m2;
  #pragma unroll
  for (int j = 0; j < 9; j++) vals[10 + j] = m * sg[j];
  const int dst[19] = {WS_CNT, WS_MUS, WS_MUS + 1, WS_MUS + 2,
                       WS_MOS, WS_MOS + 1, WS_MOS + 2, WS_MOS + 3, WS_MOS + 4, WS_MOS + 5,
                       WS_SGS, WS_SGS + 1, WS_SGS + 2, WS_SGS + 3, WS_SGS + 4,
                       WS_SGS + 5, WS_SGS + 6, WS_SGS + 7, WS_SGS + 8};
  #pragma unroll
  for (int j = 0; j < 19; j++) {
    float v = wred(vals[j]);
    if (lane == 0) {
      int base = (j == 0) ? WS_CNT + b : (j < 4 ? WS_MUS + b * 3 + (j - 1)
                 : (j < 10 ? WS_MOS + b * 6 + (j - 4) : WS_SGS + b * 9 + (j - 10)));
      (void)dst;
      atomicAdd(ws + base, v);
    }
  }
  // s-column sums: thread t owns column c=t over this block's 256 rows
  const float* sb = s + ((size_t)b * N_ + nc * 256) * C_;
  const float* mk = mask + b * N_ + nc * 256;
  float sa = 0.f;
  #pragma unroll 4
  for (int nn = 0; nn < 256; nn++) sa += mk[nn] * sb[(size_t)nn * C_ + t];
  atomicAdd(ws + WS_SSUM + b * C_ + t, sa);
}

// ---- finalize mean/std/sigavg ----
__global__ __launch_bounds__(64) void k_fin(float* __restrict__ ws) {
  int t = threadIdx.x;
  if (t < B_) {
    int b = t;
    float cnt = fmaxf(ws[WS_CNT + b], EPS_);
    float me[3];
    #pragma unroll
    for (int i = 0; i < 3; i++) { me[i] = ws[WS_MUS + b * 3 + i] / cnt; ws[WS_MEAN + b * 3 + i] = me[i]; }
    const int dg[3] = {0, 3, 5};
    #pragma unroll
    for (int i = 0; i < 3; i++) {
      float cov = ws[WS_MOS + b * 6 + dg[i]] / cnt - me[i] * me[i];
      ws[WS_STD + b * 3 + i] = fmaxf(sqrtf(fmaxf(cov, EPS_)), SIGF_);
    }
    #pragma unroll
    for (int i = 0; i < 3; i++)
      #pragma unroll
      for (int j = 0; j < 3; j++)
        ws[WS_SIGAVG + b * 9 + i * 3 + j] =
            0.5f * (ws[WS_SGS + b * 9 + i * 3 + j] + ws[WS_SGS + b * 9 + j * 3 + i]) / cnt;
  }
}

// ---- gating q vector: qv[b,t] = normalize(ssum[b,:] @ gW.T)[t] ----
__global__ __launch_bounds__(256) void k_qv(const float* __restrict__ ws_ssum,
    const float* __restrict__ gW, float* __restrict__ qv_o) {
  int b = blockIdx.x, t = threadIdx.x;
  __shared__ float sb[C_];
  __shared__ float rv[256];
  sb[t] = ws_ssum[b * C_ + t];
  __syncthreads();
  const float4* g4 = (const float4*)(gW + (size_t)t * C_);
  float qr = 0.f;
  #pragma unroll 4
  for (int c4 = 0; c4 < 64; c4++) {
    float4 g = g4[c4];
    qr += sb[c4 * 4] * g.x + sb[c4 * 4 + 1] * g.y + sb[c4 * 4 + 2] * g.z + sb[c4 * 4 + 3] * g.w;
  }
  float n2 = blk_red(qr * qr, rv, t);
  qv_o[b * C_ + t] = qr / fmaxf(sqrtf(n2), 1e-12f);
}

// ---- scores: sc[b,j] = qv[b]·pool[j] / ||pool[j]|| ; 4 threads per row ----
__global__ __launch_bounds__(256) void k_score(const float* __restrict__ qv,
    const float* __restrict__ pool, float* __restrict__ score) {
  int blk = blockIdx.x; int b = blk >> 4; int pc = blk & 15;
  int t = threadIdx.x; int row = pc * 64 + (t >> 2); int q = t & 3;
  __shared__ float qs[C_];
  qs[t] = qv[b * C_ + t];
  __syncthreads();
  const float4* p4 = (const float4*)(pool + (size_t)row * C_ + q * 64);
  float d = 0.f, p2 = 0.f;
  #pragma unroll
  for (int i = 0; i < 16; i++) {
    float4 pv = p4[i];
    int c = q * 64 + i * 4;
    d += qs[c] * pv.x + qs[c + 1] * pv.y + qs[c + 2] * pv.z + qs[c + 3] * pv.w;
    p2 += pv.x * pv.x + pv.y * pv.y + pv.z * pv.z + pv.w * pv.w;
  }
  d += __shfl_xor(d, 1); d += __shfl_xor(d, 2);
  p2 += __shfl_xor(p2, 1); p2 += __shfl_xor(p2, 2);
  if (q == 0) score[b * KMAX_ + row] = d / fmaxf(sqrtf(p2), 1e-12f);
}

// ---- bitonic sort of (score, idx); order == jax.lax.top_k ----
__global__ __launch_bounds__(256) void k_sort(const float* __restrict__ score,
    int* __restrict__ idx_o, float* __restrict__ idxf_o) {
  int b = blockIdx.x, t = threadIdx.x;
  __shared__ float val[KMAX_]; __shared__ int id[KMAX_];
  for (int j = t; j < KMAX_; j += 256) { val[j] = score[b * KMAX_ + j]; id[j] = j; }
  __syncthreads();
  for (int kk = 2; kk <= KMAX_; kk <<= 1) {
    for (int j = kk >> 1; j > 0; j >>= 1) {
      for (int i = t; i < KMAX_; i += 256) {
        int ix = i ^ j;
        if (ix > i) {
          float va = val[i], vb = val[ix]; int ia = id[i], ib = id[ix];
          bool bBeforeA = (vb > va) || (vb == va && ib < ia);
          bool up = ((i & kk) == 0);
          if (up == bBeforeA) {
            val[i] = vb; val[ix] = va; id[i] = ib; id[ix] = ia;
          }
        }
      }
      __syncthreads();
    }
  }
  if (t < KU_) {
    idx_o[b * KU_ + t] = id[t];
    idxf_o[b * KU_ + t] = (float)id[t];
  }
}

// ---- init slots / mu_k / Sig_k ----
__global__ __launch_bounds__(256) void k_init(const int* __restrict__ idx,
    const float* __restrict__ pool, const float* __restrict__ geop,
    const float* __restrict__ ws, float* __restrict__ slots,
    float* __restrict__ mu_k, float* __restrict__ sig_k) {
  int blk = blockIdx.x; int b = blk / KU_, k = blk % KU_; int t = threadIdx.x;
  int j = idx[b * KU_ + k];
  slots[((size_t)(b * KU_ + k)) * C_ + t] = pool[(size_t)j * C_ + t];
  if (t < 3) {
    mu_k[(b * KU_ + k) * 3 + t] = ws[WS_MEAN + b * 3 + t] + geop[j * 3 + t] * (0.5f * ws[WS_STD + b * 3 + t]);
  }
  if (t < 9) {
    float v = ws[WS_SIGAVG + b * 9 + t] * 0.1f;
    if (t == 0 || t == 4 || t == 8) v += SIGF_ * SIGF_ + JIT_;
    sig_k[((size_t)(b * KU_ + k)) * 9 + t] = v;
  }
}

// ---- generic row GEMM, float4 operands, out-group tiling over blockIdx.y ----
template<int ROWS, bool HASB, bool ACC, bool GELU_, bool DIVOCC, bool LNORM>
__global__ __launch_bounds__(256) void k_gemm(const float* __restrict__ in,
    const float* __restrict__ W, const float* __restrict__ bias,
    float* __restrict__ out, int IN, int OUT,
    const float* __restrict__ occ, const float* __restrict__ lng,
    const float* __restrict__ lnb) {
  extern __shared__ float sm[];
  __shared__ float lmean[4], lrstd[4];
  int t = threadIdx.x; int r0 = blockIdx.x * ROWS;
  int C4 = IN >> 2;
  for (int i = t; i < ROWS * C4; i += 256) {
    int rr = i / C4; int r = r0 + rr;
    float4 v = ((const float4*)(in + (size_t)r * IN))[i - rr * C4];
    if (DIVOCC) {
      float scv = 1.f / fmaxf(occ[r], 1e-8f);
      v.x *= scv; v.y *= scv; v.z *= scv; v.w *= scv;
    }
    ((float4*)sm)[i] = v;
  }
  __syncthreads();
  if (LNORM) {
    int w = t >> 6, lane = t & 63;
    float x0 = sm[w * 256 + lane], x1 = sm[w * 256 + lane + 64];
    float x2 = sm[w * 256 + lane + 128], x3 = sm[w * 256 + lane + 192];
    float mean = wred(x0 + x1 + x2 + x3) * (1.f / 256.f);
    float d0 = x0 - mean, d1 = x1 - mean, d2 = x2 - mean, d3 = x3 - mean;
    float var = wred(d0 * d0 + d1 * d1 + d2 * d2 + d3 * d3) * (1.f / 256.f);
    if (lane == 0) { lmean[w] = mean; lrstd[w] = rsqrtf(var + 1e-5f); }
    __syncthreads();
    for (int i = t; i < ROWS * 256; i += 256) {
      int rr = i >> 8; int c = i & 255;
      sm[i] = (sm[i] - lmean[rr]) * lrstd[rr] * lng[c] + lnb[c];
    }
    __syncthreads();
  }
  int oc = blockIdx.y * 256 + t;
  const float4* W4 = (const float4*)(W + (size_t)oc * IN);
  const float4* sm4 = (const float4*)sm;
  float acc[ROWS];
  #pragma unroll
  for (int a = 0; a < ROWS; a++) acc[a] = 0.f;
  for (int c4 = 0; c4 < C4; c4++) {
    float4 wv = W4[c4];
    #pragma unroll
    for (int a = 0; a < ROWS; a++) {
      float4 sv = sm4[a * C4 + c4];
      acc[a] += sv.x * wv.x + sv.y * wv.y + sv.z * wv.z + sv.w * wv.w;
    }
  }
  #pragma unroll
  for (int a = 0; a < ROWS; a++) {
    int r = r0 + a;
    float v = acc[a];
    if (HASB) v += bias[oc];
    if (GELU_) v = 0.5f * v * (1.0f + erff(v * 0.70710678118654752f));
    float* po = &out[(size_t)r * OUT + oc];
    if (ACC) *po += v; else *po = v;
  }
}

// ---- fused gh-gemm + GRU update ----
__global__ __launch_bounds__(256) void k_gruf(float* __restrict__ slots,
    const float* __restrict__ whh, const float* __restrict__ bhh,
    const float* __restrict__ gi) {
  __shared__ float sm[4 * C_];
  int t = threadIdx.x; int r0 = blockIdx.x * 4;
  for (int i = t; i < 4 * (C_ >> 2); i += 256) {
    int rr = i >> 6;
    ((float4*)sm)[i] = ((const float4*)(slots + (size_t)(r0 + rr) * C_))[i & 63];
  }
  __syncthreads();
  const float4* wr4 = (const float4*)(whh + (size_t)t * C_);
  const float4* wz4 = (const float4*)(whh + (size_t)(t + 256) * C_);
  const float4* wn4 = (const float4*)(whh + (size_t)(t + 512) * C_);
  const float4* sm4 = (const float4*)sm;
  float ar[4] = {0, 0, 0, 0}, az[4] = {0, 0, 0, 0}, an[4] = {0, 0, 0, 0};
  for (int c4 = 0; c4 < 64; c4++) {
    float4 wr = wr4[c4], wz = wz4[c4], wn = wn4[c4];
    #pragma unroll
    for (int a = 0; a < 4; a++) {
      float4 sv = sm4[a * 64 + c4];
      ar[a] += sv.x * wr.x + sv.y * wr.y + sv.z * wr.z + sv.w * wr.w;
      az[a] += sv.x * wz.x + sv.y * wz.y + sv.z * wz.z + sv.w * wz.w;
      an[a] += sv.x * wn.x + sv.y * wn.y + sv.z * wn.z + sv.w * wn.w;
    }
  }
  float br = bhh[t], bz = bhh[t + 256], bn = bhh[t + 512];
  #pragma unroll
  for (int a = 0; a < 4; a++) {
    int r = r0 + a;
    const float* gir = gi + (size_t)r * 768;
    float rg = 1.f / (1.f + expf(-(gir[t] + ar[a] + br)));
    float z = 1.f / (1.f + expf(-(gir[t + 256] + az[a] + bz)));
    float ng = tanhf(gir[t + 512] + rg * (an[a] + bn));
    float h = sm[a * C_ + t];
    slots[(size_t)r * C_ + t] = (1.f - z) * ng + z * h;
  }
}

// ---- FUSED semantic-logits + geo + softmax; 8 lanes per row, logits in regs ----
#define GS_CHUNK 22
__global__ __launch_bounds__(256) void k_geosm(const float* __restrict__ ksem,
    const float* __restrict__ qsem,
    const float* __restrict__ mu,
    const float* __restrict__ Sigma, const float* __restrict__ mask,
    const float* __restrict__ mu_k, const float* __restrict__ sig_k,
    const float* __restrict__ wgeo, const float* __restrict__ gsr,
    const float* __restrict__ gbias, float* __restrict__ A) {
  int blk = blockIdx.x;
  int b = blk / (N_ / 32); int nb = blk % (N_ / 32); int t = threadIdx.x;
  int rloc = t >> 3;
  int sub = t & 7;
  int n = nb * 32 + rloc;
  __shared__ float muk[KU_ * 3], sgk[KU_ * 6];
  for (int i = t; i < KU_ * 3; i += 256) muk[i] = mu_k[(size_t)b * KU_ * 3 + i];
  for (int i = t; i < KU_ * 6; i += 256) {
    int k = i / 6, c = i % 6;
    const int map[6] = {0, 1, 2, 4, 5, 8};
    sgk[i] = sig_k[((size_t)(b * KU_ + k)) * 9 + map[c]];
  }
  __syncthreads();
  // ---- phase 1: semantic logits. Lane holds ksem[n, sub*32:(sub+1)*32] in regs.
  float4 kreg[8];
  const float4* ks4 = (const float4*)(ksem + ((size_t)(b * N_ + n)) * C_ + sub * 32);
  #pragma unroll
  for (int i = 0; i < 8; i++) kreg[i] = ks4[i];
  const float* qbase = qsem + (size_t)b * KU_ * C_ + sub * 32;
  float lv[GS_CHUNK];
  #pragma unroll
  for (int kk = 0; kk < GS_CHUNK; kk++) {
    float res = -INFINITY;
    for (int so = 0; so < 8; so++) {        // dynamic loop keeps I-cache small
      int k = so * GS_CHUNK + kk;
      if (k < KU_) {
        const float4* q4 = (const float4*)(qbase + (size_t)k * C_);
        float d0 = 0.f, d1 = 0.f, d2 = 0.f, d3 = 0.f;
        #pragma unroll
        for (int i = 0; i < 8; i += 4) {
          float4 qa = q4[i], qb = q4[i + 1], qc = q4[i + 2], qd = q4[i + 3];
          d0 += kreg[i].x * qa.x + kreg[i].y * qa.y + kreg[i].z * qa.z + kreg[i].w * qa.w;
          d1 += kreg[i + 1].x * qb.x + kreg[i + 1].y * qb.y + kreg[i + 1].z * qb.z + kreg[i + 1].w * qb.w;
          d2 += kreg[i + 2].x * qc.x + kreg[i + 2].y * qc.y + kreg[i + 2].z * qc.z + kreg[i + 2].w * qc.w;
          d3 += kreg[i + 3].x * qd.x + kreg[i + 3].y * qd.y + kreg[i + 3].z * qd.z + kreg[i + 3].w * qd.w;
        }
        float d = (d0 + d1) + (d2 + d3);
        d += __shfl_xor(d, 1); d += __shfl_xor(d, 2); d += __shfl_xor(d, 4);
        if (sub == so) res = d * 0.0625f;
      }
    }
    lv[kk] = res;
  }
  // ---- phase 2: geo term + softmax (lane owns k = sub*22 + kk)
  float ah = 0.f, bs = 0.f;
  #pragma unroll
  for (int h = 0; h < H_; h++) {
    float x = gsr[h];
    ah += fmaxf(x, 0.f) + log1pf(expf(-fabsf(x)));
    bs += gbias[h];
  }
  float wg = wgeo[0];
  float m = mask[b * N_ + n];
  const float* mun = mu + ((size_t)(b * N_ + n)) * 3;
  const float* sgn = Sigma + ((size_t)(b * N_ + n)) * 9;
  float u0 = mun[0], u1 = mun[1], u2 = mun[2];
  float g00 = sgn[0], g01 = sgn[1], g02 = sgn[2], g11 = sgn[4], g12 = sgn[5], g22 = sgn[8];
  float* Arow = A + ((size_t)(b * N_ + n)) * KU_;
  const int k0 = sub * GS_CHUNK;
  float mmax = -INFINITY;
  #pragma unroll
  for (int kk = 0; kk < GS_CHUNK; kk++) {
    int k = k0 + kk;
    float l = -INFINITY;
    if (k < KU_) {
      float d0 = u0 - muk[k * 3], d1 = u1 - muk[k * 3 + 1], d2 = u2 - muk[k * 3 + 2];
      float s00 = g00 + sgk[k * 6], s01 = g01 + sgk[k * 6 + 1], s02 = g02 + sgk[k * 6 + 2];
      float s11 = g11 + sgk[k * 6 + 3], s12 = g12 + sgk[k * 6 + 4], s22 = g22 + sgk[k * 6 + 5];
      float c00 = s11 * s22 - s12 * s12;
      float c01 = s02 * s12 - s01 * s22;
      float c02 = s01 * s12 - s02 * s11;
      float det = s00 * c00 + s01 * c01 + s02 * c02;
      float c11 = s00 * s22 - s02 * s02;
      float c12 = s01 * s02 - s00 * s12;
      float c22 = s00 * s11 - s01 * s01;
      float inv = 1.0f / det;
      float x0 = (c00 * d0 + c01 * d1 + c02 * d2) * inv;
      float x1 = (c01 * d0 + c11 * d1 + c12 * d2) * inv;
      float x2 = (c02 * d0 + c12 * d1 + c22 * d2) * inv;
      float maha = d0 * x0 + d1 * x1 + d2 * x2;
      float logdet = logf(fmaxf(det, 1e-30f));
      float G = -0.5f * (maha + logdet);
      l = lv[kk] + wg * (ah * G + bs);
      if (m < 0.5f) l = -1e9f;
    }
    lv[kk] = l;
    mmax = fmaxf(mmax, l);
  }
  mmax = fmaxf(mmax, __shfl_xor(mmax, 1));
  mmax = fmaxf(mmax, __shfl_xor(mmax, 2));
  mmax = fmaxf(mmax, __shfl_xor(mmax, 4));
  float ssum = 0.f;
  #pragma unroll
  for (int kk = 0; kk < GS_CHUNK; kk++) {
    float e = expf(lv[kk] - mmax);
    lv[kk] = e;
    ssum += e;
  }
  ssum += __shfl_xor(ssum, 1);
  ssum += __shfl_xor(ssum, 2);
  ssum += __shfl_xor(ssum, 4);
  float sc = m / ssum;
  #pragma unroll
  for (int kk = 0; kk < GS_CHUNK; kk++) {
    int k = k0 + kk;
    if (k < KU_) Arow[k] = lv[kk] * sc;
  }
}

// ---- occ/mu_k/Sig_k moments, coalesced 16-k tiles, partials per n-chunk ----
#define AC_NC 4
__global__ __launch_bounds__(256) void k_accum_part(const float* __restrict__ A,
    const float* __restrict__ mu, const float* __restrict__ Sigma,
    float* __restrict__ part) {
  int blk = blockIdx.x;
  int nc = blk & 3; int tmp = blk >> 2; int kt = tmp % 11; int b = tmp / 11;
  int t = threadIdx.x; int nn = t >> 4; int kk = t & 15;
  int k = kt * 16 + kk;
  float S[10];
  #pragma unroll
  for (int i = 0; i < 10; i++) S[i] = 0.f;
  __shared__ float rowd[16][10];
  const int NCH = N_ / AC_NC;  // 512
  for (int n0 = nc * NCH; n0 < nc * NCH + NCH; n0 += 16) {
    __syncthreads();
    if (t < 144) {
      int rr = t / 9, c = t % 9;
      int n = n0 + rr;
      float v;
      if (c < 3) v = mu[((size_t)(b * N_ + n)) * 3 + c];
      else {
        const int map[6] = {0, 1, 2, 4, 5, 8};
        v = Sigma[((size_t)(b * N_ + n)) * 9 + map[c - 3]];
      }
      rowd[rr][c] = v;
    }
    float a = (k < KU_) ? A[((size_t)(b * N_ + n0 + nn)) * KU_ + k] : 0.f;
    __syncthreads();
    float m0 = rowd[nn][0], m1 = rowd[nn][1], m2 = rowd[nn][2];
    float g0 = rowd[nn][3], g1 = rowd[nn][4], g2 = rowd[nn][5];
    float g4 = rowd[nn][6], g5 = rowd[nn][7], g8 = rowd[nn][8];
    S[0] += a; S[1] += a * m0; S[2] += a * m1; S[3] += a * m2;
    S[4] += a * (g0 + m0 * m0); S[5] += a * (g1 + m0 * m1); S[6] += a * (g2 + m0 * m2);
    S[7] += a * (g4 + m1 * m1); S[8] += a * (g5 + m1 * m2); S[9] += a * (g8 + m2 * m2);
  }
  // reduce over nn within wave (nn bits are lane bits 4,5), then across 4 waves
  #pragma unroll
  for (int i = 0; i < 10; i++) { S[i] += __shfl_xor(S[i], 16); S[i] += __shfl_xor(S[i], 32); }
  __shared__ float red[4][16][10];
  int w = t >> 6, lane = t & 63;
  if (lane < 16) {
    #pragma unroll
    for (int i = 0; i < 10; i++) red[w][lane][i] = S[i];
  }
  __syncthreads();
  if (t < 160) {
    int k2 = t / 10, i = t % 10;
    float v = red[0][k2][i] + red[1][k2][i] + red[2][k2][i] + red[3][k2][i];
    part[(((size_t)nc * B_ + b) * 176 + kt * 16 + k2) * 10 + i] = v;
  }
}

__global__ __launch_bounds__(256) void k_accum_fin(const float* __restrict__ part,
    float* __restrict__ occ, float* __restrict__ mu_k, float* __restrict__ sig_k) {
  int i = blockIdx.x * 256 + threadIdx.x;
  if (i >= B_ * KU_) return;
  int b = i / KU_, k = i % KU_;
  float p[10];
  #pragma unroll
  for (int j = 0; j < 10; j++) {
    float v = 0.f;
    #pragma unroll
    for (int nc = 0; nc < AC_NC; nc++)
      v += part[(((size_t)nc * B_ + b) * 176 + k) * 10 + j];
    p[j] = v;
  }
  float o = p[0];
  occ[b * KU_ + k] = o;
  float oc = fmaxf(o, EPS_);
  float s1x = p[1], s1y = p[2], s1z = p[3];
  float q0 = s1x / oc, q1 = s1y / oc, q2 = s1z / oc;
  mu_k[(b * KU_ + k) * 3 + 0] = q0;
  mu_k[(b * KU_ + k) * 3 + 1] = q1;
  mu_k[(b * KU_ + k) * 3 + 2] = q2;
  float v00 = (p[4] - 2.f * q0 * s1x + o * q0 * q0) / oc + JIT_;
  float v01 = (p[5] - q0 * s1y - s1x * q1 + o * q0 * q1) / oc;
  float v02 = (p[6] - q0 * s1z - s1x * q2 + o * q0 * q2) / oc;
  float v11 = (p[7] - 2.f * q1 * s1y + o * q1 * q1) / oc + JIT_;
  float v12 = (p[8] - q1 * s1z - s1y * q2 + o * q1 * q2) / oc;
  float v22 = (p[9] - 2.f * q2 * s1z + o * q2 * q2) / oc + JIT_;
  v00 = fmaxf(v00, SIGF_ * SIGF_) + JIT_;
  v11 = fmaxf(v11, SIGF_ * SIGF_) + JIT_;
  v22 = fmaxf(v22, SIGF_ * SIGF_) + JIT_;
  float* po = sig_k + ((size_t)(b * KU_ + k)) * 9;
  po[0] = v00; po[1] = v01; po[2] = v02;
  po[3] = v01; po[4] = v11; po[5] = v12;
  po[6] = v02; po[7] = v12; po[8] = v22;
}

// ---- out[b,k,c] += sum_{n in chunk} A[b,n,k] * X[b,n,c] ----
__global__ __launch_bounds__(256) void k_atn(const float* __restrict__ A,
    const float* __restrict__ X, float* __restrict__ out, int NX) {
  int blk = blockIdx.x;
  int nc = blk & 7; int tmp = blk >> 3; int kt = tmp % 11; int b = tmp / 11;
  int t = threadIdx.x; int k0 = kt * 16;
  __shared__ float Ach[64 * 16];
  float acc[16];
  #pragma unroll
  for (int j = 0; j < 16; j++) acc[j] = 0.f;
  for (int n0 = nc * 256; n0 < nc * 256 + 256; n0 += 64) {
    __syncthreads();
    for (int i = t; i < 64 * 16; i += 256) {
      int nn = i >> 4, kk = i & 15; int k = k0 + kk;
      Ach[i] = (k < KU_) ? A[((size_t)(b * N_ + n0 + nn)) * KU_ + k] : 0.f;
    }
    __syncthreads();
    if (t < NX) {
      for (int nn = 0; nn < 64; nn++) {
        float xv = X[((size_t)(b * N_ + n0 + nn)) * NX + t];
        #pragma unroll
        for (int j = 0; j < 16; j++) acc[j] += Ach[(nn << 4) + j] * xv;
      }
    }
  }
  if (t < NX) {
    #pragma unroll
    for (int j = 0; j < 16; j++) {
      int k = k0 + j;
      if (k < KU_) atomicAdd(&out[((size_t)(b * KU_ + k)) * NX + t], acc[j]);
    }
  }
}

__global__ __launch_bounds__(256) void k_hist(const int* __restrict__ idx,
    float* __restrict__ okl, float* __restrict__ oent) {
  __shared__ float hist[KMAX_];
  int t = threadIdx.x;
  for (int i = t; i < KMAX_; i += 256) hist[i] = 0.f;
  __syncthreads();
  for (int i = t; i < B_ * KU_; i += 256) atomicAdd(&hist[idx[i]], 1.0f);
  __syncthreads();
  float kl = 0.f, ent = 0.f;
  const float tot = (float)(B_ * KU_);
  for (int i = t; i < KMAX_; i += 256) {
    float pc = fmaxf(hist[i] / tot, 1e-8f);
    float lp = logf(pc);
    kl += pc * (lp + LOGKMAX_);
    ent += pc * lp;
  }
  __shared__ float red[256];
  kl = blk_red(kl, red, t); ent = blk_red(ent, red, t);
  if (t == 0) { okl[0] = kl; oent[0] = ent; }
}

__global__ __launch_bounds__(256) void k_occmse(const float* __restrict__ occ,
    float* __restrict__ out) {
  __shared__ float so[B_ * KU_];
  int t = threadIdx.x;
  for (int i = t; i < B_ * KU_; i += 256) so[i] = occ[i];
  __syncthreads();
  __shared__ float red[256];
  __shared__ float bsum[B_];
  for (int b = 0; b < B_; b++) {
    float s = 0.f;
    for (int i = t; i < KU_; i += 256) s += so[b * KU_ + i];
    s = blk_red(s, red, t);
    if (t == 0) bsum[b] = fmaxf(s, 1e-8f);
    __syncthreads();
  }
  float acc = 0.f;
  const float invK = 1.0f / (float)KU_;
  for (int i = t; i < B_ * KU_; i += 256) {
    int b = i / KU_;
    float v = so[i] / bsum[b] - invK;
    acc += v * v;
  }
  acc = blk_red(acc, red, t);
  if (t == 0) out[0] = acc / (float)(B_ * KU_);
}

// ---- collapse loss partial (diag norms computed inline) ----
__global__ __launch_bounds__(256) void k_colpart(const float* __restrict__ AtA,
    float* __restrict__ colacc) {
  int blk = blockIdx.x; int b = blk / KU_, k = blk % KU_; int t = threadIdx.x;
  float acc = 0.f;
  if (t < KU_ && t != k) {
    float dk = AtA[((size_t)(b * KU_ + k)) * KU_ + k];
    float dt = AtA[((size_t)(b * KU_ + t)) * KU_ + t];
    float v  = AtA[((size_t)(b * KU_ + k)) * KU_ + t];
    float gm = v / (fmaxf(sqrtf(dk), 1e-8f) * fmaxf(sqrtf(dt), 1e-8f));
    acc = gm * gm;
  }
  float v = wred(acc);
  __shared__ float p[4];
  if ((t & 63) == 0) p[t >> 6] = v;
  __syncthreads();
  if (t == 0) atomicAdd(colacc, p[0] + p[1] + p[2] + p[3]);
}

__global__ void k_colfin(const float* __restrict__ colacc,
    const float* __restrict__ okl, const float* __restrict__ oent,
    const float* __restrict__ oocc, float* __restrict__ ocol, float* __restrict__ otot) {
  float col = colacc[0] / (float)(B_ * KU_ * KU_);
  ocol[0] = col;
  otot[0] = 0.05f * okl[0] + 0.0f * oent[0] + 0.5f * oocc[0] + 0.1f * col;
}

extern "C" void kernel_launch(void* const* d_in, const int* in_sizes, int n_in,
                              void* d_out_v, int out_size, void* d_ws, size_t ws_size,
                              hipStream_t stream) {
  const float* s     = (const float*)d_in[0];
  const float* mu    = (const float*)d_in[1];
  const float* Sigma = (const float*)d_in[2];
  const float* mask  = (const float*)d_in[3];
  const float* pool  = (const float*)d_in[4];
  const float* geop  = (const float*)d_in[5];
  const float* gW    = (const float*)d_in[6];
  const float* qW    = (const float*)d_in[7];
  const float* kW    = (const float*)d_in[8];
  const float* wih   = (const float*)d_in[9];
  const float* whh   = (const float*)d_in[10];
  const float* bih   = (const float*)d_in[11];
  const float* bhh   = (const float*)d_in[12];
  const float* lng   = (const float*)d_in[13];
  const float* lnb   = (const float*)d_in[14];
  const float* w1    = (const float*)d_in[15];
  const float* b1    = (const float*)d_in[16];
  const float* w2    = (const float*)d_in[17];
  const float* b2    = (const float*)d_in[18];
  const float* wgeo  = (const float*)d_in[19];
  const float* gsr   = (const float*)d_in[20];
  const float* gbias = (const float*)d_in[21];

  float* out = (float*)d_out_v;
  float* A     = out + O_A;
  float* slots = out + O_SLOTS;
  float* muk   = out + O_MUK;
  float* sigk  = out + O_SIGK;
  float* idxf  = out + O_IDX;
  float* okl   = out + O_KL;
  float* oent  = out + O_ENT;
  float* oocc  = out + O_OCC;
  float* ocol  = out + O_COL;
  float* otot  = out + O_TOT;

  float* ws = (float*)d_ws;
  int*   idxi   = (int*)(ws + WS_IDXI);
  float* ksem   = ws + WS_KSEM;
  float* qsem   = ws + WS_QSEM;
  float* occ    = ws + WS_OCC;
  float* slotin = ws + WS_SLOTIN;
  float* gi     = ws + WS_GI;
  float* hid    = ws + WS_HID;
  float* ata    = ws + WS_ATA;
  float* colacc = ws + WS_COLACC;

  // stage 0
  hipMemsetAsync(ws, 0, WS_STATS_BYTES, stream);
  k_stats<<<B_ * 8, 256, 0, stream>>>(s, mu, Sigma, mask, ws);
  k_fin<<<1, 64, 0, stream>>>(ws);
  k_qv<<<B_, 256, 0, stream>>>(ws + WS_SSUM, gW, ws + WS_QV);
  k_score<<<B_ * 16, 256, 0, stream>>>(ws + WS_QV, pool, ws + WS_SCORE);
  k_sort<<<B_, 256, 0, stream>>>(ws + WS_SCORE, idxi, idxf);
  k_init<<<B_ * KU_, 256, 0, stream>>>(idxi, pool, geop, ws, slots, muk, sigk);

  // k_sem = s @ kW.T  (8192 rows)
  k_gemm<8, false, false, false, false, false><<<dim3(1024, 1), 256, 8 * C_ * 4, stream>>>(
      s, kW, nullptr, ksem, C_, C_, nullptr, nullptr, nullptr);

  for (int it = 0; it < ITERS_; ++it) {
    k_gemm<4, false, false, false, false, false><<<dim3(171, 1), 256, 4 * C_ * 4, stream>>>(
        slots, qW, nullptr, qsem, C_, C_, nullptr, nullptr, nullptr);
    k_geosm<<<B_ * (N_ / 32), 256, 0, stream>>>(ksem, qsem, mu, Sigma, mask, muk, sigk,
                                                wgeo, gsr, gbias, A);
    k_accum_part<<<B_ * 11 * AC_NC, 256, 0, stream>>>(A, mu, Sigma, ws + WS_ACPART);
    k_accum_fin<<<3, 256, 0, stream>>>(ws + WS_ACPART, occ, muk, sigk);
    hipMemsetAsync(slotin, 0, (size_t)B_ * KU_ * C_ * 4, stream);
    k_atn<<<B_ * 11 * 8, 256, 0, stream>>>(A, s, slotin, C_);
    k_gemm<4, true, false, false, true, false><<<dim3(171, 3), 256, 4 * C_ * 4, stream>>>(
        slotin, wih, bih, gi, C_, 3 * C_, occ, nullptr, nullptr);
    k_gruf<<<171, 256, 0, stream>>>(slots, whh, bhh, gi);
    k_gemm<4, true, false, true, false, true><<<dim3(171, 4), 256, 4 * C_ * 4, stream>>>(
        slots, w1, b1, hid, C_, 4 * C_, nullptr, lng, lnb);
    k_gemm<4, true, true, false, false, false><<<dim3(171, 1), 256, 4 * 1024 * 4, stream>>>(
        hid, w2, b2, slots, 4 * C_, C_, nullptr, nullptr, nullptr);
  }

  // losses
  hipMemsetAsync(ata, 0, (size_t)B_ * KU_ * KU_ * 4, stream);
  k_atn<<<B_ * 11 * 8, 256, 0, stream>>>(A, A, ata, KU_);
  k_colpart<<<B_ * KU_, 256, 0, stream>>>(ata, colacc);
  k_hist<<<1, 256, 0, stream>>>(idxi, okl, oent);
  k_occmse<<<1, 256, 0, stream>>>(occ, oocc);
  k_colfin<<<1, 1, 0, stream>>>(colacc, okl, oent, oocc, ocol, otot);
}

// Round 5
// 1015.564 us; speedup vs baseline: 1.3337x; 1.3337x over previous
//
#include <hip/hip_runtime.h>
#include <math.h>

#define B_ 4
#define N_ 2048
#define C_ 256
#define KMAX_ 1024
#define KU_ 171
#define ITERS_ 3
#define H_ 4
#define EPS_ 1e-8f
#define SIGF_ 0.03f
#define JIT_ 1e-6f
#define LOGKMAX_ 6.93147180559945f

// ---------------- workspace layout (float offsets) ----------------
#define WS_CNT 0          // 4
#define WS_MUS 4          // 12
#define WS_MOS 16         // 24
#define WS_SGS 40         // 36
#define WS_COLACC 100     // 1 (zeroed by the stats memset)
#define WS_SSUM 128       // 1024
#define WS_STATS_BYTES (1152*4)
#define WS_MEAN 1152      // 12
#define WS_STD 1164       // 12
#define WS_SIGAVG 1176    // 36
#define WS_IDXI 1216      // 684 ints (pad to 1920)
#define WS_KSEM 1920                  // B*N*C = 2097152
#define WS_QSEM (WS_KSEM+2097152)     // 175104
#define WS_OCC  (WS_QSEM+175104)      // 684 (pad 704)
#define WS_SLOTIN (WS_OCC+704)        // 175104
#define WS_GI (WS_SLOTIN+175104)      // 525312
#define WS_GH (WS_GI+525312)          // 525312 region reused:
#define WS_QV     WS_GH               //   1024
#define WS_SCORE (WS_GH+1024)         //   4096
#define WS_ACPART (WS_GH+1024+4096)   //   4*4*176*10 = 28160
#define WS_XM (WS_GH+525312)          // 175104 (unused)
#define WS_HID (WS_XM+175104)         // 700416
#define WS_ATA (WS_HID+700416)        // 116964

// ---------------- output layout (float offsets) ----------------
#define O_A 0
#define O_SLOTS 1400832
#define O_MUK   1575936
#define O_SIGK  1577988
#define O_IDX   1584144
#define O_KL    1584828
#define O_ENT   1584829
#define O_OCC   1584830
#define O_COL   1584831
#define O_TOT   1584832

__device__ __forceinline__ float wred(float v) {
  #pragma unroll
  for (int i = 32; i; i >>= 1) v += __shfl_xor(v, i);
  return v;
}

__device__ __forceinline__ float blk_red(float v, float* red, int t) {
  red[t] = v; __syncthreads();
  #pragma unroll
  for (int s = 128; s > 0; s >>= 1) {
    if (t < s) red[t] += red[t + s];
    __syncthreads();
  }
  float r = red[0]; __syncthreads();
  return r;
}

// ---- partial batch stats: wave-level reductions ----
__global__ __launch_bounds__(256) void k_stats(const float* __restrict__ s,
    const float* __restrict__ mu, const float* __restrict__ Sigma,
    const float* __restrict__ mask, float* __restrict__ ws) {
  int blk = blockIdx.x; int b = blk / 8; int nc = blk % 8; int t = threadIdx.x;
  int n = nc * 256 + t;
  float m = mask[b * N_ + n];
  const float* mun = mu + ((size_t)(b * N_ + n)) * 3;
  float m0 = mun[0], m1v = mun[1], m2 = mun[2];
  const float* sgn = Sigma + ((size_t)(b * N_ + n)) * 9;
  float sg[9];
  #pragma unroll
  for (int j = 0; j < 9; j++) sg[j] = sgn[j];
  int lane = t & 63;
  float vals[19];
  vals[0] = m; vals[1] = m * m0; vals[2] = m * m1v; vals[3] = m * m2;
  vals[4] = m * m0 * m0; vals[5] = m * m0 * m1v; vals[6] = m * m0 * m2;
  vals[7] = m * m1v * m1v; vals[8] = m * m1v * m2; vals[9] = m * m2 * m2;
  #pragma unroll
  for (int j = 0; j < 9; j++) vals[10 + j] = m * sg[j];
  #pragma unroll
  for (int j = 0; j < 19; j++) {
    float v = wred(vals[j]);
    if (lane == 0) {
      int base = (j == 0) ? WS_CNT + b : (j < 4 ? WS_MUS + b * 3 + (j - 1)
                 : (j < 10 ? WS_MOS + b * 6 + (j - 4) : WS_SGS + b * 9 + (j - 10)));
      atomicAdd(ws + base, v);
    }
  }
  const float* sb = s + ((size_t)b * N_ + nc * 256) * C_;
  const float* mk = mask + b * N_ + nc * 256;
  float sa = 0.f;
  #pragma unroll 4
  for (int nn = 0; nn < 256; nn++) sa += mk[nn] * sb[(size_t)nn * C_ + t];
  atomicAdd(ws + WS_SSUM + b * C_ + t, sa);
}

// ---- finalize mean/std/sigavg ----
__global__ __launch_bounds__(64) void k_fin(float* __restrict__ ws) {
  int t = threadIdx.x;
  if (t < B_) {
    int b = t;
    float cnt = fmaxf(ws[WS_CNT + b], EPS_);
    float me[3];
    #pragma unroll
    for (int i = 0; i < 3; i++) { me[i] = ws[WS_MUS + b * 3 + i] / cnt; ws[WS_MEAN + b * 3 + i] = me[i]; }
    const int dg[3] = {0, 3, 5};
    #pragma unroll
    for (int i = 0; i < 3; i++) {
      float cov = ws[WS_MOS + b * 6 + dg[i]] / cnt - me[i] * me[i];
      ws[WS_STD + b * 3 + i] = fmaxf(sqrtf(fmaxf(cov, EPS_)), SIGF_);
    }
    #pragma unroll
    for (int i = 0; i < 3; i++)
      #pragma unroll
      for (int j = 0; j < 3; j++)
        ws[WS_SIGAVG + b * 9 + i * 3 + j] =
            0.5f * (ws[WS_SGS + b * 9 + i * 3 + j] + ws[WS_SGS + b * 9 + j * 3 + i]) / cnt;
  }
}

// ---- gating q vector ----
__global__ __launch_bounds__(256) void k_qv(const float* __restrict__ ws_ssum,
    const float* __restrict__ gW, float* __restrict__ qv_o) {
  int b = blockIdx.x, t = threadIdx.x;
  __shared__ float sb[C_];
  __shared__ float rv[256];
  sb[t] = ws_ssum[b * C_ + t];
  __syncthreads();
  const float4* g4 = (const float4*)(gW + (size_t)t * C_);
  float qr = 0.f;
  #pragma unroll 4
  for (int c4 = 0; c4 < 64; c4++) {
    float4 g = g4[c4];
    qr += sb[c4 * 4] * g.x + sb[c4 * 4 + 1] * g.y + sb[c4 * 4 + 2] * g.z + sb[c4 * 4 + 3] * g.w;
  }
  float n2 = blk_red(qr * qr, rv, t);
  qv_o[b * C_ + t] = qr / fmaxf(sqrtf(n2), 1e-12f);
}

// ---- scores ----
__global__ __launch_bounds__(256) void k_score(const float* __restrict__ qv,
    const float* __restrict__ pool, float* __restrict__ score) {
  int blk = blockIdx.x; int b = blk >> 4; int pc = blk & 15;
  int t = threadIdx.x; int row = pc * 64 + (t >> 2); int q = t & 3;
  __shared__ float qs[C_];
  qs[t] = qv[b * C_ + t];
  __syncthreads();
  const float4* p4 = (const float4*)(pool + (size_t)row * C_ + q * 64);
  float d = 0.f, p2 = 0.f;
  #pragma unroll
  for (int i = 0; i < 16; i++) {
    float4 pv = p4[i];
    int c = q * 64 + i * 4;
    d += qs[c] * pv.x + qs[c + 1] * pv.y + qs[c + 2] * pv.z + qs[c + 3] * pv.w;
    p2 += pv.x * pv.x + pv.y * pv.y + pv.z * pv.z + pv.w * pv.w;
  }
  d += __shfl_xor(d, 1); d += __shfl_xor(d, 2);
  p2 += __shfl_xor(p2, 1); p2 += __shfl_xor(p2, 2);
  if (q == 0) score[b * KMAX_ + row] = d / fmaxf(sqrtf(p2), 1e-12f);
}

// ---- bitonic sort of (score, idx); order == jax.lax.top_k ----
__global__ __launch_bounds__(256) void k_sort(const float* __restrict__ score,
    int* __restrict__ idx_o, float* __restrict__ idxf_o) {
  int b = blockIdx.x, t = threadIdx.x;
  __shared__ float val[KMAX_]; __shared__ int id[KMAX_];
  for (int j = t; j < KMAX_; j += 256) { val[j] = score[b * KMAX_ + j]; id[j] = j; }
  __syncthreads();
  for (int kk = 2; kk <= KMAX_; kk <<= 1) {
    for (int j = kk >> 1; j > 0; j >>= 1) {
      for (int i = t; i < KMAX_; i += 256) {
        int ix = i ^ j;
        if (ix > i) {
          float va = val[i], vb = val[ix]; int ia = id[i], ib = id[ix];
          bool bBeforeA = (vb > va) || (vb == va && ib < ia);
          bool up = ((i & kk) == 0);
          if (up == bBeforeA) {
            val[i] = vb; val[ix] = va; id[i] = ib; id[ix] = ia;
          }
        }
      }
      __syncthreads();
    }
  }
  if (t < KU_) {
    idx_o[b * KU_ + t] = id[t];
    idxf_o[b * KU_ + t] = (float)id[t];
  }
}

// ---- init slots / mu_k / Sig_k ----
__global__ __launch_bounds__(256) void k_init(const int* __restrict__ idx,
    const float* __restrict__ pool, const float* __restrict__ geop,
    const float* __restrict__ ws, float* __restrict__ slots,
    float* __restrict__ mu_k, float* __restrict__ sig_k) {
  int blk = blockIdx.x; int b = blk / KU_, k = blk % KU_; int t = threadIdx.x;
  int j = idx[b * KU_ + k];
  slots[((size_t)(b * KU_ + k)) * C_ + t] = pool[(size_t)j * C_ + t];
  if (t < 3) {
    mu_k[(b * KU_ + k) * 3 + t] = ws[WS_MEAN + b * 3 + t] + geop[j * 3 + t] * (0.5f * ws[WS_STD + b * 3 + t]);
  }
  if (t < 9) {
    float v = ws[WS_SIGAVG + b * 9 + t] * 0.1f;
    if (t == 0 || t == 4 || t == 8) v += SIGF_ * SIGF_ + JIT_;
    sig_k[((size_t)(b * KU_ + k)) * 9 + t] = v;
  }
}

// ---- generic row GEMM, float4 operands, out-group tiling over blockIdx.y ----
template<int ROWS, bool HASB, bool ACC, bool GELU_, bool DIVOCC, bool LNORM>
__global__ __launch_bounds__(256) void k_gemm(const float* __restrict__ in,
    const float* __restrict__ W, const float* __restrict__ bias,
    float* __restrict__ out, int IN, int OUT,
    const float* __restrict__ occ, const float* __restrict__ lng,
    const float* __restrict__ lnb) {
  extern __shared__ float sm[];
  __shared__ float lmean[4], lrstd[4];
  int t = threadIdx.x; int r0 = blockIdx.x * ROWS;
  int C4 = IN >> 2;
  for (int i = t; i < ROWS * C4; i += 256) {
    int rr = i / C4; int r = r0 + rr;
    float4 v = ((const float4*)(in + (size_t)r * IN))[i - rr * C4];
    if (DIVOCC) {
      float scv = 1.f / fmaxf(occ[r], 1e-8f);
      v.x *= scv; v.y *= scv; v.z *= scv; v.w *= scv;
    }
    ((float4*)sm)[i] = v;
  }
  __syncthreads();
  if (LNORM) {
    int w = t >> 6, lane = t & 63;
    float x0 = sm[w * 256 + lane], x1 = sm[w * 256 + lane + 64];
    float x2 = sm[w * 256 + lane + 128], x3 = sm[w * 256 + lane + 192];
    float mean = wred(x0 + x1 + x2 + x3) * (1.f / 256.f);
    float d0 = x0 - mean, d1 = x1 - mean, d2 = x2 - mean, d3 = x3 - mean;
    float var = wred(d0 * d0 + d1 * d1 + d2 * d2 + d3 * d3) * (1.f / 256.f);
    if (lane == 0) { lmean[w] = mean; lrstd[w] = rsqrtf(var + 1e-5f); }
    __syncthreads();
    for (int i = t; i < ROWS * 256; i += 256) {
      int rr = i >> 8; int c = i & 255;
      sm[i] = (sm[i] - lmean[rr]) * lrstd[rr] * lng[c] + lnb[c];
    }
    __syncthreads();
  }
  int oc = blockIdx.y * 256 + t;
  const float4* W4 = (const float4*)(W + (size_t)oc * IN);
  const float4* sm4 = (const float4*)sm;
  float acc[ROWS];
  #pragma unroll
  for (int a = 0; a < ROWS; a++) acc[a] = 0.f;
  for (int c4 = 0; c4 < C4; c4++) {
    float4 wv = W4[c4];
    #pragma unroll
    for (int a = 0; a < ROWS; a++) {
      float4 sv = sm4[a * C4 + c4];
      acc[a] += sv.x * wv.x + sv.y * wv.y + sv.z * wv.z + sv.w * wv.w;
    }
  }
  #pragma unroll
  for (int a = 0; a < ROWS; a++) {
    int r = r0 + a;
    float v = acc[a];
    if (HASB) v += bias[oc];
    if (GELU_) v = 0.5f * v * (1.0f + erff(v * 0.70710678118654752f));
    float* po = &out[(size_t)r * OUT + oc];
    if (ACC) *po += v; else *po = v;
  }
}

// ---- fused gh-gemm + GRU update ----
__global__ __launch_bounds__(256) void k_gruf(float* __restrict__ slots,
    const float* __restrict__ whh, const float* __restrict__ bhh,
    const float* __restrict__ gi) {
  __shared__ float sm[4 * C_];
  int t = threadIdx.x; int r0 = blockIdx.x * 4;
  for (int i = t; i < 4 * (C_ >> 2); i += 256) {
    int rr = i >> 6;
    ((float4*)sm)[i] = ((const float4*)(slots + (size_t)(r0 + rr) * C_))[i & 63];
  }
  __syncthreads();
  const float4* wr4 = (const float4*)(whh + (size_t)t * C_);
  const float4* wz4 = (const float4*)(whh + (size_t)(t + 256) * C_);
  const float4* wn4 = (const float4*)(whh + (size_t)(t + 512) * C_);
  const float4* sm4 = (const float4*)sm;
  float ar[4] = {0, 0, 0, 0}, az[4] = {0, 0, 0, 0}, an[4] = {0, 0, 0, 0};
  for (int c4 = 0; c4 < 64; c4++) {
    float4 wr = wr4[c4], wz = wz4[c4], wn = wn4[c4];
    #pragma unroll
    for (int a = 0; a < 4; a++) {
      float4 sv = sm4[a * 64 + c4];
      ar[a] += sv.x * wr.x + sv.y * wr.y + sv.z * wr.z + sv.w * wr.w;
      az[a] += sv.x * wz.x + sv.y * wz.y + sv.z * wz.z + sv.w * wz.w;
      an[a] += sv.x * wn.x + sv.y * wn.y + sv.z * wn.z + sv.w * wn.w;
    }
  }
  float br = bhh[t], bz = bhh[t + 256], bn = bhh[t + 512];
  #pragma unroll
  for (int a = 0; a < 4; a++) {
    int r = r0 + a;
    const float* gir = gi + (size_t)r * 768;
    float rg = 1.f / (1.f + expf(-(gir[t] + ar[a] + br)));
    float z = 1.f / (1.f + expf(-(gir[t + 256] + az[a] + bz)));
    float ng = tanhf(gir[t + 512] + rg * (an[a] + bn));
    float h = sm[a * C_ + t];
    slots[(size_t)r * C_ + t] = (1.f - z) * ng + z * h;
  }
}

// ---- logits_sem: A[b,n,k] = dot(k_sem[b,n,:], q_sem[b,k,:]) / 16 ----
__global__ __launch_bounds__(256) void k_logits(const float* __restrict__ ksem,
    const float* __restrict__ qsem, float* __restrict__ A) {
  int blk = blockIdx.x; int b = blk / (N_ / 16); int nt = blk % (N_ / 16); int t = threadIdx.x;
  __shared__ float sm[16 * C_];
  int r0 = nt * 16;
  for (int i = t; i < 16 * (C_ >> 2); i += 256) {
    int rr = i >> 6;
    ((float4*)sm)[i] = ((const float4*)(ksem + ((size_t)(b * N_ + r0 + rr)) * C_))[i & 63];
  }
  __syncthreads();
  if (t >= KU_) return;
  const float4* q4 = (const float4*)(qsem + ((size_t)(b * KU_ + t)) * C_);
  const float4* sm4 = (const float4*)sm;
  float acc[16];
  #pragma unroll
  for (int a = 0; a < 16; a++) acc[a] = 0.f;
  for (int c4 = 0; c4 < 64; c4++) {
    float4 qv = q4[c4];
    #pragma unroll
    for (int a = 0; a < 16; a++) {
      float4 sv = sm4[a * 64 + c4];
      acc[a] += sv.x * qv.x + sv.y * qv.y + sv.z * qv.z + sv.w * qv.w;
    }
  }
  #pragma unroll
  for (int a = 0; a < 16; a++)
    A[((size_t)(b * N_ + r0 + a)) * KU_ + t] = acc[a] * 0.0625f;
}

// ---- geo term + softmax, in-place on A; 8 lanes per row ----
#define GS_CHUNK 22
__global__ __launch_bounds__(256) void k_geosm(const float* __restrict__ mu,
    const float* __restrict__ Sigma, const float* __restrict__ mask,
    const float* __restrict__ mu_k, const float* __restrict__ sig_k,
    const float* __restrict__ wgeo, const float* __restrict__ gsr,
    const float* __restrict__ gbias, float* __restrict__ A) {
  int blk = blockIdx.x;
  int b = blk / (N_ / 32); int nb = blk % (N_ / 32); int t = threadIdx.x;
  int rloc = t >> 3;
  int sub = t & 7;
  int n = nb * 32 + rloc;
  __shared__ float muk[KU_ * 3], sgk[KU_ * 6];
  for (int i = t; i < KU_ * 3; i += 256) muk[i] = mu_k[(size_t)b * KU_ * 3 + i];
  for (int i = t; i < KU_ * 6; i += 256) {
    int k = i / 6, c = i % 6;
    const int map[6] = {0, 1, 2, 4, 5, 8};
    sgk[i] = sig_k[((size_t)(b * KU_ + k)) * 9 + map[c]];
  }
  __syncthreads();
  float ah = 0.f, bs = 0.f;
  #pragma unroll
  for (int h = 0; h < H_; h++) {
    float x = gsr[h];
    ah += fmaxf(x, 0.f) + log1pf(expf(-fabsf(x)));
    bs += gbias[h];
  }
  float wg = wgeo[0];
  float m = mask[b * N_ + n];
  const float* mun = mu + ((size_t)(b * N_ + n)) * 3;
  const float* sgn = Sigma + ((size_t)(b * N_ + n)) * 9;
  float u0 = mun[0], u1 = mun[1], u2 = mun[2];
  float g00 = sgn[0], g01 = sgn[1], g02 = sgn[2], g11 = sgn[4], g12 = sgn[5], g22 = sgn[8];
  float* Arow = A + ((size_t)(b * N_ + n)) * KU_;
  const int k0 = sub * GS_CHUNK;
  float lv[GS_CHUNK];
  float mmax = -INFINITY;
  #pragma unroll
  for (int kk = 0; kk < GS_CHUNK; kk++) {
    int k = k0 + kk;
    float l = -INFINITY;
    if (k < KU_) {
      float d0 = u0 - muk[k * 3], d1 = u1 - muk[k * 3 + 1], d2 = u2 - muk[k * 3 + 2];
      float s00 = g00 + sgk[k * 6], s01 = g01 + sgk[k * 6 + 1], s02 = g02 + sgk[k * 6 + 2];
      float s11 = g11 + sgk[k * 6 + 3], s12 = g12 + sgk[k * 6 + 4], s22 = g22 + sgk[k * 6 + 5];
      float c00 = s11 * s22 - s12 * s12;
      float c01 = s02 * s12 - s01 * s22;
      float c02 = s01 * s12 - s02 * s11;
      float det = s00 * c00 + s01 * c01 + s02 * c02;
      float c11 = s00 * s22 - s02 * s02;
      float c12 = s01 * s02 - s00 * s12;
      float c22 = s00 * s11 - s01 * s01;
      float inv = 1.0f / det;
      float x0 = (c00 * d0 + c01 * d1 + c02 * d2) * inv;
      float x1 = (c01 * d0 + c11 * d1 + c12 * d2) * inv;
      float x2 = (c02 * d0 + c12 * d1 + c22 * d2) * inv;
      float maha = d0 * x0 + d1 * x1 + d2 * x2;
      float logdet = logf(fmaxf(det, 1e-30f));
      float G = -0.5f * (maha + logdet);
      l = Arow[k] + wg * (ah * G + bs);
      if (m < 0.5f) l = -1e9f;
    }
    lv[kk] = l;
    mmax = fmaxf(mmax, l);
  }
  mmax = fmaxf(mmax, __shfl_xor(mmax, 1));
  mmax = fmaxf(mmax, __shfl_xor(mmax, 2));
  mmax = fmaxf(mmax, __shfl_xor(mmax, 4));
  float ssum = 0.f;
  #pragma unroll
  for (int kk = 0; kk < GS_CHUNK; kk++) {
    float e = expf(lv[kk] - mmax);
    lv[kk] = e;
    ssum += e;
  }
  ssum += __shfl_xor(ssum, 1);
  ssum += __shfl_xor(ssum, 2);
  ssum += __shfl_xor(ssum, 4);
  float sc = m / ssum;
  #pragma unroll
  for (int kk = 0; kk < GS_CHUNK; kk++) {
    int k = k0 + kk;
    if (k < KU_) Arow[k] = lv[kk] * sc;
  }
}

// ---- occ/mu_k/Sig_k moments, coalesced 16-k tiles, partials per n-chunk ----
#define AC_NC 4
__global__ __launch_bounds__(256) void k_accum_part(const float* __restrict__ A,
    const float* __restrict__ mu, const float* __restrict__ Sigma,
    float* __restrict__ part) {
  int blk = blockIdx.x;
  int nc = blk & 3; int tmp = blk >> 2; int kt = tmp % 11; int b = tmp / 11;
  int t = threadIdx.x; int nn = t >> 4; int kk = t & 15;
  int k = kt * 16 + kk;
  float S[10];
  #pragma unroll
  for (int i = 0; i < 10; i++) S[i] = 0.f;
  __shared__ float rowd[16][10];
  const int NCH = N_ / AC_NC;  // 512
  for (int n0 = nc * NCH; n0 < nc * NCH + NCH; n0 += 16) {
    __syncthreads();
    if (t < 144) {
      int rr = t / 9, c = t % 9;
      int n = n0 + rr;
      float v;
      if (c < 3) v = mu[((size_t)(b * N_ + n)) * 3 + c];
      else {
        const int map[6] = {0, 1, 2, 4, 5, 8};
        v = Sigma[((size_t)(b * N_ + n)) * 9 + map[c - 3]];
      }
      rowd[rr][c] = v;
    }
    float a = (k < KU_) ? A[((size_t)(b * N_ + n0 + nn)) * KU_ + k] : 0.f;
    __syncthreads();
    float m0 = rowd[nn][0], m1 = rowd[nn][1], m2 = rowd[nn][2];
    float g0 = rowd[nn][3], g1 = rowd[nn][4], g2 = rowd[nn][5];
    float g4 = rowd[nn][6], g5 = rowd[nn][7], g8 = rowd[nn][8];
    S[0] += a; S[1] += a * m0; S[2] += a * m1; S[3] += a * m2;
    S[4] += a * (g0 + m0 * m0); S[5] += a * (g1 + m0 * m1); S[6] += a * (g2 + m0 * m2);
    S[7] += a * (g4 + m1 * m1); S[8] += a * (g5 + m1 * m2); S[9] += a * (g8 + m2 * m2);
  }
  #pragma unroll
  for (int i = 0; i < 10; i++) { S[i] += __shfl_xor(S[i], 16); S[i] += __shfl_xor(S[i], 32); }
  __shared__ float red[4][16][10];
  int w = t >> 6, lane = t & 63;
  if (lane < 16) {
    #pragma unroll
    for (int i = 0; i < 10; i++) red[w][lane][i] = S[i];
  }
  __syncthreads();
  if (t < 160) {
    int k2 = t / 10, i = t % 10;
    float v = red[0][k2][i] + red[1][k2][i] + red[2][k2][i] + red[3][k2][i];
    part[(((size_t)nc * B_ + b) * 176 + kt * 16 + k2) * 10 + i] = v;
  }
}

__global__ __launch_bounds__(256) void k_accum_fin(const float* __restrict__ part,
    float* __restrict__ occ, float* __restrict__ mu_k, float* __restrict__ sig_k) {
  int i = blockIdx.x * 256 + threadIdx.x;
  if (i >= B_ * KU_) return;
  int b = i / KU_, k = i % KU_;
  float p[10];
  #pragma unroll
  for (int j = 0; j < 10; j++) {
    float v = 0.f;
    #pragma unroll
    for (int nc = 0; nc < AC_NC; nc++)
      v += part[(((size_t)nc * B_ + b) * 176 + k) * 10 + j];
    p[j] = v;
  }
  float o = p[0];
  occ[b * KU_ + k] = o;
  float oc = fmaxf(o, EPS_);
  float s1x = p[1], s1y = p[2], s1z = p[3];
  float q0 = s1x / oc, q1 = s1y / oc, q2 = s1z / oc;
  mu_k[(b * KU_ + k) * 3 + 0] = q0;
  mu_k[(b * KU_ + k) * 3 + 1] = q1;
  mu_k[(b * KU_ + k) * 3 + 2] = q2;
  float v00 = (p[4] - 2.f * q0 * s1x + o * q0 * q0) / oc + JIT_;
  float v01 = (p[5] - q0 * s1y - s1x * q1 + o * q0 * q1) / oc;
  float v02 = (p[6] - q0 * s1z - s1x * q2 + o * q0 * q2) / oc;
  float v11 = (p[7] - 2.f * q1 * s1y + o * q1 * q1) / oc + JIT_;
  float v12 = (p[8] - q1 * s1z - s1y * q2 + o * q1 * q2) / oc;
  float v22 = (p[9] - 2.f * q2 * s1z + o * q2 * q2) / oc + JIT_;
  v00 = fmaxf(v00, SIGF_ * SIGF_) + JIT_;
  v11 = fmaxf(v11, SIGF_ * SIGF_) + JIT_;
  v22 = fmaxf(v22, SIGF_ * SIGF_) + JIT_;
  float* po = sig_k + ((size_t)(b * KU_ + k)) * 9;
  po[0] = v00; po[1] = v01; po[2] = v02;
  po[3] = v01; po[4] = v11; po[5] = v12;
  po[6] = v02; po[7] = v12; po[8] = v22;
}

// ---- out[b,k,c] += sum_{n in chunk} A[b,n,k] * X[b,n,c] ----
__global__ __launch_bounds__(256) void k_atn(const float* __restrict__ A,
    const float* __restrict__ X, float* __restrict__ out, int NX) {
  int blk = blockIdx.x;
  int nc = blk & 7; int tmp = blk >> 3; int kt = tmp % 11; int b = tmp / 11;
  int t = threadIdx.x; int k0 = kt * 16;
  __shared__ float Ach[64 * 16];
  float acc[16];
  #pragma unroll
  for (int j = 0; j < 16; j++) acc[j] = 0.f;
  for (int n0 = nc * 256; n0 < nc * 256 + 256; n0 += 64) {
    __syncthreads();
    for (int i = t; i < 64 * 16; i += 256) {
      int nn = i >> 4, kk = i & 15; int k = k0 + kk;
      Ach[i] = (k < KU_) ? A[((size_t)(b * N_ + n0 + nn)) * KU_ + k] : 0.f;
    }
    __syncthreads();
    if (t < NX) {
      for (int nn = 0; nn < 64; nn++) {
        float xv = X[((size_t)(b * N_ + n0 + nn)) * NX + t];
        #pragma unroll
        for (int j = 0; j < 16; j++) acc[j] += Ach[(nn << 4) + j] * xv;
      }
    }
  }
  if (t < NX) {
    #pragma unroll
    for (int j = 0; j < 16; j++) {
      int k = k0 + j;
      if (k < KU_) atomicAdd(&out[((size_t)(b * KU_ + k)) * NX + t], acc[j]);
    }
  }
}

__global__ __launch_bounds__(256) void k_hist(const int* __restrict__ idx,
    float* __restrict__ okl, float* __restrict__ oent) {
  __shared__ float hist[KMAX_];
  int t = threadIdx.x;
  for (int i = t; i < KMAX_; i += 256) hist[i] = 0.f;
  __syncthreads();
  for (int i = t; i < B_ * KU_; i += 256) atomicAdd(&hist[idx[i]], 1.0f);
  __syncthreads();
  float kl = 0.f, ent = 0.f;
  const float tot = (float)(B_ * KU_);
  for (int i = t; i < KMAX_; i += 256) {
    float pc = fmaxf(hist[i] / tot, 1e-8f);
    float lp = logf(pc);
    kl += pc * (lp + LOGKMAX_);
    ent += pc * lp;
  }
  __shared__ float red[256];
  kl = blk_red(kl, red, t); ent = blk_red(ent, red, t);
  if (t == 0) { okl[0] = kl; oent[0] = ent; }
}

__global__ __launch_bounds__(256) void k_occmse(const float* __restrict__ occ,
    float* __restrict__ out) {
  __shared__ float so[B_ * KU_];
  int t = threadIdx.x;
  for (int i = t; i < B_ * KU_; i += 256) so[i] = occ[i];
  __syncthreads();
  __shared__ float red[256];
  __shared__ float bsum[B_];
  for (int b = 0; b < B_; b++) {
    float s = 0.f;
    for (int i = t; i < KU_; i += 256) s += so[b * KU_ + i];
    s = blk_red(s, red, t);
    if (t == 0) bsum[b] = fmaxf(s, 1e-8f);
    __syncthreads();
  }
  float acc = 0.f;
  const float invK = 1.0f / (float)KU_;
  for (int i = t; i < B_ * KU_; i += 256) {
    int b = i / KU_;
    float v = so[i] / bsum[b] - invK;
    acc += v * v;
  }
  acc = blk_red(acc, red, t);
  if (t == 0) out[0] = acc / (float)(B_ * KU_);
}

// ---- collapse loss partial ----
__global__ __launch_bounds__(256) void k_colpart(const float* __restrict__ AtA,
    float* __restrict__ colacc) {
  int blk = blockIdx.x; int b = blk / KU_, k = blk % KU_; int t = threadIdx.x;
  float acc = 0.f;
  if (t < KU_ && t != k) {
    float dk = AtA[((size_t)(b * KU_ + k)) * KU_ + k];
    float dt = AtA[((size_t)(b * KU_ + t)) * KU_ + t];
    float v  = AtA[((size_t)(b * KU_ + k)) * KU_ + t];
    float gm = v / (fmaxf(sqrtf(dk), 1e-8f) * fmaxf(sqrtf(dt), 1e-8f));
    acc = gm * gm;
  }
  float v = wred(acc);
  __shared__ float p[4];
  if ((t & 63) == 0) p[t >> 6] = v;
  __syncthreads();
  if (t == 0) atomicAdd(colacc, p[0] + p[1] + p[2] + p[3]);
}

__global__ void k_colfin(const float* __restrict__ colacc,
    const float* __restrict__ okl, const float* __restrict__ oent,
    const float* __restrict__ oocc, float* __restrict__ ocol, float* __restrict__ otot) {
  float col = colacc[0] / (float)(B_ * KU_ * KU_);
  ocol[0] = col;
  otot[0] = 0.05f * okl[0] + 0.0f * oent[0] + 0.5f * oocc[0] + 0.1f * col;
}

extern "C" void kernel_launch(void* const* d_in, const int* in_sizes, int n_in,
                              void* d_out_v, int out_size, void* d_ws, size_t ws_size,
                              hipStream_t stream) {
  const float* s     = (const float*)d_in[0];
  const float* mu    = (const float*)d_in[1];
  const float* Sigma = (const float*)d_in[2];
  const float* mask  = (const float*)d_in[3];
  const float* pool  = (const float*)d_in[4];
  const float* geop  = (const float*)d_in[5];
  const float* gW    = (const float*)d_in[6];
  const float* qW    = (const float*)d_in[7];
  const float* kW    = (const float*)d_in[8];
  const float* wih   = (const float*)d_in[9];
  const float* whh   = (const float*)d_in[10];
  const float* bih   = (const float*)d_in[11];
  const float* bhh   = (const float*)d_in[12];
  const float* lng   = (const float*)d_in[13];
  const float* lnb   = (const float*)d_in[14];
  const float* w1    = (const float*)d_in[15];
  const float* b1    = (const float*)d_in[16];
  const float* w2    = (const float*)d_in[17];
  const float* b2    = (const float*)d_in[18];
  const float* wgeo  = (const float*)d_in[19];
  const float* gsr   = (const float*)d_in[20];
  const float* gbias = (const float*)d_in[21];

  float* out = (float*)d_out_v;
  float* A     = out + O_A;
  float* slots = out + O_SLOTS;
  float* muk   = out + O_MUK;
  float* sigk  = out + O_SIGK;
  float* idxf  = out + O_IDX;
  float* okl   = out + O_KL;
  float* oent  = out + O_ENT;
  float* oocc  = out + O_OCC;
  float* ocol  = out + O_COL;
  float* otot  = out + O_TOT;

  float* ws = (float*)d_ws;
  int*   idxi   = (int*)(ws + WS_IDXI);
  float* ksem   = ws + WS_KSEM;
  float* qsem   = ws + WS_QSEM;
  float* occ    = ws + WS_OCC;
  float* slotin = ws + WS_SLOTIN;
  float* gi     = ws + WS_GI;
  float* hid    = ws + WS_HID;
  float* ata    = ws + WS_ATA;
  float* colacc = ws + WS_COLACC;

  // stage 0
  hipMemsetAsync(ws, 0, WS_STATS_BYTES, stream);
  k_stats<<<B_ * 8, 256, 0, stream>>>(s, mu, Sigma, mask, ws);
  k_fin<<<1, 64, 0, stream>>>(ws);
  k_qv<<<B_, 256, 0, stream>>>(ws + WS_SSUM, gW, ws + WS_QV);
  k_score<<<B_ * 16, 256, 0, stream>>>(ws + WS_QV, pool, ws + WS_SCORE);
  k_sort<<<B_, 256, 0, stream>>>(ws + WS_SCORE, idxi, idxf);
  k_init<<<B_ * KU_, 256, 0, stream>>>(idxi, pool, geop, ws, slots, muk, sigk);

  // k_sem = s @ kW.T  (8192 rows)
  k_gemm<8, false, false, false, false, false><<<dim3(1024, 1), 256, 8 * C_ * 4, stream>>>(
      s, kW, nullptr, ksem, C_, C_, nullptr, nullptr, nullptr);

  for (int it = 0; it < ITERS_; ++it) {
    k_gemm<4, false, false, false, false, false><<<dim3(171, 1), 256, 4 * C_ * 4, stream>>>(
        slots, qW, nullptr, qsem, C_, C_, nullptr, nullptr, nullptr);
    k_logits<<<B_ * (N_ / 16), 256, 0, stream>>>(ksem, qsem, A);
    k_geosm<<<B_ * (N_ / 32), 256, 0, stream>>>(mu, Sigma, mask, muk, sigk,
                                                wgeo, gsr, gbias, A);
    k_accum_part<<<B_ * 11 * AC_NC, 256, 0, stream>>>(A, mu, Sigma, ws + WS_ACPART);
    k_accum_fin<<<3, 256, 0, stream>>>(ws + WS_ACPART, occ, muk, sigk);
    hipMemsetAsync(slotin, 0, (size_t)B_ * KU_ * C_ * 4, stream);
    k_atn<<<B_ * 11 * 8, 256, 0, stream>>>(A, s, slotin, C_);
    k_gemm<4, true, false, false, true, false><<<dim3(171, 3), 256, 4 * C_ * 4, stream>>>(
        slotin, wih, bih, gi, C_, 3 * C_, occ, nullptr, nullptr);
    k_gruf<<<171, 256, 0, stream>>>(slots, whh, bhh, gi);
    k_gemm<4, true, false, true, false, true><<<dim3(171, 4), 256, 4 * C_ * 4, stream>>>(
        slots, w1, b1, hid, C_, 4 * C_, nullptr, lng, lnb);
    k_gemm<4, true, true, false, false, false><<<dim3(171, 1), 256, 4 * 1024 * 4, stream>>>(
        hid, w2, b2, slots, 4 * C_, C_, nullptr, nullptr, nullptr);
  }

  // losses
  hipMemsetAsync(ata, 0, (size_t)B_ * KU_ * KU_ * 4, stream);
  k_atn<<<B_ * 11 * 8, 256, 0, stream>>>(A, A, ata, KU_);
  k_colpart<<<B_ * KU_, 256, 0, stream>>>(ata, colacc);
  k_hist<<<1, 256, 0, stream>>>(idxi, okl, oent);
  k_occmse<<<1, 256, 0, stream>>>(occ, oocc);
  k_colfin<<<1, 1, 0, stream>>>(colacc, okl, oent, oocc, ocol, otot);
}

// Round 6
// 967.824 us; speedup vs baseline: 1.3994x; 1.0493x over previous
//
#include <hip/hip_runtime.h>
#include <math.h>

#define B_ 4
#define N_ 2048
#define C_ 256
#define KMAX_ 1024
#define KU_ 171
#define ITERS_ 3
#define H_ 4
#define EPS_ 1e-8f
#define SIGF_ 0.03f
#define JIT_ 1e-6f
#define LOGKMAX_ 6.93147180559945f

// ---------------- workspace layout (float offsets) ----------------
#define WS_CNT 0
#define WS_MUS 4
#define WS_MOS 16
#define WS_SGS 40
#define WS_COLACC 100
#define WS_SSUM 128
#define WS_STATS_BYTES (1152*4)
#define WS_MEAN 1152
#define WS_STD 1164
#define WS_SIGAVG 1176
#define WS_IDXI 1216
#define WS_KSEM 1920                   // B*N*C = 2097152
#define WS_QSEM (WS_KSEM+2097152)      // 175104
#define WS_OCC  (WS_QSEM+175104)       // 704
#define WS_PART (WS_OCC+704)           // 8*684*256 = 1400832 (atn partials)
#define WS_TAIL (WS_PART+1400832)      // == 3675712
#define WS_QV     WS_TAIL              // 1024
#define WS_SCORE (WS_TAIL+1024)        // 4096
#define WS_ACPART (WS_TAIL+8192)       // 28160
#define WS_ATA (WS_TAIL+700416)        // 116964

// ---------------- output layout (float offsets) ----------------
#define O_A 0
#define O_SLOTS 1400832
#define O_MUK   1575936
#define O_SIGK  1577988
#define O_IDX   1584144
#define O_KL    1584828
#define O_ENT   1584829
#define O_OCC   1584830
#define O_COL   1584831
#define O_TOT   1584832

__device__ __forceinline__ float wred(float v) {
  #pragma unroll
  for (int i = 32; i; i >>= 1) v += __shfl_xor(v, i);
  return v;
}
__device__ __forceinline__ float wmax(float v) {
  #pragma unroll
  for (int i = 32; i; i >>= 1) v = fmaxf(v, __shfl_xor(v, i));
  return v;
}

__device__ __forceinline__ float blk_red(float v, float* red, int t) {
  red[t] = v; __syncthreads();
  #pragma unroll
  for (int s = 128; s > 0; s >>= 1) {
    if (t < s) red[t] += red[t + s];
    __syncthreads();
  }
  float r = red[0]; __syncthreads();
  return r;
}

// ---- partial batch stats ----
__global__ __launch_bounds__(256) void k_stats(const float* __restrict__ s,
    const float* __restrict__ mu, const float* __restrict__ Sigma,
    const float* __restrict__ mask, float* __restrict__ ws) {
  int blk = blockIdx.x; int b = blk / 8; int nc = blk % 8; int t = threadIdx.x;
  int n = nc * 256 + t;
  float m = mask[b * N_ + n];
  const float* mun = mu + ((size_t)(b * N_ + n)) * 3;
  float m0 = mun[0], m1v = mun[1], m2 = mun[2];
  const float* sgn = Sigma + ((size_t)(b * N_ + n)) * 9;
  float sg[9];
  #pragma unroll
  for (int j = 0; j < 9; j++) sg[j] = sgn[j];
  int lane = t & 63;
  float vals[19];
  vals[0] = m; vals[1] = m * m0; vals[2] = m * m1v; vals[3] = m * m2;
  vals[4] = m * m0 * m0; vals[5] = m * m0 * m1v; vals[6] = m * m0 * m2;
  vals[7] = m * m1v * m1v; vals[8] = m * m1v * m2; vals[9] = m * m2 * m2;
  #pragma unroll
  for (int j = 0; j < 9; j++) vals[10 + j] = m * sg[j];
  #pragma unroll
  for (int j = 0; j < 19; j++) {
    float v = wred(vals[j]);
    if (lane == 0) {
      int base = (j == 0) ? WS_CNT + b : (j < 4 ? WS_MUS + b * 3 + (j - 1)
                 : (j < 10 ? WS_MOS + b * 6 + (j - 4) : WS_SGS + b * 9 + (j - 10)));
      atomicAdd(ws + base, v);
    }
  }
  const float* sb = s + ((size_t)b * N_ + nc * 256) * C_;
  const float* mk = mask + b * N_ + nc * 256;
  float sa = 0.f;
  #pragma unroll 4
  for (int nn = 0; nn < 256; nn++) sa += mk[nn] * sb[(size_t)nn * C_ + t];
  atomicAdd(ws + WS_SSUM + b * C_ + t, sa);
}

// ---- finalize mean/std/sigavg ----
__global__ __launch_bounds__(64) void k_fin(float* __restrict__ ws) {
  int t = threadIdx.x;
  if (t < B_) {
    int b = t;
    float cnt = fmaxf(ws[WS_CNT + b], EPS_);
    float me[3];
    #pragma unroll
    for (int i = 0; i < 3; i++) { me[i] = ws[WS_MUS + b * 3 + i] / cnt; ws[WS_MEAN + b * 3 + i] = me[i]; }
    const int dg[3] = {0, 3, 5};
    #pragma unroll
    for (int i = 0; i < 3; i++) {
      float cov = ws[WS_MOS + b * 6 + dg[i]] / cnt - me[i] * me[i];
      ws[WS_STD + b * 3 + i] = fmaxf(sqrtf(fmaxf(cov, EPS_)), SIGF_);
    }
    #pragma unroll
    for (int i = 0; i < 3; i++)
      #pragma unroll
      for (int j = 0; j < 3; j++)
        ws[WS_SIGAVG + b * 9 + i * 3 + j] =
            0.5f * (ws[WS_SGS + b * 9 + i * 3 + j] + ws[WS_SGS + b * 9 + j * 3 + i]) / cnt;
  }
}

// ---- gating q vector ----
__global__ __launch_bounds__(256) void k_qv(const float* __restrict__ ws_ssum,
    const float* __restrict__ gW, float* __restrict__ qv_o) {
  int b = blockIdx.x, t = threadIdx.x;
  __shared__ float sb[C_];
  __shared__ float rv[256];
  sb[t] = ws_ssum[b * C_ + t];
  __syncthreads();
  const float4* g4 = (const float4*)(gW + (size_t)t * C_);
  float qr = 0.f;
  #pragma unroll 4
  for (int c4 = 0; c4 < 64; c4++) {
    float4 g = g4[c4];
    qr += sb[c4 * 4] * g.x + sb[c4 * 4 + 1] * g.y + sb[c4 * 4 + 2] * g.z + sb[c4 * 4 + 3] * g.w;
  }
  float n2 = blk_red(qr * qr, rv, t);
  qv_o[b * C_ + t] = qr / fmaxf(sqrtf(n2), 1e-12f);
}

// ---- scores ----
__global__ __launch_bounds__(256) void k_score(const float* __restrict__ qv,
    const float* __restrict__ pool, float* __restrict__ score) {
  int blk = blockIdx.x; int b = blk >> 4; int pc = blk & 15;
  int t = threadIdx.x; int row = pc * 64 + (t >> 2); int q = t & 3;
  __shared__ float qs[C_];
  qs[t] = qv[b * C_ + t];
  __syncthreads();
  const float4* p4 = (const float4*)(pool + (size_t)row * C_ + q * 64);
  float d = 0.f, p2 = 0.f;
  #pragma unroll
  for (int i = 0; i < 16; i++) {
    float4 pv = p4[i];
    int c = q * 64 + i * 4;
    d += qs[c] * pv.x + qs[c + 1] * pv.y + qs[c + 2] * pv.z + qs[c + 3] * pv.w;
    p2 += pv.x * pv.x + pv.y * pv.y + pv.z * pv.z + pv.w * pv.w;
  }
  d += __shfl_xor(d, 1); d += __shfl_xor(d, 2);
  p2 += __shfl_xor(p2, 1); p2 += __shfl_xor(p2, 2);
  if (q == 0) score[b * KMAX_ + row] = d / fmaxf(sqrtf(p2), 1e-12f);
}

// ---- bitonic sort; order == jax.lax.top_k ----
__global__ __launch_bounds__(256) void k_sort(const float* __restrict__ score,
    int* __restrict__ idx_o, float* __restrict__ idxf_o) {
  int b = blockIdx.x, t = threadIdx.x;
  __shared__ float val[KMAX_]; __shared__ int id[KMAX_];
  for (int j = t; j < KMAX_; j += 256) { val[j] = score[b * KMAX_ + j]; id[j] = j; }
  __syncthreads();
  for (int kk = 2; kk <= KMAX_; kk <<= 1) {
    for (int j = kk >> 1; j > 0; j >>= 1) {
      for (int i = t; i < KMAX_; i += 256) {
        int ix = i ^ j;
        if (ix > i) {
          float va = val[i], vb = val[ix]; int ia = id[i], ib = id[ix];
          bool bBeforeA = (vb > va) || (vb == va && ib < ia);
          bool up = ((i & kk) == 0);
          if (up == bBeforeA) {
            val[i] = vb; val[ix] = va; id[i] = ib; id[ix] = ia;
          }
        }
      }
      __syncthreads();
    }
  }
  if (t < KU_) {
    idx_o[b * KU_ + t] = id[t];
    idxf_o[b * KU_ + t] = (float)id[t];
  }
}

// ---- init slots / mu_k / Sig_k ----
__global__ __launch_bounds__(256) void k_init(const int* __restrict__ idx,
    const float* __restrict__ pool, const float* __restrict__ geop,
    const float* __restrict__ ws, float* __restrict__ slots,
    float* __restrict__ mu_k, float* __restrict__ sig_k) {
  int blk = blockIdx.x; int b = blk / KU_, k = blk % KU_; int t = threadIdx.x;
  int j = idx[b * KU_ + k];
  slots[((size_t)(b * KU_ + k)) * C_ + t] = pool[(size_t)j * C_ + t];
  if (t < 3) {
    mu_k[(b * KU_ + k) * 3 + t] = ws[WS_MEAN + b * 3 + t] + geop[j * 3 + t] * (0.5f * ws[WS_STD + b * 3 + t]);
  }
  if (t < 9) {
    float v = ws[WS_SIGAVG + b * 9 + t] * 0.1f;
    if (t == 0 || t == 4 || t == 8) v += SIGF_ * SIGF_ + JIT_;
    sig_k[((size_t)(b * KU_ + k)) * 9 + t] = v;
  }
}

// ---- plain row GEMM: out[r,t] = dot(in[r,:], W[t,:]) ----
template<int ROWS>
__global__ __launch_bounds__(256) void k_gemm_plain(const float* __restrict__ in,
    const float* __restrict__ W, float* __restrict__ out, int IN, int OUT, float scale) {
  extern __shared__ float sm[];
  int t = threadIdx.x; int r0 = blockIdx.x * ROWS;
  int C4 = IN >> 2;
  for (int i = t; i < ROWS * C4; i += 256) {
    int rr = i / C4;
    ((float4*)sm)[i] = ((const float4*)(in + (size_t)(r0 + rr) * IN))[i - rr * C4];
  }
  __syncthreads();
  const float4* W4 = (const float4*)(W + (size_t)t * IN);
  const float4* sm4 = (const float4*)sm;
  float acc[ROWS];
  #pragma unroll
  for (int a = 0; a < ROWS; a++) acc[a] = 0.f;
  for (int c4 = 0; c4 < C4; c4++) {
    float4 wv = W4[c4];
    #pragma unroll
    for (int a = 0; a < ROWS; a++) {
      float4 sv = sm4[a * C4 + c4];
      acc[a] += sv.x * wv.x + sv.y * wv.y + sv.z * wv.z + sv.w * wv.w;
    }
  }
  #pragma unroll
  for (int a = 0; a < ROWS; a++)
    out[(size_t)(r0 + a) * OUT + t] = acc[a] * scale;
}

// ---- FUSED logits + geo + softmax (k_logits-style staging preserved) ----
__global__ __launch_bounds__(256) void k_lgsm(const float* __restrict__ ksem,
    const float* __restrict__ qsem, const float* __restrict__ mu,
    const float* __restrict__ Sigma, const float* __restrict__ mask,
    const float* __restrict__ mu_k, const float* __restrict__ sig_k,
    const float* __restrict__ wgeo, const float* __restrict__ gsr,
    const float* __restrict__ gbias, float* __restrict__ A) {
  __shared__ float ksm[16 * C_];
  __shared__ float Asm[16][172];
  __shared__ float muk[KU_ * 3];
  __shared__ float sgk[KU_ * 6];
  __shared__ float rowd[16][10];
  int blk = blockIdx.x; int b = blk / (N_ / 16); int nt = blk % (N_ / 16);
  int t = threadIdx.x; int r0 = nt * 16;
  // stage ksem tile
  for (int i = t; i < 16 * (C_ >> 2); i += 256) {
    int rr = i >> 6;
    ((float4*)ksm)[i] = ((const float4*)(ksem + ((size_t)(b * N_ + r0 + rr)) * C_))[i & 63];
  }
  // stage muk / sgk
  for (int i = t; i < KU_ * 3; i += 256) muk[i] = mu_k[(size_t)b * KU_ * 3 + i];
  for (int i = t; i < KU_ * 6; i += 256) {
    int k = i / 6, c = i % 6;
    const int map[6] = {0, 1, 2, 4, 5, 8};
    sgk[i] = sig_k[((size_t)(b * KU_ + k)) * 9 + map[c]];
  }
  // stage per-row data: mask, mu(3), sig6
  if (t < 160) {
    int rr = t / 10, c = t % 10;
    int n = r0 + rr;
    float v;
    if (c == 0) v = mask[b * N_ + n];
    else if (c < 4) v = mu[((size_t)(b * N_ + n)) * 3 + (c - 1)];
    else {
      const int map[6] = {0, 1, 2, 4, 5, 8};
      v = Sigma[((size_t)(b * N_ + n)) * 9 + map[c - 4]];
    }
    rowd[rr][c] = v;
  }
  __syncthreads();
  // phase 1: semantic logits (thread t owns slot k=t)
  if (t < KU_) {
    const float4* q4 = (const float4*)(qsem + ((size_t)(b * KU_ + t)) * C_);
    const float4* sm4 = (const float4*)ksm;
    float acc[16];
    #pragma unroll
    for (int a = 0; a < 16; a++) acc[a] = 0.f;
    for (int c4 = 0; c4 < 64; c4++) {
      float4 qv = q4[c4];
      #pragma unroll
      for (int a = 0; a < 16; a++) {
        float4 sv = sm4[a * 64 + c4];
        acc[a] += sv.x * qv.x + sv.y * qv.y + sv.z * qv.z + sv.w * qv.w;
      }
    }
    // phase 2: + geo term (same k=t, loop rows)
    float ah = 0.f, bs = 0.f;
    #pragma unroll
    for (int h = 0; h < H_; h++) {
      float x = gsr[h];
      ah += fmaxf(x, 0.f) + log1pf(expf(-fabsf(x)));
      bs += gbias[h];
    }
    float wg = wgeo[0];
    float mk0 = muk[t * 3], mk1 = muk[t * 3 + 1], mk2 = muk[t * 3 + 2];
    float k00 = sgk[t * 6], k01 = sgk[t * 6 + 1], k02 = sgk[t * 6 + 2];
    float k11 = sgk[t * 6 + 3], k12 = sgk[t * 6 + 4], k22 = sgk[t * 6 + 5];
    #pragma unroll
    for (int a = 0; a < 16; a++) {
      float m = rowd[a][0];
      float d0 = rowd[a][1] - mk0, d1 = rowd[a][2] - mk1, d2 = rowd[a][3] - mk2;
      float s00 = rowd[a][4] + k00, s01 = rowd[a][5] + k01, s02 = rowd[a][6] + k02;
      float s11 = rowd[a][7] + k11, s12 = rowd[a][8] + k12, s22 = rowd[a][9] + k22;
      float c00 = s11 * s22 - s12 * s12;
      float c01 = s02 * s12 - s01 * s22;
      float c02 = s01 * s12 - s02 * s11;
      float det = s00 * c00 + s01 * c01 + s02 * c02;
      float c11 = s00 * s22 - s02 * s02;
      float c12 = s01 * s02 - s00 * s12;
      float c22 = s00 * s11 - s01 * s01;
      float inv = 1.0f / det;
      float x0 = (c00 * d0 + c01 * d1 + c02 * d2) * inv;
      float x1 = (c01 * d0 + c11 * d1 + c12 * d2) * inv;
      float x2 = (c02 * d0 + c12 * d1 + c22 * d2) * inv;
      float maha = d0 * x0 + d1 * x1 + d2 * x2;
      float logdet = logf(fmaxf(det, 1e-30f));
      float G = -0.5f * (maha + logdet);
      float l = acc[a] * 0.0625f + wg * (ah * G + bs);
      if (m < 0.5f) l = -1e9f;
      Asm[a][t] = l;
    }
  }
  __syncthreads();
  // phase 3: row softmax, warp w handles rows 4w..4w+3
  int w = t >> 6, lane = t & 63;
  #pragma unroll
  for (int q = 0; q < 4; q++) {
    int a = w * 4 + q;
    float v0 = (lane < KU_) ? Asm[a][lane] : -INFINITY;
    float v1 = (lane + 64 < KU_) ? Asm[a][lane + 64] : -INFINITY;
    float v2 = (lane + 128 < KU_) ? Asm[a][lane + 128] : -INFINITY;
    float mx = wmax(fmaxf(v0, fmaxf(v1, v2)));
    float e0 = (lane < KU_) ? expf(v0 - mx) : 0.f;
    float e1 = (lane + 64 < KU_) ? expf(v1 - mx) : 0.f;
    float e2 = (lane + 128 < KU_) ? expf(v2 - mx) : 0.f;
    float ss = wred(e0 + e1 + e2);
    float scale = rowd[a][0] / ss;
    if (lane < KU_) Asm[a][lane] = e0 * scale;
    if (lane + 64 < KU_) Asm[a][lane + 64] = e1 * scale;
    if (lane + 128 < KU_) Asm[a][lane + 128] = e2 * scale;
  }
  __syncthreads();
  // phase 4: write A
  for (int i = t; i < 16 * KU_; i += 256) {
    int a = i / KU_, k = i - a * KU_;
    A[((size_t)(b * N_ + r0 + a)) * KU_ + k] = Asm[a][k];
  }
}

// ---- occ/mu_k/Sig_k moments ----
#define AC_NC 4
__global__ __launch_bounds__(256) void k_accum_part(const float* __restrict__ A,
    const float* __restrict__ mu, const float* __restrict__ Sigma,
    float* __restrict__ part) {
  int blk = blockIdx.x;
  int nc = blk & 3; int tmp = blk >> 2; int kt = tmp % 11; int b = tmp / 11;
  int t = threadIdx.x; int nn = t >> 4; int kk = t & 15;
  int k = kt * 16 + kk;
  float S[10];
  #pragma unroll
  for (int i = 0; i < 10; i++) S[i] = 0.f;
  __shared__ float rowd[16][10];
  const int NCH = N_ / AC_NC;
  for (int n0 = nc * NCH; n0 < nc * NCH + NCH; n0 += 16) {
    __syncthreads();
    if (t < 144) {
      int rr = t / 9, c = t % 9;
      int n = n0 + rr;
      float v;
      if (c < 3) v = mu[((size_t)(b * N_ + n)) * 3 + c];
      else {
        const int map[6] = {0, 1, 2, 4, 5, 8};
        v = Sigma[((size_t)(b * N_ + n)) * 9 + map[c - 3]];
      }
      rowd[rr][c] = v;
    }
    float a = (k < KU_) ? A[((size_t)(b * N_ + n0 + nn)) * KU_ + k] : 0.f;
    __syncthreads();
    float m0 = rowd[nn][0], m1 = rowd[nn][1], m2 = rowd[nn][2];
    float g0 = rowd[nn][3], g1 = rowd[nn][4], g2 = rowd[nn][5];
    float g4 = rowd[nn][6], g5 = rowd[nn][7], g8 = rowd[nn][8];
    S[0] += a; S[1] += a * m0; S[2] += a * m1; S[3] += a * m2;
    S[4] += a * (g0 + m0 * m0); S[5] += a * (g1 + m0 * m1); S[6] += a * (g2 + m0 * m2);
    S[7] += a * (g4 + m1 * m1); S[8] += a * (g5 + m1 * m2); S[9] += a * (g8 + m2 * m2);
  }
  #pragma unroll
  for (int i = 0; i < 10; i++) { S[i] += __shfl_xor(S[i], 16); S[i] += __shfl_xor(S[i], 32); }
  __shared__ float red[4][16][10];
  int w = t >> 6, lane = t & 63;
  if (lane < 16) {
    #pragma unroll
    for (int i = 0; i < 10; i++) red[w][lane][i] = S[i];
  }
  __syncthreads();
  if (t < 160) {
    int k2 = t / 10, i = t % 10;
    float v = red[0][k2][i] + red[1][k2][i] + red[2][k2][i] + red[3][k2][i];
    part[(((size_t)nc * B_ + b) * 176 + kt * 16 + k2) * 10 + i] = v;
  }
}

__global__ __launch_bounds__(256) void k_accum_fin(const float* __restrict__ part,
    float* __restrict__ occ, float* __restrict__ mu_k, float* __restrict__ sig_k) {
  int i = blockIdx.x * 256 + threadIdx.x;
  if (i >= B_ * KU_) return;
  int b = i / KU_, k = i % KU_;
  float p[10];
  #pragma unroll
  for (int j = 0; j < 10; j++) {
    float v = 0.f;
    #pragma unroll
    for (int nc = 0; nc < AC_NC; nc++)
      v += part[(((size_t)nc * B_ + b) * 176 + k) * 10 + j];
    p[j] = v;
  }
  float o = p[0];
  occ[b * KU_ + k] = o;
  float oc = fmaxf(o, EPS_);
  float s1x = p[1], s1y = p[2], s1z = p[3];
  float q0 = s1x / oc, q1 = s1y / oc, q2 = s1z / oc;
  mu_k[(b * KU_ + k) * 3 + 0] = q0;
  mu_k[(b * KU_ + k) * 3 + 1] = q1;
  mu_k[(b * KU_ + k) * 3 + 2] = q2;
  float v00 = (p[4] - 2.f * q0 * s1x + o * q0 * q0) / oc + JIT_;
  float v01 = (p[5] - q0 * s1y - s1x * q1 + o * q0 * q1) / oc;
  float v02 = (p[6] - q0 * s1z - s1x * q2 + o * q0 * q2) / oc;
  float v11 = (p[7] - 2.f * q1 * s1y + o * q1 * q1) / oc + JIT_;
  float v12 = (p[8] - q1 * s1z - s1y * q2 + o * q1 * q2) / oc;
  float v22 = (p[9] - 2.f * q2 * s1z + o * q2 * q2) / oc + JIT_;
  v00 = fmaxf(v00, SIGF_ * SIGF_) + JIT_;
  v11 = fmaxf(v11, SIGF_ * SIGF_) + JIT_;
  v22 = fmaxf(v22, SIGF_ * SIGF_) + JIT_;
  float* po = sig_k + ((size_t)(b * KU_ + k)) * 9;
  po[0] = v00; po[1] = v01; po[2] = v02;
  po[3] = v01; po[4] = v11; po[5] = v12;
  po[6] = v02; po[7] = v12; po[8] = v22;
}

// ---- slotin partials: part[nc][b*KU+k][c] = sum_{n in chunk} A[b,n,k]*s[b,n,c] ----
__global__ __launch_bounds__(256) void k_atn_s(const float* __restrict__ A,
    const float* __restrict__ X, float* __restrict__ part) {
  int blk = blockIdx.x;
  int nc = blk & 7; int tmp = blk >> 3; int kt = tmp % 11; int b = tmp / 11;
  int t = threadIdx.x; int k0 = kt * 16;
  __shared__ float Ach[64 * 16];
  float acc[16];
  #pragma unroll
  for (int j = 0; j < 16; j++) acc[j] = 0.f;
  for (int n0 = nc * 256; n0 < nc * 256 + 256; n0 += 64) {
    __syncthreads();
    for (int i = t; i < 64 * 16; i += 256) {
      int nn = i >> 4, kk = i & 15; int k = k0 + kk;
      Ach[i] = (k < KU_) ? A[((size_t)(b * N_ + n0 + nn)) * KU_ + k] : 0.f;
    }
    __syncthreads();
    for (int nn = 0; nn < 64; nn++) {
      float xv = X[((size_t)(b * N_ + n0 + nn)) * C_ + t];
      #pragma unroll
      for (int j = 0; j < 16; j++) acc[j] += Ach[(nn << 4) + j] * xv;
    }
  }
  #pragma unroll
  for (int j = 0; j < 16; j++) {
    int k = k0 + j;
    if (k < KU_) part[((size_t)nc * (B_ * KU_) + b * KU_ + k) * C_ + t] = acc[j];
  }
}

// ---- atomic version for AtA (NX=171) ----
__global__ __launch_bounds__(256) void k_atn(const float* __restrict__ A,
    const float* __restrict__ X, float* __restrict__ out, int NX) {
  int blk = blockIdx.x;
  int nc = blk & 7; int tmp = blk >> 3; int kt = tmp % 11; int b = tmp / 11;
  int t = threadIdx.x; int k0 = kt * 16;
  __shared__ float Ach[64 * 16];
  float acc[16];
  #pragma unroll
  for (int j = 0; j < 16; j++) acc[j] = 0.f;
  for (int n0 = nc * 256; n0 < nc * 256 + 256; n0 += 64) {
    __syncthreads();
    for (int i = t; i < 64 * 16; i += 256) {
      int nn = i >> 4, kk = i & 15; int k = k0 + kk;
      Ach[i] = (k < KU_) ? A[((size_t)(b * N_ + n0 + nn)) * KU_ + k] : 0.f;
    }
    __syncthreads();
    if (t < NX) {
      for (int nn = 0; nn < 64; nn++) {
        float xv = X[((size_t)(b * N_ + n0 + nn)) * NX + t];
        #pragma unroll
        for (int j = 0; j < 16; j++) acc[j] += Ach[(nn << 4) + j] * xv;
      }
    }
  }
  if (t < NX) {
    #pragma unroll
    for (int j = 0; j < 16; j++) {
      int k = k0 + j;
      if (k < KU_) atomicAdd(&out[((size_t)(b * KU_ + k)) * NX + t], acc[j]);
    }
  }
}

// ---- FUSED slot update: gates + GRU + LN + MLP + residual + next qsem ----
__global__ __launch_bounds__(256) void k_slotup(const float* __restrict__ part,
    const float* __restrict__ occ, float* __restrict__ slots,
    const float* __restrict__ wih, const float* __restrict__ bih,
    const float* __restrict__ whh, const float* __restrict__ bhh,
    const float* __restrict__ lng, const float* __restrict__ lnb,
    const float* __restrict__ w1p, const float* __restrict__ b1p,
    const float* __restrict__ w2p, const float* __restrict__ b2p,
    const float* __restrict__ qWp, float* __restrict__ qsem) {
  __shared__ float sx[1024], sh[1024], sg[1024], sxm[1024], shid[4096];
  int t = threadIdx.x; int r0 = blockIdx.x * 4;
  // stage: x = (sum of 8 partials)/occ ; h = slots
  for (int i = t; i < 1024; i += 256) {
    int rr = i >> 8, c = i & 255;
    int r = r0 + rr;
    float v = 0.f;
    #pragma unroll
    for (int nc = 0; nc < 8; nc++) v += part[((size_t)nc * (B_ * KU_) + r) * C_ + c];
    sx[i] = v / fmaxf(occ[r], 1e-8f);
    sh[i] = slots[(size_t)r * C_ + c];
  }
  __syncthreads();
  // gates: thread t owns gate-column t
  {
    const float4* wir = (const float4*)(wih + (size_t)t * C_);
    const float4* wiz = (const float4*)(wih + (size_t)(t + 256) * C_);
    const float4* win = (const float4*)(wih + (size_t)(t + 512) * C_);
    const float4* whr = (const float4*)(whh + (size_t)t * C_);
    const float4* whz = (const float4*)(whh + (size_t)(t + 256) * C_);
    const float4* whn = (const float4*)(whh + (size_t)(t + 512) * C_);
    const float4* sx4 = (const float4*)sx;
    const float4* sh4 = (const float4*)sh;
    float gir[4] = {0,0,0,0}, giz[4] = {0,0,0,0}, gin[4] = {0,0,0,0};
    float ghr[4] = {0,0,0,0}, ghz[4] = {0,0,0,0}, ghn[4] = {0,0,0,0};
    for (int c4 = 0; c4 < 64; c4++) {
      float4 a1 = wir[c4], a2 = wiz[c4], a3 = win[c4];
      float4 h1 = whr[c4], h2 = whz[c4], h3 = whn[c4];
      #pragma unroll
      for (int a = 0; a < 4; a++) {
        float4 xv = sx4[a * 64 + c4], hv = sh4[a * 64 + c4];
        gir[a] += xv.x * a1.x + xv.y * a1.y + xv.z * a1.z + xv.w * a1.w;
        giz[a] += xv.x * a2.x + xv.y * a2.y + xv.z * a2.z + xv.w * a2.w;
        gin[a] += xv.x * a3.x + xv.y * a3.y + xv.z * a3.z + xv.w * a3.w;
        ghr[a] += hv.x * h1.x + hv.y * h1.y + hv.z * h1.z + hv.w * h1.w;
        ghz[a] += hv.x * h2.x + hv.y * h2.y + hv.z * h2.z + hv.w * h2.w;
        ghn[a] += hv.x * h3.x + hv.y * h3.y + hv.z * h3.z + hv.w * h3.w;
      }
    }
    float bir = bih[t], biz = bih[t + 256], bin = bih[t + 512];
    float bhr = bhh[t], bhz = bhh[t + 256], bhn = bhh[t + 512];
    #pragma unroll
    for (int a = 0; a < 4; a++) {
      float r = 1.f / (1.f + expf(-(gir[a] + bir + ghr[a] + bhr)));
      float z = 1.f / (1.f + expf(-(giz[a] + biz + ghz[a] + bhz)));
      float n = tanhf(gin[a] + bin + r * (ghn[a] + bhn));
      sg[a * 256 + t] = (1.f - z) * n + z * sh[a * 256 + t];
    }
  }
  __syncthreads();
  // LN: warp w handles row w
  {
    int w = t >> 6, lane = t & 63;
    int a = w;
    float x0 = sg[a * 256 + lane], x1 = sg[a * 256 + lane + 64];
    float x2 = sg[a * 256 + lane + 128], x3 = sg[a * 256 + lane + 192];
    float mean = wred(x0 + x1 + x2 + x3) * (1.f / 256.f);
    float d0 = x0 - mean, d1 = x1 - mean, d2 = x2 - mean, d3 = x3 - mean;
    float var = wred(d0 * d0 + d1 * d1 + d2 * d2 + d3 * d3) * (1.f / 256.f);
    float rstd = rsqrtf(var + 1e-5f);
    sxm[a * 256 + lane]       = d0 * rstd * lng[lane]       + lnb[lane];
    sxm[a * 256 + lane + 64]  = d1 * rstd * lng[lane + 64]  + lnb[lane + 64];
    sxm[a * 256 + lane + 128] = d2 * rstd * lng[lane + 128] + lnb[lane + 128];
    sxm[a * 256 + lane + 192] = d3 * rstd * lng[lane + 192] + lnb[lane + 192];
  }
  __syncthreads();
  // w1 + gelu: thread t owns outcols t, t+256, t+512, t+768
  {
    const float4* q0 = (const float4*)(w1p + (size_t)t * C_);
    const float4* q1 = (const float4*)(w1p + (size_t)(t + 256) * C_);
    const float4* q2 = (const float4*)(w1p + (size_t)(t + 512) * C_);
    const float4* q3 = (const float4*)(w1p + (size_t)(t + 768) * C_);
    const float4* sxm4 = (const float4*)sxm;
    float acc[4][4];
    #pragma unroll
    for (int a = 0; a < 4; a++)
      #pragma unroll
      for (int j = 0; j < 4; j++) acc[a][j] = 0.f;
    for (int c4 = 0; c4 < 64; c4++) {
      float4 v0 = q0[c4], v1 = q1[c4], v2 = q2[c4], v3 = q3[c4];
      #pragma unroll
      for (int a = 0; a < 4; a++) {
        float4 xv = sxm4[a * 64 + c4];
        acc[a][0] += xv.x * v0.x + xv.y * v0.y + xv.z * v0.z + xv.w * v0.w;
        acc[a][1] += xv.x * v1.x + xv.y * v1.y + xv.z * v1.z + xv.w * v1.w;
        acc[a][2] += xv.x * v2.x + xv.y * v2.y + xv.z * v2.z + xv.w * v2.w;
        acc[a][3] += xv.x * v3.x + xv.y * v3.y + xv.z * v3.z + xv.w * v3.w;
      }
    }
    float bb0 = b1p[t], bb1 = b1p[t + 256], bb2v = b1p[t + 512], bb3 = b1p[t + 768];
    #pragma unroll
    for (int a = 0; a < 4; a++) {
      float v;
      v = acc[a][0] + bb0; shid[a * 1024 + t]       = 0.5f * v * (1.f + erff(v * 0.70710678118654752f));
      v = acc[a][1] + bb1; shid[a * 1024 + t + 256] = 0.5f * v * (1.f + erff(v * 0.70710678118654752f));
      v = acc[a][2] + bb2v; shid[a * 1024 + t + 512] = 0.5f * v * (1.f + erff(v * 0.70710678118654752f));
      v = acc[a][3] + bb3; shid[a * 1024 + t + 768] = 0.5f * v * (1.f + erff(v * 0.70710678118654752f));
    }
  }
  __syncthreads();
  // w2 + residual
  {
    const float4* wr = (const float4*)(w2p + (size_t)t * 1024);
    const float4* sh4 = (const float4*)shid;
    float o[4] = {0, 0, 0, 0};
    for (int c4 = 0; c4 < 256; c4++) {
      float4 wv = wr[c4];
      #pragma unroll
      for (int a = 0; a < 4; a++) {
        float4 hv = sh4[a * 256 + c4];
        o[a] += hv.x * wv.x + hv.y * wv.y + hv.z * wv.z + hv.w * wv.w;
      }
    }
    float bb = b2p[t];
    #pragma unroll
    for (int a = 0; a < 4; a++) {
      float fin = sg[a * 256 + t] + o[a] + bb;
      slots[(size_t)(r0 + a) * C_ + t] = fin;
      sx[a * 256 + t] = fin;  // reuse for qsem
    }
  }
  __syncthreads();
  // next-iteration qsem = slots_new @ qW.T
  {
    const float4* qr = (const float4*)(qWp + (size_t)t * C_);
    const float4* sx4 = (const float4*)sx;
    float o[4] = {0, 0, 0, 0};
    for (int c4 = 0; c4 < 64; c4++) {
      float4 wv = qr[c4];
      #pragma unroll
      for (int a = 0; a < 4; a++) {
        float4 xv = sx4[a * 64 + c4];
        o[a] += xv.x * wv.x + xv.y * wv.y + xv.z * wv.z + xv.w * wv.w;
      }
    }
    #pragma unroll
    for (int a = 0; a < 4; a++)
      qsem[(size_t)(r0 + a) * C_ + t] = o[a];
  }
}

__global__ __launch_bounds__(256) void k_hist(const int* __restrict__ idx,
    float* __restrict__ okl, float* __restrict__ oent) {
  __shared__ float hist[KMAX_];
  int t = threadIdx.x;
  for (int i = t; i < KMAX_; i += 256) hist[i] = 0.f;
  __syncthreads();
  for (int i = t; i < B_ * KU_; i += 256) atomicAdd(&hist[idx[i]], 1.0f);
  __syncthreads();
  float kl = 0.f, ent = 0.f;
  const float tot = (float)(B_ * KU_);
  for (int i = t; i < KMAX_; i += 256) {
    float pc = fmaxf(hist[i] / tot, 1e-8f);
    float lp = logf(pc);
    kl += pc * (lp + LOGKMAX_);
    ent += pc * lp;
  }
  __shared__ float red[256];
  kl = blk_red(kl, red, t); ent = blk_red(ent, red, t);
  if (t == 0) { okl[0] = kl; oent[0] = ent; }
}

__global__ __launch_bounds__(256) void k_occmse(const float* __restrict__ occ,
    float* __restrict__ out) {
  __shared__ float so[B_ * KU_];
  int t = threadIdx.x;
  for (int i = t; i < B_ * KU_; i += 256) so[i] = occ[i];
  __syncthreads();
  __shared__ float red[256];
  __shared__ float bsum[B_];
  for (int b = 0; b < B_; b++) {
    float s = 0.f;
    for (int i = t; i < KU_; i += 256) s += so[b * KU_ + i];
    s = blk_red(s, red, t);
    if (t == 0) bsum[b] = fmaxf(s, 1e-8f);
    __syncthreads();
  }
  float acc = 0.f;
  const float invK = 1.0f / (float)KU_;
  for (int i = t; i < B_ * KU_; i += 256) {
    int b = i / KU_;
    float v = so[i] / bsum[b] - invK;
    acc += v * v;
  }
  acc = blk_red(acc, red, t);
  if (t == 0) out[0] = acc / (float)(B_ * KU_);
}

// ---- collapse loss partial ----
__global__ __launch_bounds__(256) void k_colpart(const float* __restrict__ AtA,
    float* __restrict__ colacc) {
  int blk = blockIdx.x; int b = blk / KU_, k = blk % KU_; int t = threadIdx.x;
  float acc = 0.f;
  if (t < KU_ && t != k) {
    float dk = AtA[((size_t)(b * KU_ + k)) * KU_ + k];
    float dt = AtA[((size_t)(b * KU_ + t)) * KU_ + t];
    float v  = AtA[((size_t)(b * KU_ + k)) * KU_ + t];
    float gm = v / (fmaxf(sqrtf(dk), 1e-8f) * fmaxf(sqrtf(dt), 1e-8f));
    acc = gm * gm;
  }
  float v = wred(acc);
  __shared__ float p[4];
  if ((t & 63) == 0) p[t >> 6] = v;
  __syncthreads();
  if (t == 0) atomicAdd(colacc, p[0] + p[1] + p[2] + p[3]);
}

__global__ void k_colfin(const float* __restrict__ colacc,
    const float* __restrict__ okl, const float* __restrict__ oent,
    const float* __restrict__ oocc, float* __restrict__ ocol, float* __restrict__ otot) {
  float col = colacc[0] / (float)(B_ * KU_ * KU_);
  ocol[0] = col;
  otot[0] = 0.05f * okl[0] + 0.0f * oent[0] + 0.5f * oocc[0] + 0.1f * col;
}

extern "C" void kernel_launch(void* const* d_in, const int* in_sizes, int n_in,
                              void* d_out_v, int out_size, void* d_ws, size_t ws_size,
                              hipStream_t stream) {
  const float* s     = (const float*)d_in[0];
  const float* mu    = (const float*)d_in[1];
  const float* Sigma = (const float*)d_in[2];
  const float* mask  = (const float*)d_in[3];
  const float* pool  = (const float*)d_in[4];
  const float* geop  = (const float*)d_in[5];
  const float* gW    = (const float*)d_in[6];
  const float* qW    = (const float*)d_in[7];
  const float* kW    = (const float*)d_in[8];
  const float* wih   = (const float*)d_in[9];
  const float* whh   = (const float*)d_in[10];
  const float* bih   = (const float*)d_in[11];
  const float* bhh   = (const float*)d_in[12];
  const float* lng   = (const float*)d_in[13];
  const float* lnb   = (const float*)d_in[14];
  const float* w1    = (const float*)d_in[15];
  const float* b1    = (const float*)d_in[16];
  const float* w2    = (const float*)d_in[17];
  const float* b2    = (const float*)d_in[18];
  const float* wgeo  = (const float*)d_in[19];
  const float* gsr   = (const float*)d_in[20];
  const float* gbias = (const float*)d_in[21];

  float* out = (float*)d_out_v;
  float* A     = out + O_A;
  float* slots = out + O_SLOTS;
  float* muk   = out + O_MUK;
  float* sigk  = out + O_SIGK;
  float* idxf  = out + O_IDX;
  float* okl   = out + O_KL;
  float* oent  = out + O_ENT;
  float* oocc  = out + O_OCC;
  float* ocol  = out + O_COL;
  float* otot  = out + O_TOT;

  float* ws = (float*)d_ws;
  int*   idxi   = (int*)(ws + WS_IDXI);
  float* ksem   = ws + WS_KSEM;
  float* qsem   = ws + WS_QSEM;
  float* occ    = ws + WS_OCC;
  float* atpart = ws + WS_PART;
  float* acpart = ws + WS_ACPART;
  float* ata    = ws + WS_ATA;
  float* colacc = ws + WS_COLACC;

  // stage 0
  hipMemsetAsync(ws, 0, WS_STATS_BYTES, stream);
  k_stats<<<B_ * 8, 256, 0, stream>>>(s, mu, Sigma, mask, ws);
  k_fin<<<1, 64, 0, stream>>>(ws);
  k_qv<<<B_, 256, 0, stream>>>(ws + WS_SSUM, gW, ws + WS_QV);
  k_score<<<B_ * 16, 256, 0, stream>>>(ws + WS_QV, pool, ws + WS_SCORE);
  k_sort<<<B_, 256, 0, stream>>>(ws + WS_SCORE, idxi, idxf);
  k_init<<<B_ * KU_, 256, 0, stream>>>(idxi, pool, geop, ws, slots, muk, sigk);

  // ksem = s @ kW.T ; initial qsem = slots @ qW.T
  k_gemm_plain<8><<<1024, 256, 8 * C_ * 4, stream>>>(s, kW, ksem, C_, C_, 1.0f);
  k_gemm_plain<4><<<171, 256, 4 * C_ * 4, stream>>>(slots, qW, qsem, C_, C_, 1.0f);

  for (int it = 0; it < ITERS_; ++it) {
    k_lgsm<<<B_ * (N_ / 16), 256, 0, stream>>>(ksem, qsem, mu, Sigma, mask,
                                               muk, sigk, wgeo, gsr, gbias, A);
    k_accum_part<<<B_ * 11 * AC_NC, 256, 0, stream>>>(A, mu, Sigma, acpart);
    k_accum_fin<<<3, 256, 0, stream>>>(acpart, occ, muk, sigk);
    k_atn_s<<<B_ * 11 * 8, 256, 0, stream>>>(A, s, atpart);
    k_slotup<<<171, 256, 0, stream>>>(atpart, occ, slots, wih, bih, whh, bhh,
                                      lng, lnb, w1, b1, w2, b2, qW, qsem);
  }

  // losses
  hipMemsetAsync(ata, 0, (size_t)B_ * KU_ * KU_ * 4, stream);
  k_atn<<<B_ * 11 * 8, 256, 0, stream>>>(A, A, ata, KU_);
  k_colpart<<<B_ * KU_, 256, 0, stream>>>(ata, colacc);
  k_hist<<<1, 256, 0, stream>>>(idxi, okl, oent);
  k_occmse<<<1, 256, 0, stream>>>(occ, oocc);
  k_colfin<<<1, 1, 0, stream>>>(colacc, okl, oent, oocc, ocol, otot);
}

// Round 7
// 877.445 us; speedup vs baseline: 1.5436x; 1.1030x over previous
//
#include <hip/hip_runtime.h>
#include <math.h>

#define B_ 4
#define N_ 2048
#define C_ 256
#define KMAX_ 1024
#define KU_ 171
#define BK_ 684
#define ITERS_ 3
#define H_ 4
#define EPS_ 1e-8f
#define SIGF_ 0.03f
#define JIT_ 1e-6f
#define LOGKMAX_ 6.93147180559945f

// ---------------- workspace layout (float offsets) ----------------
#define WS_CNT 0
#define WS_MUS 4
#define WS_MOS 16
#define WS_SGS 40
#define WS_COLACC 100
#define WS_SSUM 128
#define WS_STATS_BYTES (1152*4)
#define WS_MEAN 1152
#define WS_STD 1164
#define WS_SIGAVG 1176
#define WS_IDXI 1216
#define WS_KSEM 1920                    // B*N*C = 2097152
#define WS_QSEM (WS_KSEM+2097152)       // 175104
#define WS_OCC  (WS_QSEM+175104)        // 704
#define WS_PART (WS_OCC+704)            // 8*684*256 = 1400832 (atn partials; later aliased by w2part)
#define WS_W2P  WS_PART                 // 4*684*256 = 700416 (alias, strictly ordered)
#define WS_GBUF (WS_PART+1400832)       // 4*684*256 = 700416 (alias: ATA after loop)
#define WS_ATA  WS_GBUF
#define WS_SNEW (WS_GBUF+700416)        // 175104
#define WS_XM   (WS_SNEW+175104)        // 175104
#define WS_HID  (WS_XM+175104)          // 684*1024 = 700416
#define WS_ACPART (WS_HID+700416)       // 28160
#define WS_QV   (WS_ACPART+28160)       // 1024
#define WS_SCORE (WS_QV+1024)           // 4096

// ---------------- output layout (float offsets) ----------------
#define O_A 0
#define O_SLOTS 1400832
#define O_MUK   1575936
#define O_SIGK  1577988
#define O_IDX   1584144
#define O_KL    1584828
#define O_ENT   1584829
#define O_OCC   1584830
#define O_COL   1584831
#define O_TOT   1584832

__device__ __forceinline__ float wred(float v) {
  #pragma unroll
  for (int i = 32; i; i >>= 1) v += __shfl_xor(v, i);
  return v;
}
__device__ __forceinline__ float wmax(float v) {
  #pragma unroll
  for (int i = 32; i; i >>= 1) v = fmaxf(v, __shfl_xor(v, i));
  return v;
}

__device__ __forceinline__ float blk_red(float v, float* red, int t) {
  red[t] = v; __syncthreads();
  #pragma unroll
  for (int s = 128; s > 0; s >>= 1) {
    if (t < s) red[t] += red[t + s];
    __syncthreads();
  }
  float r = red[0]; __syncthreads();
  return r;
}

// ---- partial batch stats ----
__global__ __launch_bounds__(256) void k_stats(const float* __restrict__ s,
    const float* __restrict__ mu, const float* __restrict__ Sigma,
    const float* __restrict__ mask, float* __restrict__ ws) {
  int blk = blockIdx.x; int b = blk / 8; int nc = blk % 8; int t = threadIdx.x;
  int n = nc * 256 + t;
  float m = mask[b * N_ + n];
  const float* mun = mu + ((size_t)(b * N_ + n)) * 3;
  float m0 = mun[0], m1v = mun[1], m2 = mun[2];
  const float* sgn = Sigma + ((size_t)(b * N_ + n)) * 9;
  float sg[9];
  #pragma unroll
  for (int j = 0; j < 9; j++) sg[j] = sgn[j];
  int lane = t & 63;
  float vals[19];
  vals[0] = m; vals[1] = m * m0; vals[2] = m * m1v; vals[3] = m * m2;
  vals[4] = m * m0 * m0; vals[5] = m * m0 * m1v; vals[6] = m * m0 * m2;
  vals[7] = m * m1v * m1v; vals[8] = m * m1v * m2; vals[9] = m * m2 * m2;
  #pragma unroll
  for (int j = 0; j < 9; j++) vals[10 + j] = m * sg[j];
  #pragma unroll
  for (int j = 0; j < 19; j++) {
    float v = wred(vals[j]);
    if (lane == 0) {
      int base = (j == 0) ? WS_CNT + b : (j < 4 ? WS_MUS + b * 3 + (j - 1)
                 : (j < 10 ? WS_MOS + b * 6 + (j - 4) : WS_SGS + b * 9 + (j - 10)));
      atomicAdd(ws + base, v);
    }
  }
  const float* sb = s + ((size_t)b * N_ + nc * 256) * C_;
  const float* mk = mask + b * N_ + nc * 256;
  float sa = 0.f;
  #pragma unroll 4
  for (int nn = 0; nn < 256; nn++) sa += mk[nn] * sb[(size_t)nn * C_ + t];
  atomicAdd(ws + WS_SSUM + b * C_ + t, sa);
}

// ---- finalize mean/std/sigavg ----
__global__ __launch_bounds__(64) void k_fin(float* __restrict__ ws) {
  int t = threadIdx.x;
  if (t < B_) {
    int b = t;
    float cnt = fmaxf(ws[WS_CNT + b], EPS_);
    float me[3];
    #pragma unroll
    for (int i = 0; i < 3; i++) { me[i] = ws[WS_MUS + b * 3 + i] / cnt; ws[WS_MEAN + b * 3 + i] = me[i]; }
    const int dg[3] = {0, 3, 5};
    #pragma unroll
    for (int i = 0; i < 3; i++) {
      float cov = ws[WS_MOS + b * 6 + dg[i]] / cnt - me[i] * me[i];
      ws[WS_STD + b * 3 + i] = fmaxf(sqrtf(fmaxf(cov, EPS_)), SIGF_);
    }
    #pragma unroll
    for (int i = 0; i < 3; i++)
      #pragma unroll
      for (int j = 0; j < 3; j++)
        ws[WS_SIGAVG + b * 9 + i * 3 + j] =
            0.5f * (ws[WS_SGS + b * 9 + i * 3 + j] + ws[WS_SGS + b * 9 + j * 3 + i]) / cnt;
  }
}

// ---- gating q vector ----
__global__ __launch_bounds__(256) void k_qv(const float* __restrict__ ws_ssum,
    const float* __restrict__ gW, float* __restrict__ qv_o) {
  int b = blockIdx.x, t = threadIdx.x;
  __shared__ float sb[C_];
  __shared__ float rv[256];
  sb[t] = ws_ssum[b * C_ + t];
  __syncthreads();
  const float4* g4 = (const float4*)(gW + (size_t)t * C_);
  float qr = 0.f;
  #pragma unroll 4
  for (int c4 = 0; c4 < 64; c4++) {
    float4 g = g4[c4];
    qr += sb[c4 * 4] * g.x + sb[c4 * 4 + 1] * g.y + sb[c4 * 4 + 2] * g.z + sb[c4 * 4 + 3] * g.w;
  }
  float n2 = blk_red(qr * qr, rv, t);
  qv_o[b * C_ + t] = qr / fmaxf(sqrtf(n2), 1e-12f);
}

// ---- scores ----
__global__ __launch_bounds__(256) void k_score(const float* __restrict__ qv,
    const float* __restrict__ pool, float* __restrict__ score) {
  int blk = blockIdx.x; int b = blk >> 4; int pc = blk & 15;
  int t = threadIdx.x; int row = pc * 64 + (t >> 2); int q = t & 3;
  __shared__ float qs[C_];
  qs[t] = qv[b * C_ + t];
  __syncthreads();
  const float4* p4 = (const float4*)(pool + (size_t)row * C_ + q * 64);
  float d = 0.f, p2 = 0.f;
  #pragma unroll
  for (int i = 0; i < 16; i++) {
    float4 pv = p4[i];
    int c = q * 64 + i * 4;
    d += qs[c] * pv.x + qs[c + 1] * pv.y + qs[c + 2] * pv.z + qs[c + 3] * pv.w;
    p2 += pv.x * pv.x + pv.y * pv.y + pv.z * pv.z + pv.w * pv.w;
  }
  d += __shfl_xor(d, 1); d += __shfl_xor(d, 2);
  p2 += __shfl_xor(p2, 1); p2 += __shfl_xor(p2, 2);
  if (q == 0) score[b * KMAX_ + row] = d / fmaxf(sqrtf(p2), 1e-12f);
}

// ---- bitonic sort; order == jax.lax.top_k ----
__global__ __launch_bounds__(256) void k_sort(const float* __restrict__ score,
    int* __restrict__ idx_o, float* __restrict__ idxf_o) {
  int b = blockIdx.x, t = threadIdx.x;
  __shared__ float val[KMAX_]; __shared__ int id[KMAX_];
  for (int j = t; j < KMAX_; j += 256) { val[j] = score[b * KMAX_ + j]; id[j] = j; }
  __syncthreads();
  for (int kk = 2; kk <= KMAX_; kk <<= 1) {
    for (int j = kk >> 1; j > 0; j >>= 1) {
      for (int i = t; i < KMAX_; i += 256) {
        int ix = i ^ j;
        if (ix > i) {
          float va = val[i], vb = val[ix]; int ia = id[i], ib = id[ix];
          bool bBeforeA = (vb > va) || (vb == va && ib < ia);
          bool up = ((i & kk) == 0);
          if (up == bBeforeA) {
            val[i] = vb; val[ix] = va; id[i] = ib; id[ix] = ia;
          }
        }
      }
      __syncthreads();
    }
  }
  if (t < KU_) {
    idx_o[b * KU_ + t] = id[t];
    idxf_o[b * KU_ + t] = (float)id[t];
  }
}

// ---- init slots / mu_k / Sig_k ----
__global__ __launch_bounds__(256) void k_init(const int* __restrict__ idx,
    const float* __restrict__ pool, const float* __restrict__ geop,
    const float* __restrict__ ws, float* __restrict__ slots,
    float* __restrict__ mu_k, float* __restrict__ sig_k) {
  int blk = blockIdx.x; int b = blk / KU_, k = blk % KU_; int t = threadIdx.x;
  int j = idx[b * KU_ + k];
  slots[((size_t)(b * KU_ + k)) * C_ + t] = pool[(size_t)j * C_ + t];
  if (t < 3) {
    mu_k[(b * KU_ + k) * 3 + t] = ws[WS_MEAN + b * 3 + t] + geop[j * 3 + t] * (0.5f * ws[WS_STD + b * 3 + t]);
  }
  if (t < 9) {
    float v = ws[WS_SIGAVG + b * 9 + t] * 0.1f;
    if (t == 0 || t == 4 || t == 8) v += SIGF_ * SIGF_ + JIT_;
    sig_k[((size_t)(b * KU_ + k)) * 9 + t] = v;
  }
}

// ---- plain row GEMM: out[r,t] = dot(in[r,:], W[t,:]) ----
template<int ROWS>
__global__ __launch_bounds__(256) void k_gemm_plain(const float* __restrict__ in,
    const float* __restrict__ W, float* __restrict__ out, int IN, int OUT, float scale) {
  extern __shared__ float sm[];
  int t = threadIdx.x; int r0 = blockIdx.x * ROWS;
  int C4 = IN >> 2;
  for (int i = t; i < ROWS * C4; i += 256) {
    int rr = i / C4;
    ((float4*)sm)[i] = ((const float4*)(in + (size_t)(r0 + rr) * IN))[i - rr * C4];
  }
  __syncthreads();
  const float4* W4 = (const float4*)(W + (size_t)t * IN);
  const float4* sm4 = (const float4*)sm;
  float acc[ROWS];
  #pragma unroll
  for (int a = 0; a < ROWS; a++) acc[a] = 0.f;
  for (int c4 = 0; c4 < C4; c4++) {
    float4 wv = W4[c4];
    #pragma unroll
    for (int a = 0; a < ROWS; a++) {
      float4 sv = sm4[a * C4 + c4];
      acc[a] += sv.x * wv.x + sv.y * wv.y + sv.z * wv.z + sv.w * wv.w;
    }
  }
  #pragma unroll
  for (int a = 0; a < ROWS; a++)
    out[(size_t)(r0 + a) * OUT + t] = acc[a] * scale;
}

// ---- FUSED logits + geo + softmax ----
__global__ __launch_bounds__(256) void k_lgsm(const float* __restrict__ ksem,
    const float* __restrict__ qsem, const float* __restrict__ mu,
    const float* __restrict__ Sigma, const float* __restrict__ mask,
    const float* __restrict__ mu_k, const float* __restrict__ sig_k,
    const float* __restrict__ wgeo, const float* __restrict__ gsr,
    const float* __restrict__ gbias, float* __restrict__ A) {
  __shared__ float ksm[16 * C_];
  __shared__ float Asm[16][172];
  __shared__ float muk[KU_ * 3];
  __shared__ float sgk[KU_ * 6];
  __shared__ float rowd[16][10];
  int blk = blockIdx.x; int b = blk / (N_ / 16); int nt = blk % (N_ / 16);
  int t = threadIdx.x; int r0 = nt * 16;
  for (int i = t; i < 16 * (C_ >> 2); i += 256) {
    int rr = i >> 6;
    ((float4*)ksm)[i] = ((const float4*)(ksem + ((size_t)(b * N_ + r0 + rr)) * C_))[i & 63];
  }
  for (int i = t; i < KU_ * 3; i += 256) muk[i] = mu_k[(size_t)b * KU_ * 3 + i];
  for (int i = t; i < KU_ * 6; i += 256) {
    int k = i / 6, c = i % 6;
    const int map[6] = {0, 1, 2, 4, 5, 8};
    sgk[i] = sig_k[((size_t)(b * KU_ + k)) * 9 + map[c]];
  }
  if (t < 160) {
    int rr = t / 10, c = t % 10;
    int n = r0 + rr;
    float v;
    if (c == 0) v = mask[b * N_ + n];
    else if (c < 4) v = mu[((size_t)(b * N_ + n)) * 3 + (c - 1)];
    else {
      const int map[6] = {0, 1, 2, 4, 5, 8};
      v = Sigma[((size_t)(b * N_ + n)) * 9 + map[c - 4]];
    }
    rowd[rr][c] = v;
  }
  __syncthreads();
  if (t < KU_) {
    const float4* q4 = (const float4*)(qsem + ((size_t)(b * KU_ + t)) * C_);
    const float4* sm4 = (const float4*)ksm;
    float acc[16];
    #pragma unroll
    for (int a = 0; a < 16; a++) acc[a] = 0.f;
    for (int c4 = 0; c4 < 64; c4++) {
      float4 qv = q4[c4];
      #pragma unroll
      for (int a = 0; a < 16; a++) {
        float4 sv = sm4[a * 64 + c4];
        acc[a] += sv.x * qv.x + sv.y * qv.y + sv.z * qv.z + sv.w * qv.w;
      }
    }
    float ah = 0.f, bs = 0.f;
    #pragma unroll
    for (int h = 0; h < H_; h++) {
      float x = gsr[h];
      ah += fmaxf(x, 0.f) + log1pf(expf(-fabsf(x)));
      bs += gbias[h];
    }
    float wg = wgeo[0];
    float mk0 = muk[t * 3], mk1 = muk[t * 3 + 1], mk2 = muk[t * 3 + 2];
    float k00 = sgk[t * 6], k01 = sgk[t * 6 + 1], k02 = sgk[t * 6 + 2];
    float k11 = sgk[t * 6 + 3], k12 = sgk[t * 6 + 4], k22 = sgk[t * 6 + 5];
    #pragma unroll
    for (int a = 0; a < 16; a++) {
      float m = rowd[a][0];
      float d0 = rowd[a][1] - mk0, d1 = rowd[a][2] - mk1, d2 = rowd[a][3] - mk2;
      float s00 = rowd[a][4] + k00, s01 = rowd[a][5] + k01, s02 = rowd[a][6] + k02;
      float s11 = rowd[a][7] + k11, s12 = rowd[a][8] + k12, s22 = rowd[a][9] + k22;
      float c00 = s11 * s22 - s12 * s12;
      float c01 = s02 * s12 - s01 * s22;
      float c02 = s01 * s12 - s02 * s11;
      float det = s00 * c00 + s01 * c01 + s02 * c02;
      float c11 = s00 * s22 - s02 * s02;
      float c12 = s01 * s02 - s00 * s12;
      float c22 = s00 * s11 - s01 * s01;
      float inv = 1.0f / det;
      float x0 = (c00 * d0 + c01 * d1 + c02 * d2) * inv;
      float x1 = (c01 * d0 + c11 * d1 + c12 * d2) * inv;
      float x2 = (c02 * d0 + c12 * d1 + c22 * d2) * inv;
      float maha = d0 * x0 + d1 * x1 + d2 * x2;
      float logdet = logf(fmaxf(det, 1e-30f));
      float G = -0.5f * (maha + logdet);
      float l = acc[a] * 0.0625f + wg * (ah * G + bs);
      if (m < 0.5f) l = -1e9f;
      Asm[a][t] = l;
    }
  }
  __syncthreads();
  int w = t >> 6, lane = t & 63;
  #pragma unroll
  for (int q = 0; q < 4; q++) {
    int a = w * 4 + q;
    float v0 = (lane < KU_) ? Asm[a][lane] : -INFINITY;
    float v1 = (lane + 64 < KU_) ? Asm[a][lane + 64] : -INFINITY;
    float v2 = (lane + 128 < KU_) ? Asm[a][lane + 128] : -INFINITY;
    float mx = wmax(fmaxf(v0, fmaxf(v1, v2)));
    float e0 = (lane < KU_) ? expf(v0 - mx) : 0.f;
    float e1 = (lane + 64 < KU_) ? expf(v1 - mx) : 0.f;
    float e2 = (lane + 128 < KU_) ? expf(v2 - mx) : 0.f;
    float ss = wred(e0 + e1 + e2);
    float scale = rowd[a][0] / ss;
    if (lane < KU_) Asm[a][lane] = e0 * scale;
    if (lane + 64 < KU_) Asm[a][lane + 64] = e1 * scale;
    if (lane + 128 < KU_) Asm[a][lane + 128] = e2 * scale;
  }
  __syncthreads();
  for (int i = t; i < 16 * KU_; i += 256) {
    int a = i / KU_, k = i - a * KU_;
    A[((size_t)(b * N_ + r0 + a)) * KU_ + k] = Asm[a][k];
  }
}

// ---- occ/mu_k/Sig_k moments ----
#define AC_NC 4
__global__ __launch_bounds__(256) void k_accum_part(const float* __restrict__ A,
    const float* __restrict__ mu, const float* __restrict__ Sigma,
    float* __restrict__ part) {
  int blk = blockIdx.x;
  int nc = blk & 3; int tmp = blk >> 2; int kt = tmp % 11; int b = tmp / 11;
  int t = threadIdx.x; int nn = t >> 4; int kk = t & 15;
  int k = kt * 16 + kk;
  float S[10];
  #pragma unroll
  for (int i = 0; i < 10; i++) S[i] = 0.f;
  __shared__ float rowd[16][10];
  const int NCH = N_ / AC_NC;
  for (int n0 = nc * NCH; n0 < nc * NCH + NCH; n0 += 16) {
    __syncthreads();
    if (t < 144) {
      int rr = t / 9, c = t % 9;
      int n = n0 + rr;
      float v;
      if (c < 3) v = mu[((size_t)(b * N_ + n)) * 3 + c];
      else {
        const int map[6] = {0, 1, 2, 4, 5, 8};
        v = Sigma[((size_t)(b * N_ + n)) * 9 + map[c - 3]];
      }
      rowd[rr][c] = v;
    }
    float a = (k < KU_) ? A[((size_t)(b * N_ + n0 + nn)) * KU_ + k] : 0.f;
    __syncthreads();
    float m0 = rowd[nn][0], m1 = rowd[nn][1], m2 = rowd[nn][2];
    float g0 = rowd[nn][3], g1 = rowd[nn][4], g2 = rowd[nn][5];
    float g4 = rowd[nn][6], g5 = rowd[nn][7], g8 = rowd[nn][8];
    S[0] += a; S[1] += a * m0; S[2] += a * m1; S[3] += a * m2;
    S[4] += a * (g0 + m0 * m0); S[5] += a * (g1 + m0 * m1); S[6] += a * (g2 + m0 * m2);
    S[7] += a * (g4 + m1 * m1); S[8] += a * (g5 + m1 * m2); S[9] += a * (g8 + m2 * m2);
  }
  #pragma unroll
  for (int i = 0; i < 10; i++) { S[i] += __shfl_xor(S[i], 16); S[i] += __shfl_xor(S[i], 32); }
  __shared__ float red[4][16][10];
  int w = t >> 6, lane = t & 63;
  if (lane < 16) {
    #pragma unroll
    for (int i = 0; i < 10; i++) red[w][lane][i] = S[i];
  }
  __syncthreads();
  if (t < 160) {
    int k2 = t / 10, i = t % 10;
    float v = red[0][k2][i] + red[1][k2][i] + red[2][k2][i] + red[3][k2][i];
    part[(((size_t)nc * B_ + b) * 176 + kt * 16 + k2) * 10 + i] = v;
  }
}

__global__ __launch_bounds__(256) void k_accum_fin(const float* __restrict__ part,
    float* __restrict__ occ, float* __restrict__ mu_k, float* __restrict__ sig_k) {
  int i = blockIdx.x * 256 + threadIdx.x;
  if (i >= B_ * KU_) return;
  int b = i / KU_, k = i % KU_;
  float p[10];
  #pragma unroll
  for (int j = 0; j < 10; j++) {
    float v = 0.f;
    #pragma unroll
    for (int nc = 0; nc < AC_NC; nc++)
      v += part[(((size_t)nc * B_ + b) * 176 + k) * 10 + j];
    p[j] = v;
  }
  float o = p[0];
  occ[b * KU_ + k] = o;
  float oc = fmaxf(o, EPS_);
  float s1x = p[1], s1y = p[2], s1z = p[3];
  float q0 = s1x / oc, q1 = s1y / oc, q2 = s1z / oc;
  mu_k[(b * KU_ + k) * 3 + 0] = q0;
  mu_k[(b * KU_ + k) * 3 + 1] = q1;
  mu_k[(b * KU_ + k) * 3 + 2] = q2;
  float v00 = (p[4] - 2.f * q0 * s1x + o * q0 * q0) / oc + JIT_;
  float v01 = (p[5] - q0 * s1y - s1x * q1 + o * q0 * q1) / oc;
  float v02 = (p[6] - q0 * s1z - s1x * q2 + o * q0 * q2) / oc;
  float v11 = (p[7] - 2.f * q1 * s1y + o * q1 * q1) / oc + JIT_;
  float v12 = (p[8] - q1 * s1z - s1y * q2 + o * q1 * q2) / oc;
  float v22 = (p[9] - 2.f * q2 * s1z + o * q2 * q2) / oc + JIT_;
  v00 = fmaxf(v00, SIGF_ * SIGF_) + JIT_;
  v11 = fmaxf(v11, SIGF_ * SIGF_) + JIT_;
  v22 = fmaxf(v22, SIGF_ * SIGF_) + JIT_;
  float* po = sig_k + ((size_t)(b * KU_ + k)) * 9;
  po[0] = v00; po[1] = v01; po[2] = v02;
  po[3] = v01; po[4] = v11; po[5] = v12;
  po[6] = v02; po[7] = v12; po[8] = v22;
}

// ---- slotin partials: part[nc][b*KU+k][c] = sum_{n in chunk} A[b,n,k]*s[b,n,c] ----
__global__ __launch_bounds__(256) void k_atn_s(const float* __restrict__ A,
    const float* __restrict__ X, float* __restrict__ part) {
  int blk = blockIdx.x;
  int nc = blk & 7; int tmp = blk >> 3; int kt = tmp % 11; int b = tmp / 11;
  int t = threadIdx.x; int k0 = kt * 16;
  __shared__ float Ach[64 * 16];
  float acc[16];
  #pragma unroll
  for (int j = 0; j < 16; j++) acc[j] = 0.f;
  for (int n0 = nc * 256; n0 < nc * 256 + 256; n0 += 64) {
    __syncthreads();
    for (int i = t; i < 64 * 16; i += 256) {
      int nn = i >> 4, kk = i & 15; int k = k0 + kk;
      Ach[i] = (k < KU_) ? A[((size_t)(b * N_ + n0 + nn)) * KU_ + k] : 0.f;
    }
    __syncthreads();
    for (int nn = 0; nn < 64; nn++) {
      float xv = X[((size_t)(b * N_ + n0 + nn)) * C_ + t];
      #pragma unroll
      for (int j = 0; j < 16; j++) acc[j] += Ach[(nn << 4) + j] * xv;
    }
  }
  #pragma unroll
  for (int j = 0; j < 16; j++) {
    int k = k0 + j;
    if (k < KU_) part[((size_t)nc * (B_ * KU_) + b * KU_ + k) * C_ + t] = acc[j];
  }
}

// ---- atomic version for AtA (NX=171) ----
__global__ __launch_bounds__(256) void k_atn(const float* __restrict__ A,
    const float* __restrict__ X, float* __restrict__ out, int NX) {
  int blk = blockIdx.x;
  int nc = blk & 7; int tmp = blk >> 3; int kt = tmp % 11; int b = tmp / 11;
  int t = threadIdx.x; int k0 = kt * 16;
  __shared__ float Ach[64 * 16];
  float acc[16];
  #pragma unroll
  for (int j = 0; j < 16; j++) acc[j] = 0.f;
  for (int n0 = nc * 256; n0 < nc * 256 + 256; n0 += 64) {
    __syncthreads();
    for (int i = t; i < 64 * 16; i += 256) {
      int nn = i >> 4, kk = i & 15; int k = k0 + kk;
      Ach[i] = (k < KU_) ? A[((size_t)(b * N_ + n0 + nn)) * KU_ + k] : 0.f;
    }
    __syncthreads();
    if (t < NX) {
      for (int nn = 0; nn < 64; nn++) {
        float xv = X[((size_t)(b * N_ + n0 + nn)) * NX + t];
        #pragma unroll
        for (int j = 0; j < 16; j++) acc[j] += Ach[(nn << 4) + j] * xv;
      }
    }
  }
  if (t < NX) {
    #pragma unroll
    for (int j = 0; j < 16; j++) {
      int k = k0 + j;
      if (k < KU_) atomicAdd(&out[((size_t)(b * KU_ + k)) * NX + t], acc[j]);
    }
  }
}

// ---- GRU gate panels: p=0 r-gate (x,h), p=1 z-gate (x,h), p=2 n-input (x), p=3 n-hidden (h) ----
__global__ __launch_bounds__(256) void k_gg(const float* __restrict__ part,
    const float* __restrict__ occ, const float* __restrict__ slots,
    const float* __restrict__ wih, const float* __restrict__ bih,
    const float* __restrict__ whh, const float* __restrict__ bhh,
    float* __restrict__ gbuf) {
  int p = blockIdx.y; int r0 = blockIdx.x * 8; int t = threadIdx.x;
  __shared__ float sx[8 * C_];
  __shared__ float sh[8 * C_];
  bool needx = (p < 3), needh = (p != 2);
  for (int i = t; i < 8 * C_; i += 256) {
    int rr = i >> 8, c = i & 255;
    int r = r0 + rr;
    if (r < BK_) {
      if (needx) {
        float v = 0.f;
        #pragma unroll
        for (int nc = 0; nc < 8; nc++) v += part[((size_t)nc * BK_ + r) * C_ + c];
        sx[i] = v / fmaxf(occ[r], 1e-8f);
      }
      if (needh) sh[i] = slots[(size_t)r * C_ + c];
    } else {
      if (needx) sx[i] = 0.f;
      if (needh) sh[i] = 0.f;
    }
  }
  __syncthreads();
  int grow = (p == 3) ? 512 + t : ((p == 2) ? 512 + t : p * 256 + t);
  float acc[8];
  #pragma unroll
  for (int a = 0; a < 8; a++) acc[a] = 0.f;
  const float4* sx4 = (const float4*)sx;
  const float4* sh4 = (const float4*)sh;
  if (p < 2) {
    const float4* wi = (const float4*)(wih + (size_t)grow * C_);
    const float4* wh = (const float4*)(whh + (size_t)grow * C_);
    for (int c4 = 0; c4 < 64; c4++) {
      float4 a1 = wi[c4], a2 = wh[c4];
      #pragma unroll
      for (int a = 0; a < 8; a++) {
        float4 xv = sx4[a * 64 + c4], hv = sh4[a * 64 + c4];
        acc[a] += xv.x * a1.x + xv.y * a1.y + xv.z * a1.z + xv.w * a1.w
                + hv.x * a2.x + hv.y * a2.y + hv.z * a2.z + hv.w * a2.w;
      }
    }
  } else if (p == 2) {
    const float4* wi = (const float4*)(wih + (size_t)grow * C_);
    for (int c4 = 0; c4 < 64; c4++) {
      float4 a1 = wi[c4];
      #pragma unroll
      for (int a = 0; a < 8; a++) {
        float4 xv = sx4[a * 64 + c4];
        acc[a] += xv.x * a1.x + xv.y * a1.y + xv.z * a1.z + xv.w * a1.w;
      }
    }
  } else {
    const float4* wh = (const float4*)(whh + (size_t)grow * C_);
    for (int c4 = 0; c4 < 64; c4++) {
      float4 a2 = wh[c4];
      #pragma unroll
      for (int a = 0; a < 8; a++) {
        float4 hv = sh4[a * 64 + c4];
        acc[a] += hv.x * a2.x + hv.y * a2.y + hv.z * a2.z + hv.w * a2.w;
      }
    }
  }
  float bias = (p < 2) ? (bih[grow] + bhh[grow]) : ((p == 2) ? bih[grow] : bhh[grow]);
  #pragma unroll
  for (int a = 0; a < 8; a++) {
    int r = r0 + a;
    if (r < BK_) gbuf[((size_t)p * BK_ + r) * C_ + t] = acc[a] + bias;
  }
}

// ---- GRU combine + LayerNorm; 1 row per block ----
__global__ __launch_bounds__(256) void k_gru_ln(const float* __restrict__ gbuf,
    const float* __restrict__ slots, const float* __restrict__ lng,
    const float* __restrict__ lnb, float* __restrict__ snew, float* __restrict__ xm) {
  int r = blockIdx.x; int t = threadIdx.x;
  float gr = gbuf[((size_t)0 * BK_ + r) * C_ + t];
  float gz = gbuf[((size_t)1 * BK_ + r) * C_ + t];
  float gi = gbuf[((size_t)2 * BK_ + r) * C_ + t];
  float gh = gbuf[((size_t)3 * BK_ + r) * C_ + t];
  float rg = 1.f / (1.f + expf(-gr));
  float z = 1.f / (1.f + expf(-gz));
  float n = tanhf(gi + rg * gh);
  float h = slots[(size_t)r * C_ + t];
  float sn = (1.f - z) * n + z * h;
  snew[(size_t)r * C_ + t] = sn;
  __shared__ float reda[4], redb[4];
  int w = t >> 6, lane = t & 63;
  float sum = wred(sn);
  if (lane == 0) reda[w] = sum;
  __syncthreads();
  float mean = (reda[0] + reda[1] + reda[2] + reda[3]) * (1.f / 256.f);
  float d = sn - mean;
  float vs = wred(d * d);
  if (lane == 0) redb[w] = vs;
  __syncthreads();
  float var = (redb[0] + redb[1] + redb[2] + redb[3]) * (1.f / 256.f);
  xm[(size_t)r * C_ + t] = d * rsqrtf(var + 1e-5f) * lng[t] + lnb[t];
}

// ---- w1 + gelu: hid[r, y*256+t] ----
__global__ __launch_bounds__(256) void k_w1(const float* __restrict__ xm,
    const float* __restrict__ w1p, const float* __restrict__ b1p,
    float* __restrict__ hid) {
  int r0 = blockIdx.x * 4; int t = threadIdx.x; int oc = blockIdx.y * 256 + t;
  __shared__ float sm[4 * C_];
  for (int i = t; i < 4 * 64; i += 256) {
    int rr = i >> 6;
    ((float4*)sm)[i] = ((const float4*)(xm + (size_t)(r0 + rr) * C_))[i & 63];
  }
  __syncthreads();
  const float4* W4 = (const float4*)(w1p + (size_t)oc * C_);
  const float4* sm4 = (const float4*)sm;
  float acc[4] = {0, 0, 0, 0};
  for (int c4 = 0; c4 < 64; c4++) {
    float4 wv = W4[c4];
    #pragma unroll
    for (int a = 0; a < 4; a++) {
      float4 sv = sm4[a * 64 + c4];
      acc[a] += sv.x * wv.x + sv.y * wv.y + sv.z * wv.z + sv.w * wv.w;
    }
  }
  float bb = b1p[oc];
  #pragma unroll
  for (int a = 0; a < 4; a++) {
    float v = acc[a] + bb;
    hid[(size_t)(r0 + a) * 1024 + oc] = 0.5f * v * (1.f + erff(v * 0.70710678118654752f));
  }
}

// ---- w2 K-split partials: w2part[kc][r][t] = sum_{c in chunk kc} hid[r,c]*w2[t,c] ----
__global__ __launch_bounds__(256) void k_w2p(const float* __restrict__ hid,
    const float* __restrict__ w2p, float* __restrict__ w2part) {
  int r0 = blockIdx.x * 4; int kc = blockIdx.y; int t = threadIdx.x;
  __shared__ float sm[4 * C_];
  for (int i = t; i < 4 * 64; i += 256) {
    int rr = i >> 6;
    ((float4*)sm)[i] = ((const float4*)(hid + (size_t)(r0 + rr) * 1024 + kc * 256))[i & 63];
  }
  __syncthreads();
  const float4* W4 = (const float4*)(w2p + (size_t)t * 1024 + kc * 256);
  const float4* sm4 = (const float4*)sm;
  float acc[4] = {0, 0, 0, 0};
  for (int c4 = 0; c4 < 64; c4++) {
    float4 wv = W4[c4];
    #pragma unroll
    for (int a = 0; a < 4; a++) {
      float4 sv = sm4[a * 64 + c4];
      acc[a] += sv.x * wv.x + sv.y * wv.y + sv.z * wv.z + sv.w * wv.w;
    }
  }
  #pragma unroll
  for (int a = 0; a < 4; a++)
    w2part[((size_t)kc * BK_ + r0 + a) * C_ + t] = acc[a];
}

// ---- finalize slots = snew + b2 + sum(w2part); then qsem = slots@qW.T ----
__global__ __launch_bounds__(256) void k_qsemf(const float* __restrict__ snew,
    const float* __restrict__ w2part, const float* __restrict__ b2p,
    const float* __restrict__ qWp, float* __restrict__ slots,
    float* __restrict__ qsem) {
  int r0 = blockIdx.x * 4; int t = threadIdx.x;
  __shared__ float sfin[4 * C_];
  for (int i = t; i < 4 * C_; i += 256) {
    int rr = i >> 8, c = i & 255;
    int r = r0 + rr;
    float v = snew[(size_t)r * C_ + c] + b2p[c];
    #pragma unroll
    for (int kc = 0; kc < 4; kc++) v += w2part[((size_t)kc * BK_ + r) * C_ + c];
    sfin[i] = v;
    slots[(size_t)r * C_ + c] = v;
  }
  __syncthreads();
  const float4* qr = (const float4*)(qWp + (size_t)t * C_);
  const float4* s4 = (const float4*)sfin;
  float o[4] = {0, 0, 0, 0};
  for (int c4 = 0; c4 < 64; c4++) {
    float4 wv = qr[c4];
    #pragma unroll
    for (int a = 0; a < 4; a++) {
      float4 xv = s4[a * 64 + c4];
      o[a] += xv.x * wv.x + xv.y * wv.y + xv.z * wv.z + xv.w * wv.w;
    }
  }
  #pragma unroll
  for (int a = 0; a < 4; a++)
    qsem[(size_t)(r0 + a) * C_ + t] = o[a];
}

__global__ __launch_bounds__(256) void k_hist(const int* __restrict__ idx,
    float* __restrict__ okl, float* __restrict__ oent) {
  __shared__ float hist[KMAX_];
  int t = threadIdx.x;
  for (int i = t; i < KMAX_; i += 256) hist[i] = 0.f;
  __syncthreads();
  for (int i = t; i < B_ * KU_; i += 256) atomicAdd(&hist[idx[i]], 1.0f);
  __syncthreads();
  float kl = 0.f, ent = 0.f;
  const float tot = (float)(B_ * KU_);
  for (int i = t; i < KMAX_; i += 256) {
    float pc = fmaxf(hist[i] / tot, 1e-8f);
    float lp = logf(pc);
    kl += pc * (lp + LOGKMAX_);
    ent += pc * lp;
  }
  __shared__ float red[256];
  kl = blk_red(kl, red, t); ent = blk_red(ent, red, t);
  if (t == 0) { okl[0] = kl; oent[0] = ent; }
}

__global__ __launch_bounds__(256) void k_occmse(const float* __restrict__ occ,
    float* __restrict__ out) {
  __shared__ float so[B_ * KU_];
  int t = threadIdx.x;
  for (int i = t; i < B_ * KU_; i += 256) so[i] = occ[i];
  __syncthreads();
  __shared__ float red[256];
  __shared__ float bsum[B_];
  for (int b = 0; b < B_; b++) {
    float s = 0.f;
    for (int i = t; i < KU_; i += 256) s += so[b * KU_ + i];
    s = blk_red(s, red, t);
    if (t == 0) bsum[b] = fmaxf(s, 1e-8f);
    __syncthreads();
  }
  float acc = 0.f;
  const float invK = 1.0f / (float)KU_;
  for (int i = t; i < B_ * KU_; i += 256) {
    int b = i / KU_;
    float v = so[i] / bsum[b] - invK;
    acc += v * v;
  }
  acc = blk_red(acc, red, t);
  if (t == 0) out[0] = acc / (float)(B_ * KU_);
}

// ---- collapse loss partial ----
__global__ __launch_bounds__(256) void k_colpart(const float* __restrict__ AtA,
    float* __restrict__ colacc) {
  int blk = blockIdx.x; int b = blk / KU_, k = blk % KU_; int t = threadIdx.x;
  float acc = 0.f;
  if (t < KU_ && t != k) {
    float dk = AtA[((size_t)(b * KU_ + k)) * KU_ + k];
    float dt = AtA[((size_t)(b * KU_ + t)) * KU_ + t];
    float v  = AtA[((size_t)(b * KU_ + k)) * KU_ + t];
    float gm = v / (fmaxf(sqrtf(dk), 1e-8f) * fmaxf(sqrtf(dt), 1e-8f));
    acc = gm * gm;
  }
  float v = wred(acc);
  __shared__ float p[4];
  if ((t & 63) == 0) p[t >> 6] = v;
  __syncthreads();
  if (t == 0) atomicAdd(colacc, p[0] + p[1] + p[2] + p[3]);
}

__global__ void k_colfin(const float* __restrict__ colacc,
    const float* __restrict__ okl, const float* __restrict__ oent,
    const float* __restrict__ oocc, float* __restrict__ ocol, float* __restrict__ otot) {
  float col = colacc[0] / (float)(B_ * KU_ * KU_);
  ocol[0] = col;
  otot[0] = 0.05f * okl[0] + 0.0f * oent[0] + 0.5f * oocc[0] + 0.1f * col;
}

extern "C" void kernel_launch(void* const* d_in, const int* in_sizes, int n_in,
                              void* d_out_v, int out_size, void* d_ws, size_t ws_size,
                              hipStream_t stream) {
  const float* s     = (const float*)d_in[0];
  const float* mu    = (const float*)d_in[1];
  const float* Sigma = (const float*)d_in[2];
  const float* mask  = (const float*)d_in[3];
  const float* pool  = (const float*)d_in[4];
  const float* geop  = (const float*)d_in[5];
  const float* gW    = (const float*)d_in[6];
  const float* qW    = (const float*)d_in[7];
  const float* kW    = (const float*)d_in[8];
  const float* wih   = (const float*)d_in[9];
  const float* whh   = (const float*)d_in[10];
  const float* bih   = (const float*)d_in[11];
  const float* bhh   = (const float*)d_in[12];
  const float* lng   = (const float*)d_in[13];
  const float* lnb   = (const float*)d_in[14];
  const float* w1    = (const float*)d_in[15];
  const float* b1    = (const float*)d_in[16];
  const float* w2    = (const float*)d_in[17];
  const float* b2    = (const float*)d_in[18];
  const float* wgeo  = (const float*)d_in[19];
  const float* gsr   = (const float*)d_in[20];
  const float* gbias = (const float*)d_in[21];

  float* out = (float*)d_out_v;
  float* A     = out + O_A;
  float* slots = out + O_SLOTS;
  float* muk   = out + O_MUK;
  float* sigk  = out + O_SIGK;
  float* idxf  = out + O_IDX;
  float* okl   = out + O_KL;
  float* oent  = out + O_ENT;
  float* oocc  = out + O_OCC;
  float* ocol  = out + O_COL;
  float* otot  = out + O_TOT;

  float* ws = (float*)d_ws;
  int*   idxi   = (int*)(ws + WS_IDXI);
  float* ksem   = ws + WS_KSEM;
  float* qsem   = ws + WS_QSEM;
  float* occ    = ws + WS_OCC;
  float* atpart = ws + WS_PART;
  float* gbuf   = ws + WS_GBUF;
  float* snew   = ws + WS_SNEW;
  float* xm     = ws + WS_XM;
  float* hid    = ws + WS_HID;
  float* w2part = ws + WS_W2P;
  float* acpart = ws + WS_ACPART;
  float* ata    = ws + WS_ATA;
  float* colacc = ws + WS_COLACC;

  // stage 0
  hipMemsetAsync(ws, 0, WS_STATS_BYTES, stream);
  k_stats<<<B_ * 8, 256, 0, stream>>>(s, mu, Sigma, mask, ws);
  k_fin<<<1, 64, 0, stream>>>(ws);
  k_qv<<<B_, 256, 0, stream>>>(ws + WS_SSUM, gW, ws + WS_QV);
  k_score<<<B_ * 16, 256, 0, stream>>>(ws + WS_QV, pool, ws + WS_SCORE);
  k_sort<<<B_, 256, 0, stream>>>(ws + WS_SCORE, idxi, idxf);
  k_init<<<B_ * KU_, 256, 0, stream>>>(idxi, pool, geop, ws, slots, muk, sigk);

  // ksem = s @ kW.T ; initial qsem = slots @ qW.T
  k_gemm_plain<8><<<1024, 256, 8 * C_ * 4, stream>>>(s, kW, ksem, C_, C_, 1.0f);
  k_gemm_plain<4><<<171, 256, 4 * C_ * 4, stream>>>(slots, qW, qsem, C_, C_, 1.0f);

  for (int it = 0; it < ITERS_; ++it) {
    k_lgsm<<<B_ * (N_ / 16), 256, 0, stream>>>(ksem, qsem, mu, Sigma, mask,
                                               muk, sigk, wgeo, gsr, gbias, A);
    k_accum_part<<<B_ * 11 * AC_NC, 256, 0, stream>>>(A, mu, Sigma, acpart);
    k_accum_fin<<<3, 256, 0, stream>>>(acpart, occ, muk, sigk);
    k_atn_s<<<B_ * 11 * 8, 256, 0, stream>>>(A, s, atpart);
    k_gg<<<dim3(86, 4), 256, 0, stream>>>(atpart, occ, slots, wih, bih, whh, bhh, gbuf);
    k_gru_ln<<<BK_, 256, 0, stream>>>(gbuf, slots, lng, lnb, snew, xm);
    k_w1<<<dim3(171, 4), 256, 0, stream>>>(xm, w1, b1, hid);
    k_w2p<<<dim3(171, 4), 256, 0, stream>>>(hid, w2, w2part);
    k_qsemf<<<171, 256, 0, stream>>>(snew, w2part, b2, qW, slots, qsem);
  }

  // losses
  hipMemsetAsync(ata, 0, (size_t)B_ * KU_ * KU_ * 4, stream);
  k_atn<<<B_ * 11 * 8, 256, 0, stream>>>(A, A, ata, KU_);
  k_colpart<<<B_ * KU_, 256, 0, stream>>>(ata, colacc);
  k_hist<<<1, 256, 0, stream>>>(idxi, okl, oent);
  k_occmse<<<1, 256, 0, stream>>>(occ, oocc);
  k_colfin<<<1, 1, 0, stream>>>(colacc, okl, oent, oocc, ocol, otot);
}

// Round 8
// 786.546 us; speedup vs baseline: 1.7220x; 1.1156x over previous
//
#include <hip/hip_runtime.h>
#include <math.h>

#define B_ 4
#define N_ 2048
#define C_ 256
#define KMAX_ 1024
#define KU_ 171
#define BK_ 684
#define ITERS_ 3
#define H_ 4
#define EPS_ 1e-8f
#define SIGF_ 0.03f
#define JIT_ 1e-6f
#define LOGKMAX_ 6.93147180559945f

// ---------------- workspace layout (float offsets) ----------------
#define WS_CNT 0
#define WS_MUS 4
#define WS_MOS 16
#define WS_SGS 40
#define WS_COLACC 100
#define WS_SSUM 128
#define WS_STATS_BYTES (1152*4)
#define WS_MEAN 1152
#define WS_STD 1164
#define WS_SIGAVG 1176
#define WS_IDXI 1216
#define WS_KSEM 1920                    // B*N*C = 2097152
#define WS_QSEM (WS_KSEM+2097152)       // 175104
#define WS_OCC  (WS_QSEM+175104)        // 704
#define WS_PART (WS_OCC+704)            // 8*684*256 = 1400832 (atn partials; w2part alias)
#define WS_W2P  WS_PART
#define WS_GBUF (WS_PART+1400832)       // 4*684*256 = 700416 (ATA alias after loop)
#define WS_ATA  WS_GBUF
#define WS_SNEW (WS_GBUF+700416)        // 175104
#define WS_HID  (WS_SNEW+175104)        // 684*1024 = 700416
#define WS_ACPART (WS_HID+700416)       // 28160
#define WS_QV   (WS_ACPART+28160)       // 1024
#define WS_SCORE (WS_QV+1024)           // 4096

// ---------------- output layout (float offsets) ----------------
#define O_A 0
#define O_SLOTS 1400832
#define O_MUK   1575936
#define O_SIGK  1577988
#define O_IDX   1584144
#define O_KL    1584828
#define O_ENT   1584829
#define O_OCC   1584830
#define O_COL   1584831
#define O_TOT   1584832

__device__ __forceinline__ float wred(float v) {
  #pragma unroll
  for (int i = 32; i; i >>= 1) v += __shfl_xor(v, i);
  return v;
}
__device__ __forceinline__ float wmax(float v) {
  #pragma unroll
  for (int i = 32; i; i >>= 1) v = fmaxf(v, __shfl_xor(v, i));
  return v;
}

__device__ __forceinline__ float blk_red(float v, float* red, int t) {
  red[t] = v; __syncthreads();
  #pragma unroll
  for (int s = 128; s > 0; s >>= 1) {
    if (t < s) red[t] += red[t + s];
    __syncthreads();
  }
  float r = red[0]; __syncthreads();
  return r;
}

// ---- partial batch stats ----
__global__ __launch_bounds__(256) void k_stats(const float* __restrict__ s,
    const float* __restrict__ mu, const float* __restrict__ Sigma,
    const float* __restrict__ mask, float* __restrict__ ws) {
  int blk = blockIdx.x; int b = blk / 8; int nc = blk % 8; int t = threadIdx.x;
  int n = nc * 256 + t;
  float m = mask[b * N_ + n];
  const float* mun = mu + ((size_t)(b * N_ + n)) * 3;
  float m0 = mun[0], m1v = mun[1], m2 = mun[2];
  const float* sgn = Sigma + ((size_t)(b * N_ + n)) * 9;
  float sg[9];
  #pragma unroll
  for (int j = 0; j < 9; j++) sg[j] = sgn[j];
  int lane = t & 63;
  float vals[19];
  vals[0] = m; vals[1] = m * m0; vals[2] = m * m1v; vals[3] = m * m2;
  vals[4] = m * m0 * m0; vals[5] = m * m0 * m1v; vals[6] = m * m0 * m2;
  vals[7] = m * m1v * m1v; vals[8] = m * m1v * m2; vals[9] = m * m2 * m2;
  #pragma unroll
  for (int j = 0; j < 9; j++) vals[10 + j] = m * sg[j];
  #pragma unroll
  for (int j = 0; j < 19; j++) {
    float v = wred(vals[j]);
    if (lane == 0) {
      int base = (j == 0) ? WS_CNT + b : (j < 4 ? WS_MUS + b * 3 + (j - 1)
                 : (j < 10 ? WS_MOS + b * 6 + (j - 4) : WS_SGS + b * 9 + (j - 10)));
      atomicAdd(ws + base, v);
    }
  }
  const float* sb = s + ((size_t)b * N_ + nc * 256) * C_;
  const float* mk = mask + b * N_ + nc * 256;
  float sa = 0.f;
  #pragma unroll 4
  for (int nn = 0; nn < 256; nn++) sa += mk[nn] * sb[(size_t)nn * C_ + t];
  atomicAdd(ws + WS_SSUM + b * C_ + t, sa);
}

// ---- gating q vector + (block 0) finalize mean/std/sigavg ----
__global__ __launch_bounds__(256) void k_qv(float* __restrict__ ws,
    const float* __restrict__ gW, float* __restrict__ qv_o) {
  int b = blockIdx.x, t = threadIdx.x;
  __shared__ float sb[C_];
  __shared__ float rv[256];
  sb[t] = ws[WS_SSUM + b * C_ + t];
  __syncthreads();
  if (blockIdx.x == 0 && t < B_) {
    int bb = t;
    float cnt = fmaxf(ws[WS_CNT + bb], EPS_);
    float me[3];
    #pragma unroll
    for (int i = 0; i < 3; i++) { me[i] = ws[WS_MUS + bb * 3 + i] / cnt; ws[WS_MEAN + bb * 3 + i] = me[i]; }
    const int dg[3] = {0, 3, 5};
    #pragma unroll
    for (int i = 0; i < 3; i++) {
      float cov = ws[WS_MOS + bb * 6 + dg[i]] / cnt - me[i] * me[i];
      ws[WS_STD + bb * 3 + i] = fmaxf(sqrtf(fmaxf(cov, EPS_)), SIGF_);
    }
    #pragma unroll
    for (int i = 0; i < 3; i++)
      #pragma unroll
      for (int j = 0; j < 3; j++)
        ws[WS_SIGAVG + bb * 9 + i * 3 + j] =
            0.5f * (ws[WS_SGS + bb * 9 + i * 3 + j] + ws[WS_SGS + bb * 9 + j * 3 + i]) / cnt;
  }
  const float4* g4 = (const float4*)(gW + (size_t)t * C_);
  float qr = 0.f;
  #pragma unroll 4
  for (int c4 = 0; c4 < 64; c4++) {
    float4 g = g4[c4];
    qr += sb[c4 * 4] * g.x + sb[c4 * 4 + 1] * g.y + sb[c4 * 4 + 2] * g.z + sb[c4 * 4 + 3] * g.w;
  }
  float n2 = blk_red(qr * qr, rv, t);
  qv_o[b * C_ + t] = qr / fmaxf(sqrtf(n2), 1e-12f);
}

// ---- scores ----
__global__ __launch_bounds__(256) void k_score(const float* __restrict__ qv,
    const float* __restrict__ pool, float* __restrict__ score) {
  int blk = blockIdx.x; int b = blk >> 4; int pc = blk & 15;
  int t = threadIdx.x; int row = pc * 64 + (t >> 2); int q = t & 3;
  __shared__ float qs[C_];
  qs[t] = qv[b * C_ + t];
  __syncthreads();
  const float4* p4 = (const float4*)(pool + (size_t)row * C_ + q * 64);
  float d = 0.f, p2 = 0.f;
  #pragma unroll
  for (int i = 0; i < 16; i++) {
    float4 pv = p4[i];
    int c = q * 64 + i * 4;
    d += qs[c] * pv.x + qs[c + 1] * pv.y + qs[c + 2] * pv.z + qs[c + 3] * pv.w;
    p2 += pv.x * pv.x + pv.y * pv.y + pv.z * pv.z + pv.w * pv.w;
  }
  d += __shfl_xor(d, 1); d += __shfl_xor(d, 2);
  p2 += __shfl_xor(p2, 1); p2 += __shfl_xor(p2, 2);
  if (q == 0) score[b * KMAX_ + row] = d / fmaxf(sqrtf(p2), 1e-12f);
}

// ---- bitonic sort; order == jax.lax.top_k ----
__global__ __launch_bounds__(256) void k_sort(const float* __restrict__ score,
    int* __restrict__ idx_o, float* __restrict__ idxf_o) {
  int b = blockIdx.x, t = threadIdx.x;
  __shared__ float val[KMAX_]; __shared__ int id[KMAX_];
  for (int j = t; j < KMAX_; j += 256) { val[j] = score[b * KMAX_ + j]; id[j] = j; }
  __syncthreads();
  for (int kk = 2; kk <= KMAX_; kk <<= 1) {
    for (int j = kk >> 1; j > 0; j >>= 1) {
      for (int i = t; i < KMAX_; i += 256) {
        int ix = i ^ j;
        if (ix > i) {
          float va = val[i], vb = val[ix]; int ia = id[i], ib = id[ix];
          bool bBeforeA = (vb > va) || (vb == va && ib < ia);
          bool up = ((i & kk) == 0);
          if (up == bBeforeA) {
            val[i] = vb; val[ix] = va; id[i] = ib; id[ix] = ia;
          }
        }
      }
      __syncthreads();
    }
  }
  if (t < KU_) {
    idx_o[b * KU_ + t] = id[t];
    idxf_o[b * KU_ + t] = (float)id[t];
  }
}

// ---- init slots / mu_k / Sig_k ----
__global__ __launch_bounds__(256) void k_init(const int* __restrict__ idx,
    const float* __restrict__ pool, const float* __restrict__ geop,
    const float* __restrict__ ws, float* __restrict__ slots,
    float* __restrict__ mu_k, float* __restrict__ sig_k) {
  int blk = blockIdx.x; int b = blk / KU_, k = blk % KU_; int t = threadIdx.x;
  int j = idx[b * KU_ + k];
  slots[((size_t)(b * KU_ + k)) * C_ + t] = pool[(size_t)j * C_ + t];
  if (t < 3) {
    mu_k[(b * KU_ + k) * 3 + t] = ws[WS_MEAN + b * 3 + t] + geop[j * 3 + t] * (0.5f * ws[WS_STD + b * 3 + t]);
  }
  if (t < 9) {
    float v = ws[WS_SIGAVG + b * 9 + t] * 0.1f;
    if (t == 0 || t == 4 || t == 8) v += SIGF_ * SIGF_ + JIT_;
    sig_k[((size_t)(b * KU_ + k)) * 9 + t] = v;
  }
}

// ---- plain row GEMM: out[r,t] = dot(in[r,:], W[t,:]) ----
template<int ROWS>
__global__ __launch_bounds__(256) void k_gemm_plain(const float* __restrict__ in,
    const float* __restrict__ W, float* __restrict__ out, int IN, int OUT, float scale) {
  extern __shared__ float sm[];
  int t = threadIdx.x; int r0 = blockIdx.x * ROWS;
  int C4 = IN >> 2;
  for (int i = t; i < ROWS * C4; i += 256) {
    int rr = i / C4;
    ((float4*)sm)[i] = ((const float4*)(in + (size_t)(r0 + rr) * IN))[i - rr * C4];
  }
  __syncthreads();
  const float4* W4 = (const float4*)(W + (size_t)t * IN);
  const float4* sm4 = (const float4*)sm;
  float acc[ROWS];
  #pragma unroll
  for (int a = 0; a < ROWS; a++) acc[a] = 0.f;
  for (int c4 = 0; c4 < C4; c4++) {
    float4 wv = W4[c4];
    #pragma unroll
    for (int a = 0; a < ROWS; a++) {
      float4 sv = sm4[a * C4 + c4];
      acc[a] += sv.x * wv.x + sv.y * wv.y + sv.z * wv.z + sv.w * wv.w;
    }
  }
  #pragma unroll
  for (int a = 0; a < ROWS; a++)
    out[(size_t)(r0 + a) * OUT + t] = acc[a] * scale;
}

// ---- FUSED logits + geo + softmax; 8-row tiles for occupancy ----
#define LG_R 8
__global__ __launch_bounds__(256) void k_lgsm(const float* __restrict__ ksem,
    const float* __restrict__ qsem, const float* __restrict__ mu,
    const float* __restrict__ Sigma, const float* __restrict__ mask,
    const float* __restrict__ mu_k, const float* __restrict__ sig_k,
    const float* __restrict__ wgeo, const float* __restrict__ gsr,
    const float* __restrict__ gbias, float* __restrict__ A) {
  __shared__ float ksm[LG_R * C_];
  __shared__ float Asm[LG_R][172];
  __shared__ float muk[KU_ * 3];
  __shared__ float sgk[KU_ * 6];
  __shared__ float rowd[LG_R][10];
  int blk = blockIdx.x; int b = blk / (N_ / LG_R); int nt = blk % (N_ / LG_R);
  int t = threadIdx.x; int r0 = nt * LG_R;
  for (int i = t; i < LG_R * (C_ >> 2); i += 256) {
    int rr = i >> 6;
    ((float4*)ksm)[i] = ((const float4*)(ksem + ((size_t)(b * N_ + r0 + rr)) * C_))[i & 63];
  }
  for (int i = t; i < KU_ * 3; i += 256) muk[i] = mu_k[(size_t)b * KU_ * 3 + i];
  for (int i = t; i < KU_ * 6; i += 256) {
    int k = i / 6, c = i % 6;
    const int map[6] = {0, 1, 2, 4, 5, 8};
    sgk[i] = sig_k[((size_t)(b * KU_ + k)) * 9 + map[c]];
  }
  if (t < LG_R * 10) {
    int rr = t / 10, c = t % 10;
    int n = r0 + rr;
    float v;
    if (c == 0) v = mask[b * N_ + n];
    else if (c < 4) v = mu[((size_t)(b * N_ + n)) * 3 + (c - 1)];
    else {
      const int map[6] = {0, 1, 2, 4, 5, 8};
      v = Sigma[((size_t)(b * N_ + n)) * 9 + map[c - 4]];
    }
    rowd[rr][c] = v;
  }
  __syncthreads();
  if (t < KU_) {
    const float4* q4 = (const float4*)(qsem + ((size_t)(b * KU_ + t)) * C_);
    const float4* sm4 = (const float4*)ksm;
    float acc[LG_R];
    #pragma unroll
    for (int a = 0; a < LG_R; a++) acc[a] = 0.f;
    for (int c4 = 0; c4 < 64; c4++) {
      float4 qv = q4[c4];
      #pragma unroll
      for (int a = 0; a < LG_R; a++) {
        float4 sv = sm4[a * 64 + c4];
        acc[a] += sv.x * qv.x + sv.y * qv.y + sv.z * qv.z + sv.w * qv.w;
      }
    }
    float ah = 0.f, bs = 0.f;
    #pragma unroll
    for (int h = 0; h < H_; h++) {
      float x = gsr[h];
      ah += fmaxf(x, 0.f) + log1pf(expf(-fabsf(x)));
      bs += gbias[h];
    }
    float wg = wgeo[0];
    float mk0 = muk[t * 3], mk1 = muk[t * 3 + 1], mk2 = muk[t * 3 + 2];
    float k00 = sgk[t * 6], k01 = sgk[t * 6 + 1], k02 = sgk[t * 6 + 2];
    float k11 = sgk[t * 6 + 3], k12 = sgk[t * 6 + 4], k22 = sgk[t * 6 + 5];
    #pragma unroll
    for (int a = 0; a < LG_R; a++) {
      float m = rowd[a][0];
      float d0 = rowd[a][1] - mk0, d1 = rowd[a][2] - mk1, d2 = rowd[a][3] - mk2;
      float s00 = rowd[a][4] + k00, s01 = rowd[a][5] + k01, s02 = rowd[a][6] + k02;
      float s11 = rowd[a][7] + k11, s12 = rowd[a][8] + k12, s22 = rowd[a][9] + k22;
      float c00 = s11 * s22 - s12 * s12;
      float c01 = s02 * s12 - s01 * s22;
      float c02 = s01 * s12 - s02 * s11;
      float det = s00 * c00 + s01 * c01 + s02 * c02;
      float c11 = s00 * s22 - s02 * s02;
      float c12 = s01 * s02 - s00 * s12;
      float c22 = s00 * s11 - s01 * s01;
      float inv = 1.0f / det;
      float x0 = (c00 * d0 + c01 * d1 + c02 * d2) * inv;
      float x1 = (c01 * d0 + c11 * d1 + c12 * d2) * inv;
      float x2 = (c02 * d0 + c12 * d1 + c22 * d2) * inv;
      float maha = d0 * x0 + d1 * x1 + d2 * x2;
      float logdet = logf(fmaxf(det, 1e-30f));
      float G = -0.5f * (maha + logdet);
      float l = acc[a] * 0.0625f + wg * (ah * G + bs);
      if (m < 0.5f) l = -1e9f;
      Asm[a][t] = l;
    }
  }
  __syncthreads();
  int w = t >> 6, lane = t & 63;
  #pragma unroll
  for (int q = 0; q < 2; q++) {
    int a = w * 2 + q;
    float v0 = (lane < KU_) ? Asm[a][lane] : -INFINITY;
    float v1 = (lane + 64 < KU_) ? Asm[a][lane + 64] : -INFINITY;
    float v2 = (lane + 128 < KU_) ? Asm[a][lane + 128] : -INFINITY;
    float mx = wmax(fmaxf(v0, fmaxf(v1, v2)));
    float e0 = (lane < KU_) ? expf(v0 - mx) : 0.f;
    float e1 = (lane + 64 < KU_) ? expf(v1 - mx) : 0.f;
    float e2 = (lane + 128 < KU_) ? expf(v2 - mx) : 0.f;
    float ss = wred(e0 + e1 + e2);
    float scale = rowd[a][0] / ss;
    if (lane < KU_) Asm[a][lane] = e0 * scale;
    if (lane + 64 < KU_) Asm[a][lane + 64] = e1 * scale;
    if (lane + 128 < KU_) Asm[a][lane + 128] = e2 * scale;
  }
  __syncthreads();
  for (int i = t; i < LG_R * KU_; i += 256) {
    int a = i / KU_, k = i - a * KU_;
    A[((size_t)(b * N_ + r0 + a)) * KU_ + k] = Asm[a][k];
  }
}

// ---- FUSED moments + slotin partials: blocks 0..175 accum_part, 176..527 atn_s ----
#define AC_NC 4
__global__ __launch_bounds__(256) void k_amoms(const float* __restrict__ A,
    const float* __restrict__ mu, const float* __restrict__ Sigma,
    const float* __restrict__ s, float* __restrict__ acpart,
    float* __restrict__ atpart) {
  __shared__ float shm[1024];           // atn: Ach[64*16]; accum: rowd[16][10] in first 160
  __shared__ float red2[4][16][10];
  int t = threadIdx.x;
  if (blockIdx.x < 176) {
    int blk = blockIdx.x;
    int nc = blk & 3; int tmp = blk >> 2; int kt = tmp % 11; int b = tmp / 11;
    int nn = t >> 4; int kk = t & 15;
    int k = kt * 16 + kk;
    float S[10];
    #pragma unroll
    for (int i = 0; i < 10; i++) S[i] = 0.f;
    float (*rowd)[10] = (float(*)[10])shm;
    const int NCH = N_ / AC_NC;
    for (int n0 = nc * NCH; n0 < nc * NCH + NCH; n0 += 16) {
      __syncthreads();
      if (t < 144) {
        int rr = t / 9, c = t % 9;
        int n = n0 + rr;
        float v;
        if (c < 3) v = mu[((size_t)(b * N_ + n)) * 3 + c];
        else {
          const int map[6] = {0, 1, 2, 4, 5, 8};
          v = Sigma[((size_t)(b * N_ + n)) * 9 + map[c - 3]];
        }
        rowd[rr][c] = v;
      }
      float a = (k < KU_) ? A[((size_t)(b * N_ + n0 + nn)) * KU_ + k] : 0.f;
      __syncthreads();
      float m0 = rowd[nn][0], m1 = rowd[nn][1], m2 = rowd[nn][2];
      float g0 = rowd[nn][3], g1 = rowd[nn][4], g2 = rowd[nn][5];
      float g4 = rowd[nn][6], g5 = rowd[nn][7], g8 = rowd[nn][8];
      S[0] += a; S[1] += a * m0; S[2] += a * m1; S[3] += a * m2;
      S[4] += a * (g0 + m0 * m0); S[5] += a * (g1 + m0 * m1); S[6] += a * (g2 + m0 * m2);
      S[7] += a * (g4 + m1 * m1); S[8] += a * (g5 + m1 * m2); S[9] += a * (g8 + m2 * m2);
    }
    #pragma unroll
    for (int i = 0; i < 10; i++) { S[i] += __shfl_xor(S[i], 16); S[i] += __shfl_xor(S[i], 32); }
    int w = t >> 6, lane = t & 63;
    if (lane < 16) {
      #pragma unroll
      for (int i = 0; i < 10; i++) red2[w][lane][i] = S[i];
    }
    __syncthreads();
    if (t < 160) {
      int k2 = t / 10, i = t % 10;
      float v = red2[0][k2][i] + red2[1][k2][i] + red2[2][k2][i] + red2[3][k2][i];
      acpart[(((size_t)nc * B_ + b) * 176 + kt * 16 + k2) * 10 + i] = v;
    }
  } else {
    int blk = blockIdx.x - 176;
    int nc = blk & 7; int tmp = blk >> 3; int kt = tmp % 11; int b = tmp / 11;
    int k0 = kt * 16;
    float* Ach = shm;
    float acc[16];
    #pragma unroll
    for (int j = 0; j < 16; j++) acc[j] = 0.f;
    for (int n0 = nc * 256; n0 < nc * 256 + 256; n0 += 64) {
      __syncthreads();
      for (int i = t; i < 64 * 16; i += 256) {
        int nn = i >> 4, kk = i & 15; int k = k0 + kk;
        Ach[i] = (k < KU_) ? A[((size_t)(b * N_ + n0 + nn)) * KU_ + k] : 0.f;
      }
      __syncthreads();
      for (int nn = 0; nn < 64; nn++) {
        float xv = s[((size_t)(b * N_ + n0 + nn)) * C_ + t];
        #pragma unroll
        for (int j = 0; j < 16; j++) acc[j] += Ach[(nn << 4) + j] * xv;
      }
    }
    #pragma unroll
    for (int j = 0; j < 16; j++) {
      int k = k0 + j;
      if (k < KU_) atpart[((size_t)nc * (B_ * BK_ / 4) + b * KU_ + k) * C_ + t] = acc[j];
    }
  }
}

// ---- GRU gate panels (x<86) + accum finalize (x>=86, y==0) ----
__global__ __launch_bounds__(256) void k_gg(const float* __restrict__ atpart,
    const float* __restrict__ acpart, const float* __restrict__ slots,
    const float* __restrict__ wih, const float* __restrict__ bih,
    const float* __restrict__ whh, const float* __restrict__ bhh,
    float* __restrict__ gbuf, float* __restrict__ occ,
    float* __restrict__ mu_k, float* __restrict__ sig_k) {
  int t = threadIdx.x;
  if (blockIdx.x >= 86) {
    if (blockIdx.y != 0) return;
    int i = (blockIdx.x - 86) * 256 + t;
    if (i >= B_ * KU_) return;
    int b = i / KU_, k = i % KU_;
    float p[10];
    #pragma unroll
    for (int j = 0; j < 10; j++) {
      float v = 0.f;
      #pragma unroll
      for (int nc = 0; nc < AC_NC; nc++)
        v += acpart[(((size_t)nc * B_ + b) * 176 + k) * 10 + j];
      p[j] = v;
    }
    float o = p[0];
    occ[b * KU_ + k] = o;
    float oc = fmaxf(o, EPS_);
    float s1x = p[1], s1y = p[2], s1z = p[3];
    float q0 = s1x / oc, q1 = s1y / oc, q2 = s1z / oc;
    mu_k[(b * KU_ + k) * 3 + 0] = q0;
    mu_k[(b * KU_ + k) * 3 + 1] = q1;
    mu_k[(b * KU_ + k) * 3 + 2] = q2;
    float v00 = (p[4] - 2.f * q0 * s1x + o * q0 * q0) / oc + JIT_;
    float v01 = (p[5] - q0 * s1y - s1x * q1 + o * q0 * q1) / oc;
    float v02 = (p[6] - q0 * s1z - s1x * q2 + o * q0 * q2) / oc;
    float v11 = (p[7] - 2.f * q1 * s1y + o * q1 * q1) / oc + JIT_;
    float v12 = (p[8] - q1 * s1z - s1y * q2 + o * q1 * q2) / oc;
    float v22 = (p[9] - 2.f * q2 * s1z + o * q2 * q2) / oc + JIT_;
    v00 = fmaxf(v00, SIGF_ * SIGF_) + JIT_;
    v11 = fmaxf(v11, SIGF_ * SIGF_) + JIT_;
    v22 = fmaxf(v22, SIGF_ * SIGF_) + JIT_;
    float* po = sig_k + ((size_t)(b * KU_ + k)) * 9;
    po[0] = v00; po[1] = v01; po[2] = v02;
    po[3] = v01; po[4] = v11; po[5] = v12;
    po[6] = v02; po[7] = v12; po[8] = v22;
    return;
  }
  int p = blockIdx.y; int r0 = blockIdx.x * 8;
  __shared__ float sx[8 * C_];
  __shared__ float sh[8 * C_];
  __shared__ float socc[8];
  bool needx = (p < 3), needh = (p != 2);
  if (t < 8) {
    int r = r0 + t;
    float o = 0.f;
    if (r < BK_) {
      int b = r / KU_, k = r % KU_;
      #pragma unroll
      for (int nc = 0; nc < AC_NC; nc++)
        o += acpart[(((size_t)nc * B_ + b) * 176 + k) * 10];
    }
    socc[t] = fmaxf(o, 1e-8f);
  }
  __syncthreads();
  for (int i = t; i < 8 * C_; i += 256) {
    int rr = i >> 8, c = i & 255;
    int r = r0 + rr;
    if (r < BK_) {
      if (needx) {
        float v = 0.f;
        #pragma unroll
        for (int nc = 0; nc < 8; nc++) v += atpart[((size_t)nc * BK_ + r) * C_ + c];
        sx[i] = v / socc[rr];
      }
      if (needh) sh[i] = slots[(size_t)r * C_ + c];
    } else {
      if (needx) sx[i] = 0.f;
      if (needh) sh[i] = 0.f;
    }
  }
  __syncthreads();
  int grow = (p >= 2) ? 512 + t : p * 256 + t;
  float acc[8];
  #pragma unroll
  for (int a = 0; a < 8; a++) acc[a] = 0.f;
  const float4* sx4 = (const float4*)sx;
  const float4* sh4 = (const float4*)sh;
  if (p < 2) {
    const float4* wi = (const float4*)(wih + (size_t)grow * C_);
    const float4* wh = (const float4*)(whh + (size_t)grow * C_);
    for (int c4 = 0; c4 < 64; c4++) {
      float4 a1 = wi[c4], a2 = wh[c4];
      #pragma unroll
      for (int a = 0; a < 8; a++) {
        float4 xv = sx4[a * 64 + c4], hv = sh4[a * 64 + c4];
        acc[a] += xv.x * a1.x + xv.y * a1.y + xv.z * a1.z + xv.w * a1.w
                + hv.x * a2.x + hv.y * a2.y + hv.z * a2.z + hv.w * a2.w;
      }
    }
  } else if (p == 2) {
    const float4* wi = (const float4*)(wih + (size_t)grow * C_);
    for (int c4 = 0; c4 < 64; c4++) {
      float4 a1 = wi[c4];
      #pragma unroll
      for (int a = 0; a < 8; a++) {
        float4 xv = sx4[a * 64 + c4];
        acc[a] += xv.x * a1.x + xv.y * a1.y + xv.z * a1.z + xv.w * a1.w;
      }
    }
  } else {
    const float4* wh = (const float4*)(whh + (size_t)grow * C_);
    for (int c4 = 0; c4 < 64; c4++) {
      float4 a2 = wh[c4];
      #pragma unroll
      for (int a = 0; a < 8; a++) {
        float4 hv = sh4[a * 64 + c4];
        acc[a] += hv.x * a2.x + hv.y * a2.y + hv.z * a2.z + hv.w * a2.w;
      }
    }
  }
  float bias = (p < 2) ? (bih[grow] + bhh[grow]) : ((p == 2) ? bih[grow] : bhh[grow]);
  #pragma unroll
  for (int a = 0; a < 8; a++) {
    int r = r0 + a;
    if (r < BK_) gbuf[((size_t)p * BK_ + r) * C_ + t] = acc[a] + bias;
  }
}

// ---- FUSED GRU combine + LN + w1 + gelu; y==0 also writes snew ----
__global__ __launch_bounds__(256) void k_w1ln(const float* __restrict__ gbuf,
    const float* __restrict__ slots, const float* __restrict__ lng,
    const float* __restrict__ lnb, const float* __restrict__ w1p,
    const float* __restrict__ b1p, float* __restrict__ snew,
    float* __restrict__ hid) {
  int r0 = blockIdx.x * 4; int t = threadIdx.x; int oc = blockIdx.y * 256 + t;
  __shared__ float ssn[4 * C_];
  __shared__ float sxm[4 * C_];
  bool wr = (blockIdx.y == 0);
  for (int i = t; i < 4 * C_; i += 256) {
    int rr = i >> 8, c = i & 255;
    int r = r0 + rr;
    float gr = gbuf[((size_t)0 * BK_ + r) * C_ + c];
    float gz = gbuf[((size_t)1 * BK_ + r) * C_ + c];
    float gi = gbuf[((size_t)2 * BK_ + r) * C_ + c];
    float gh = gbuf[((size_t)3 * BK_ + r) * C_ + c];
    float rg = 1.f / (1.f + expf(-gr));
    float z = 1.f / (1.f + expf(-gz));
    float n = tanhf(gi + rg * gh);
    float h = slots[(size_t)r * C_ + c];
    float sn = (1.f - z) * n + z * h;
    ssn[i] = sn;
    if (wr) snew[(size_t)r * C_ + c] = sn;
  }
  __syncthreads();
  {
    int w = t >> 6, lane = t & 63;
    float x0 = ssn[w * 256 + lane], x1 = ssn[w * 256 + lane + 64];
    float x2 = ssn[w * 256 + lane + 128], x3 = ssn[w * 256 + lane + 192];
    float mean = wred(x0 + x1 + x2 + x3) * (1.f / 256.f);
    float d0 = x0 - mean, d1 = x1 - mean, d2 = x2 - mean, d3 = x3 - mean;
    float var = wred(d0 * d0 + d1 * d1 + d2 * d2 + d3 * d3) * (1.f / 256.f);
    float rstd = rsqrtf(var + 1e-5f);
    sxm[w * 256 + lane]       = d0 * rstd * lng[lane]       + lnb[lane];
    sxm[w * 256 + lane + 64]  = d1 * rstd * lng[lane + 64]  + lnb[lane + 64];
    sxm[w * 256 + lane + 128] = d2 * rstd * lng[lane + 128] + lnb[lane + 128];
    sxm[w * 256 + lane + 192] = d3 * rstd * lng[lane + 192] + lnb[lane + 192];
  }
  __syncthreads();
  const float4* W4 = (const float4*)(w1p + (size_t)oc * C_);
  const float4* sm4 = (const float4*)sxm;
  float acc[4] = {0, 0, 0, 0};
  for (int c4 = 0; c4 < 64; c4++) {
    float4 wv = W4[c4];
    #pragma unroll
    for (int a = 0; a < 4; a++) {
      float4 sv = sm4[a * 64 + c4];
      acc[a] += sv.x * wv.x + sv.y * wv.y + sv.z * wv.z + sv.w * wv.w;
    }
  }
  float bb = b1p[oc];
  #pragma unroll
  for (int a = 0; a < 4; a++) {
    float v = acc[a] + bb;
    hid[(size_t)(r0 + a) * 1024 + oc] = 0.5f * v * (1.f + erff(v * 0.70710678118654752f));
  }
}

// ---- w2 K-split partials ----
__global__ __launch_bounds__(256) void k_w2p(const float* __restrict__ hid,
    const float* __restrict__ w2p, float* __restrict__ w2part) {
  int r0 = blockIdx.x * 4; int kc = blockIdx.y; int t = threadIdx.x;
  __shared__ float sm[4 * C_];
  for (int i = t; i < 4 * 64; i += 256) {
    int rr = i >> 6;
    ((float4*)sm)[i] = ((const float4*)(hid + (size_t)(r0 + rr) * 1024 + kc * 256))[i & 63];
  }
  __syncthreads();
  const float4* W4 = (const float4*)(w2p + (size_t)t * 1024 + kc * 256);
  const float4* sm4 = (const float4*)sm;
  float acc[4] = {0, 0, 0, 0};
  for (int c4 = 0; c4 < 64; c4++) {
    float4 wv = W4[c4];
    #pragma unroll
    for (int a = 0; a < 4; a++) {
      float4 sv = sm4[a * 64 + c4];
      acc[a] += sv.x * wv.x + sv.y * wv.y + sv.z * wv.z + sv.w * wv.w;
    }
  }
  #pragma unroll
  for (int a = 0; a < 4; a++)
    w2part[((size_t)kc * BK_ + r0 + a) * C_ + t] = acc[a];
}

// ---- finalize slots = snew + b2 + sum(w2part); then qsem = slots@qW.T ----
__global__ __launch_bounds__(256) void k_qsemf(const float* __restrict__ snew,
    const float* __restrict__ w2part, const float* __restrict__ b2p,
    const float* __restrict__ qWp, float* __restrict__ slots,
    float* __restrict__ qsem) {
  int r0 = blockIdx.x * 4; int t = threadIdx.x;
  __shared__ float sfin[4 * C_];
  for (int i = t; i < 4 * C_; i += 256) {
    int rr = i >> 8, c = i & 255;
    int r = r0 + rr;
    float v = snew[(size_t)r * C_ + c] + b2p[c];
    #pragma unroll
    for (int kc = 0; kc < 4; kc++) v += w2part[((size_t)kc * BK_ + r) * C_ + c];
    sfin[i] = v;
    slots[(size_t)r * C_ + c] = v;
  }
  __syncthreads();
  const float4* qr = (const float4*)(qWp + (size_t)t * C_);
  const float4* s4 = (const float4*)sfin;
  float o[4] = {0, 0, 0, 0};
  for (int c4 = 0; c4 < 64; c4++) {
    float4 wv = qr[c4];
    #pragma unroll
    for (int a = 0; a < 4; a++) {
      float4 xv = s4[a * 64 + c4];
      o[a] += xv.x * wv.x + xv.y * wv.y + xv.z * wv.z + xv.w * wv.w;
    }
  }
  #pragma unroll
  for (int a = 0; a < 4; a++)
    qsem[(size_t)(r0 + a) * C_ + t] = o[a];
}

// ---- atomic A^T A ----
__global__ __launch_bounds__(256) void k_atn(const float* __restrict__ A,
    const float* __restrict__ X, float* __restrict__ out, int NX) {
  int blk = blockIdx.x;
  int nc = blk & 7; int tmp = blk >> 3; int kt = tmp % 11; int b = tmp / 11;
  int t = threadIdx.x; int k0 = kt * 16;
  __shared__ float Ach[64 * 16];
  float acc[16];
  #pragma unroll
  for (int j = 0; j < 16; j++) acc[j] = 0.f;
  for (int n0 = nc * 256; n0 < nc * 256 + 256; n0 += 64) {
    __syncthreads();
    for (int i = t; i < 64 * 16; i += 256) {
      int nn = i >> 4, kk = i & 15; int k = k0 + kk;
      Ach[i] = (k < KU_) ? A[((size_t)(b * N_ + n0 + nn)) * KU_ + k] : 0.f;
    }
    __syncthreads();
    if (t < NX) {
      for (int nn = 0; nn < 64; nn++) {
        float xv = X[((size_t)(b * N_ + n0 + nn)) * NX + t];
        #pragma unroll
        for (int j = 0; j < 16; j++) acc[j] += Ach[(nn << 4) + j] * xv;
      }
    }
  }
  if (t < NX) {
    #pragma unroll
    for (int j = 0; j < 16; j++) {
      int k = k0 + j;
      if (k < KU_) atomicAdd(&out[((size_t)(b * KU_ + k)) * NX + t], acc[j]);
    }
  }
}

// ---- hist (block 0) + occmse (block 1) ----
__global__ __launch_bounds__(256) void k_histocc(const int* __restrict__ idx,
    const float* __restrict__ occ, float* __restrict__ okl,
    float* __restrict__ oent, float* __restrict__ oocc) {
  int t = threadIdx.x;
  __shared__ float buf[KMAX_];
  __shared__ float red[256];
  if (blockIdx.x == 0) {
    for (int i = t; i < KMAX_; i += 256) buf[i] = 0.f;
    __syncthreads();
    for (int i = t; i < B_ * KU_; i += 256) atomicAdd(&buf[idx[i]], 1.0f);
    __syncthreads();
    float kl = 0.f, ent = 0.f;
    const float tot = (float)(B_ * KU_);
    for (int i = t; i < KMAX_; i += 256) {
      float pc = fmaxf(buf[i] / tot, 1e-8f);
      float lp = logf(pc);
      kl += pc * (lp + LOGKMAX_);
      ent += pc * lp;
    }
    kl = blk_red(kl, red, t); ent = blk_red(ent, red, t);
    if (t == 0) { okl[0] = kl; oent[0] = ent; }
  } else {
    for (int i = t; i < B_ * KU_; i += 256) buf[i] = occ[i];
    __syncthreads();
    __shared__ float bsum[B_];
    for (int b = 0; b < B_; b++) {
      float s = 0.f;
      for (int i = t; i < KU_; i += 256) s += buf[b * KU_ + i];
      s = blk_red(s, red, t);
      if (t == 0) bsum[b] = fmaxf(s, 1e-8f);
      __syncthreads();
    }
    float acc = 0.f;
    const float invK = 1.0f / (float)KU_;
    for (int i = t; i < B_ * KU_; i += 256) {
      int b = i / KU_;
      float v = buf[i] / bsum[b] - invK;
      acc += v * v;
    }
    acc = blk_red(acc, red, t);
    if (t == 0) oocc[0] = acc / (float)(B_ * KU_);
  }
}

// ---- collapse loss partial ----
__global__ __launch_bounds__(256) void k_colpart(const float* __restrict__ AtA,
    float* __restrict__ colacc) {
  int blk = blockIdx.x; int b = blk / KU_, k = blk % KU_; int t = threadIdx.x;
  float acc = 0.f;
  if (t < KU_ && t != k) {
    float dk = AtA[((size_t)(b * KU_ + k)) * KU_ + k];
    float dt = AtA[((size_t)(b * KU_ + t)) * KU_ + t];
    float v  = AtA[((size_t)(b * KU_ + k)) * KU_ + t];
    float gm = v / (fmaxf(sqrtf(dk), 1e-8f) * fmaxf(sqrtf(dt), 1e-8f));
    acc = gm * gm;
  }
  float v = wred(acc);
  __shared__ float p[4];
  if ((t & 63) == 0) p[t >> 6] = v;
  __syncthreads();
  if (t == 0) atomicAdd(colacc, p[0] + p[1] + p[2] + p[3]);
}

__global__ void k_colfin(const float* __restrict__ colacc,
    const float* __restrict__ okl, const float* __restrict__ oent,
    const float* __restrict__ oocc, float* __restrict__ ocol, float* __restrict__ otot) {
  float col = colacc[0] / (float)(B_ * KU_ * KU_);
  ocol[0] = col;
  otot[0] = 0.05f * okl[0] + 0.0f * oent[0] + 0.5f * oocc[0] + 0.1f * col;
}

extern "C" void kernel_launch(void* const* d_in, const int* in_sizes, int n_in,
                              void* d_out_v, int out_size, void* d_ws, size_t ws_size,
                              hipStream_t stream) {
  const float* s     = (const float*)d_in[0];
  const float* mu    = (const float*)d_in[1];
  const float* Sigma = (const float*)d_in[2];
  const float* mask  = (const float*)d_in[3];
  const float* pool  = (const float*)d_in[4];
  const float* geop  = (const float*)d_in[5];
  const float* gW    = (const float*)d_in[6];
  const float* qW    = (const float*)d_in[7];
  const float* kW    = (const float*)d_in[8];
  const float* wih   = (const float*)d_in[9];
  const float* whh   = (const float*)d_in[10];
  const float* bih   = (const float*)d_in[11];
  const float* bhh   = (const float*)d_in[12];
  const float* lng   = (const float*)d_in[13];
  const float* lnb   = (const float*)d_in[14];
  const float* w1    = (const float*)d_in[15];
  const float* b1    = (const float*)d_in[16];
  const float* w2    = (const float*)d_in[17];
  const float* b2    = (const float*)d_in[18];
  const float* wgeo  = (const float*)d_in[19];
  const float* gsr   = (const float*)d_in[20];
  const float* gbias = (const float*)d_in[21];

  float* out = (float*)d_out_v;
  float* A     = out + O_A;
  float* slots = out + O_SLOTS;
  float* muk   = out + O_MUK;
  float* sigk  = out + O_SIGK;
  float* idxf  = out + O_IDX;
  float* okl   = out + O_KL;
  float* oent  = out + O_ENT;
  float* oocc  = out + O_OCC;
  float* ocol  = out + O_COL;
  float* otot  = out + O_TOT;

  float* ws = (float*)d_ws;
  int*   idxi   = (int*)(ws + WS_IDXI);
  float* ksem   = ws + WS_KSEM;
  float* qsem   = ws + WS_QSEM;
  float* occ    = ws + WS_OCC;
  float* atpart = ws + WS_PART;
  float* gbuf   = ws + WS_GBUF;
  float* snew   = ws + WS_SNEW;
  float* hid    = ws + WS_HID;
  float* w2part = ws + WS_W2P;
  float* acpart = ws + WS_ACPART;
  float* ata    = ws + WS_ATA;
  float* colacc = ws + WS_COLACC;

  // stage 0
  hipMemsetAsync(ws, 0, WS_STATS_BYTES, stream);
  k_stats<<<B_ * 8, 256, 0, stream>>>(s, mu, Sigma, mask, ws);
  k_qv<<<B_, 256, 0, stream>>>(ws, gW, ws + WS_QV);
  k_score<<<B_ * 16, 256, 0, stream>>>(ws + WS_QV, pool, ws + WS_SCORE);
  k_sort<<<B_, 256, 0, stream>>>(ws + WS_SCORE, idxi, idxf);
  k_init<<<B_ * KU_, 256, 0, stream>>>(idxi, pool, geop, ws, slots, muk, sigk);

  // ksem = s @ kW.T ; initial qsem = slots @ qW.T
  k_gemm_plain<8><<<1024, 256, 8 * C_ * 4, stream>>>(s, kW, ksem, C_, C_, 1.0f);
  k_gemm_plain<4><<<171, 256, 4 * C_ * 4, stream>>>(slots, qW, qsem, C_, C_, 1.0f);

  for (int it = 0; it < ITERS_; ++it) {
    k_lgsm<<<B_ * (N_ / LG_R), 256, 0, stream>>>(ksem, qsem, mu, Sigma, mask,
                                                 muk, sigk, wgeo, gsr, gbias, A);
    k_amoms<<<176 + 352, 256, 0, stream>>>(A, mu, Sigma, s, acpart, atpart);
    k_gg<<<dim3(89, 4), 256, 0, stream>>>(atpart, acpart, slots, wih, bih, whh, bhh,
                                          gbuf, occ, muk, sigk);
    k_w1ln<<<dim3(171, 4), 256, 0, stream>>>(gbuf, slots, lng, lnb, w1, b1, snew, hid);
    k_w2p<<<dim3(171, 4), 256, 0, stream>>>(hid, w2, w2part);
    k_qsemf<<<171, 256, 0, stream>>>(snew, w2part, b2, qW, slots, qsem);
  }

  // losses
  hipMemsetAsync(ata, 0, (size_t)B_ * KU_ * KU_ * 4, stream);
  k_atn<<<B_ * 11 * 8, 256, 0, stream>>>(A, A, ata, KU_);
  k_colpart<<<B_ * KU_, 256, 0, stream>>>(ata, colacc);
  k_histocc<<<2, 256, 0, stream>>>(idxi, occ, okl, oent, oocc);
  k_colfin<<<1, 1, 0, stream>>>(colacc, okl, oent, oocc, ocol, otot);
}